// Round 6
// baseline (108.787 us; speedup 1.0000x reference)
//
#include <hip/hip_runtime.h>
#include <hip/hip_bf16.h>
#include <stdint.h>
#include <stddef.h>

#define BATCH 4
#define SEQ   2048
#define DM    512
#define NST   64
#define LN_EPS 1e-5f

typedef __attribute__((ext_vector_type(8))) short short8;
typedef __attribute__((ext_vector_type(4))) float f32x4;

// DPP row_ror:N = 0x120+N (rotate within 16-lane row) — VALU pipe, no LDS
#define ROR_ADD(v, C) \
    v += __int_as_float(__builtin_amdgcn_mov_dpp(__float_as_int(v), (C), 0xF, 0xF, true))

// ---------------- Kernel 0: precompute per-(d,s) scan constants + W -> bf16 ----------------
__global__ __launch_bounds__(256) void k_pre(
    const float* __restrict__ logA, const float* __restrict__ Aim,
    const float* __restrict__ Bp, const float* __restrict__ Cp,
    const float* __restrict__ W,
    float4* __restrict__ c0, __hip_bfloat16* __restrict__ Wbf)
{
    int i = blockIdx.x * 256 + threadIdx.x;
    if (i < DM * DM) Wbf[i] = __float2bfloat16(W[i]);
    if (i < DM * NST) {
        float a = expf(logA[i]);          // decay rate, > 0
        float wim = Aim[i];
        float mag = expf(-a);             // |e^A|
        float er = mag * cosf(wim);
        float ei = mag * sinf(wim);
        float Br = Bp[2*i], Bi = Bp[2*i+1];
        float Cr = Cp[2*i], Ci = Cp[2*i+1];
        float CBr = Cr*Br + Ci*Bi;        // conj(C)*B
        float CBi = Cr*Bi - Ci*Br;
        c0[i] = make_float4(er, ei, CBr, CBi);
    }
}

// ---------------- Kernel 1a: carry pre-scan ----------------
// Scans l = 2047..512 (lane = state, wave = one (b,d) column) recording the exact
// scan state g at l = 1536, 1024, 512 -> carry-in for phase B segments 2, 1, 0.
__global__ __launch_bounds__(512) void k_scanA(
    const float* __restrict__ x, const float4* __restrict__ c0,
    float2* __restrict__ carr)
{
    const int tid  = threadIdx.x;
    const int w    = tid >> 6;
    const int lane = tid & 63;
    const int widx = blockIdx.x * 8 + w;     // 0..2047
    const int b    = widx >> 9, d = widx & 511;

    const float4 cc = c0[d * NST + lane];
    const float er = cc.x, ei = cc.y, CBr = cc.z, CBi = cc.w;
    const float* xcol = x + (size_t)b * SEQ * DM + d;

    float gr = 0.f, gi = 0.f;
    float xpre = xcol[(size_t)(SEQ - 64 + lane) * DM];   // gather: 8 waves/block share lines

    for (int ch = 31; ch >= 8; --ch) {
        const int l0 = ch * 64;
        float xreg = xpre;
        if (ch > 8) xpre = xcol[(size_t)(l0 - 64 + lane) * DM];
        #pragma unroll
        for (int i = 63; i >= 0; --i) {
            float xv = __uint_as_float(
                __builtin_amdgcn_readlane(__float_as_uint(xreg), i));
            float u0 = CBr * xv, u1 = CBi * xv;
            float t  = fmaf(ei, gr, u1);
            gr = fmaf(er, gr, fmaf(-ei, gi, u0));
            gi = fmaf(er, gi, t);
        }
        if (ch == 24 || ch == 16 || ch == 8) {           // g at l0 = 1536 / 1024 / 512
            int seg = (ch >> 3) - 1;                     // -> carry for segment 2 / 1 / 0
            carr[(((size_t)seg * BATCH + b) * DM + d) * NST + lane] = make_float2(gr, gi);
        }
    }
}

// ---------------- Kernel 1b: segmented scan, 4 states/lane ----------------
// 16 lanes per column (lane m holds states m, m+16, m+32, m+48), 4 columns per wave.
// Reduce over 64 states = 3 in-register adds + 4-stage DPP row_ror rotate-add.
// grid: 4 segments x 64 col-groups = 256 blocks; block = 8 waves = 32 consecutive d.
__global__ __launch_bounds__(512) void k_scanB(
    const float* __restrict__ x, const float4* __restrict__ c0,
    const float* __restrict__ Dp, const float2* __restrict__ carr,
    __hip_bfloat16* __restrict__ ybf)
{
    __shared__ float xs[2][8][4][65];        // double-buffered per-wave x stage (pad 65)
    __shared__ __hip_bfloat16 yt[64][36];    // block y transpose tile (pad 36: 8B-aligned rows)

    const int tid  = threadIdx.x;
    const int w    = tid >> 6;
    const int lane = tid & 63;
    const int g    = lane >> 4;              // column within wave
    const int m    = lane & 15;              // lane within column group
    const int seg  = blockIdx.x >> 6;        // 0..3, l in [512seg, 512seg+511]
    const int cg   = blockIdx.x & 63;
    const int b    = cg >> 4;
    const int d0   = (cg & 15) * 32;
    const int dcol = w * 4 + g;              // 0..31
    const int d    = d0 + dcol;

    // per-lane 4 states s = m + 16k: constants + carry-in
    float er[4], ei[4], CBr[4], CBi[4], gr[4], gi[4];
    #pragma unroll
    for (int k = 0; k < 4; ++k) {
        float4 cc = c0[d * NST + m + 16 * k];
        er[k] = cc.x; ei[k] = cc.y; CBr[k] = cc.z; CBi[k] = cc.w;
        if (seg < 3) {
            float2 cin = carr[(((size_t)seg * BATCH + b) * DM + d) * NST + m + 16 * k];
            gr[k] = cin.x; gi[k] = cin.y;
        } else { gr[k] = 0.f; gi[k] = 0.f; }
    }
    const float Dd = Dp[d];
    const float* xcol = x + (size_t)b * SEQ * DM + d;

    // stage top chunk (ch=7) into buffer 1
    float xin[4];
    {
        const int l0 = seg * 512 + 448;
        #pragma unroll
        for (int it = 0; it < 4; ++it)
            xin[it] = xcol[(size_t)(l0 + m + 16 * it) * DM];
        #pragma unroll
        for (int it = 0; it < 4; ++it)
            xs[1][w][g][m + 16 * it] = xin[it];
    }

    for (int ch = 7; ch >= 0; --ch) {
        const int pb  = ch & 1;
        const int l0c = seg * 512 + ch * 64;

        // prefetch next chunk to regs (global latency hides under the 64-step scan)
        if (ch > 0) {
            #pragma unroll
            for (int it = 0; it < 4; ++it)
                xin[it] = xcol[(size_t)(l0c - 64 + m + 16 * it) * DM];
        }

        float yk[4] = {0.f, 0.f, 0.f, 0.f};
        float xk[4] = {0.f, 0.f, 0.f, 0.f};
        const float* xsp = &xs[pb][w][g][0];

        #pragma unroll
        for (int i = 63; i >= 0; --i) {
            float xv = xsp[i];               // LDS broadcast: uniform addr per 16-lane group,
                                             // 4 groups -> 4 distinct banks (pad 65) = free
            #pragma unroll
            for (int k = 0; k < 4; ++k) {
                float u0 = CBr[k] * xv;
                float u1 = CBi[k] * xv;
                float t  = fmaf(ei[k], gr[k], u1);
                gr[k] = fmaf(er[k], gr[k], fmaf(-ei[k], gi[k], u0));
                gi[k] = fmaf(er[k], gi[k], t);
            }
            float ysum = (gr[0] + gr[1]) + (gr[2] + gr[3]);
            ROR_ADD(ysum, 0x121);            // row_ror:1
            ROR_ADD(ysum, 0x122);            // row_ror:2
            ROR_ADD(ysum, 0x124);            // row_ror:4
            ROR_ADD(ysum, 0x128);            // row_ror:8  -> all 16 lanes hold column sum
            const bool pick = (m == (i & 15));
            yk[i >> 4] = pick ? ysum : yk[i >> 4];
            xk[i >> 4] = pick ? xv   : xk[i >> 4];
        }

        // stage next chunk (other buffer; wave-private -> no barrier)
        if (ch > 0) {
            #pragma unroll
            for (int it = 0; it < 4; ++it)
                xs[pb ^ 1][w][g][m + 16 * it] = xin[it];
        }

        // y + D*x -> transpose tile (wave w owns cols 4w..4w+3)
        #pragma unroll
        for (int it = 0; it < 4; ++it)
            yt[m + 16 * it][dcol] = __float2bfloat16(yk[it] + Dd * xk[it]);
        __syncthreads();

        // coalesced store: 512 threads cover 64 rows x 32 cols bf16 (8B per thread)
        {
            const int row = tid >> 3, c4 = (tid & 7) * 4;
            const uint2 vv = *(const uint2*)&yt[row][c4];
            *(uint2*)&ybf[(size_t)(b * SEQ + l0c + row) * DM + d0 + c4] = vv;
        }
        __syncthreads();
    }
}

// ---------------- Kernel 2: fused out_proj GEMM (bf16 MFMA) + residual + LayerNorm ----------------
// out[r][o] = LN_o( b_out[o] + sum_d y[r][d]*W[o][d] + x[r][o] ),  r = b*SEQ+l in [0,8192)
__global__ __launch_bounds__(256) void k_gemm_ln(
    const __hip_bfloat16* __restrict__ ybf, const __hip_bfloat16* __restrict__ Wbf,
    const float* __restrict__ x, const float* __restrict__ bout,
    const float* __restrict__ gamma, const float* __restrict__ beta,
    float* __restrict__ out)
{
    __shared__ short As[32][32];      // y tile [row][k], 16B-chunk XOR swizzle
    __shared__ short Bs[512][32];     // W tile [o][k],   16B-chunk XOR swizzle
    __shared__ float red[4][32][2];   // per-wave row partials (sum, sumsq)
    __shared__ float stats[32][2];    // per-row (mu, rstd)

    const int tid  = threadIdx.x;
    const int w    = tid >> 6;
    const int lane = tid & 63;
    const int q    = lane >> 4;       // k-block / row-quad selector
    const int m    = lane & 15;       // row (A) / col (B,C)
    const int r0   = blockIdx.x * 32;

    f32x4 acc[2][8];
    #pragma unroll
    for (int a = 0; a < 2; ++a)
        #pragma unroll
        for (int n = 0; n < 8; ++n)
            #pragma unroll
            for (int k = 0; k < 4; ++k) acc[a][n][k] = 0.f;

    for (int k0 = 0; k0 < DM; k0 += 32) {
        __syncthreads();
        if (tid < 128) {
            int row = tid >> 2, j = tid & 3;
            short8 v = *(const short8*)(ybf + (size_t)(r0 + row) * DM + k0 + j * 8);
            *(short8*)&As[row][(j ^ (row & 3)) * 8] = v;
        }
        #pragma unroll
        for (int it = 0; it < 8; ++it) {
            int o = it * 64 + (tid >> 2), j = tid & 3;
            short8 v = *(const short8*)(Wbf + (size_t)o * DM + k0 + j * 8);
            *(short8*)&Bs[o][(j ^ (o & 3)) * 8] = v;
        }
        __syncthreads();

        short8 a0 = *(const short8*)&As[m][(q ^ (m & 3)) * 8];
        short8 a1 = *(const short8*)&As[16 + m][(q ^ (m & 3)) * 8];
        #pragma unroll
        for (int nf = 0; nf < 8; ++nf) {
            int o = w * 128 + nf * 16 + m;
            short8 bb = *(const short8*)&Bs[o][(q ^ (m & 3)) * 8];
            acc[0][nf] = __builtin_amdgcn_mfma_f32_16x16x32_bf16(a0, bb, acc[0][nf], 0, 0, 0);
            acc[1][nf] = __builtin_amdgcn_mfma_f32_16x16x32_bf16(a1, bb, acc[1][nf], 0, 0, 0);
        }
    }

    float bo[8], ga[8], be[8];
    #pragma unroll
    for (int nf = 0; nf < 8; ++nf) {
        int o = w * 128 + nf * 16 + m;
        bo[nf] = bout[o]; ga[nf] = gamma[o]; be[nf] = beta[o];
    }

    float rs[2][4], rq[2][4];
    #pragma unroll
    for (int mf = 0; mf < 2; ++mf)
        #pragma unroll
        for (int i = 0; i < 4; ++i) { rs[mf][i] = 0.f; rq[mf][i] = 0.f; }

    #pragma unroll
    for (int mf = 0; mf < 2; ++mf)
        #pragma unroll
        for (int nf = 0; nf < 8; ++nf) {
            int o = w * 128 + nf * 16 + m;
            #pragma unroll
            for (int i = 0; i < 4; ++i) {
                int row = mf * 16 + q * 4 + i;     // C/D: row=(lane>>4)*4+reg, col=lane&15
                float zv = acc[mf][nf][i] + bo[nf] + x[(size_t)(r0 + row) * DM + o];
                acc[mf][nf][i] = zv;
                rs[mf][i] += zv;
                rq[mf][i] += zv * zv;
            }
        }

    #pragma unroll
    for (int mask = 1; mask < 16; mask <<= 1) {
        #pragma unroll
        for (int mf = 0; mf < 2; ++mf)
            #pragma unroll
            for (int i = 0; i < 4; ++i) {
                rs[mf][i] += __shfl_xor(rs[mf][i], mask);
                rq[mf][i] += __shfl_xor(rq[mf][i], mask);
            }
    }
    if (m == 0) {
        #pragma unroll
        for (int mf = 0; mf < 2; ++mf)
            #pragma unroll
            for (int i = 0; i < 4; ++i) {
                int row = mf * 16 + q * 4 + i;
                red[w][row][0] = rs[mf][i];
                red[w][row][1] = rq[mf][i];
            }
    }
    __syncthreads();
    if (tid < 32) {
        float s = 0.f, sq = 0.f;
        #pragma unroll
        for (int ww = 0; ww < 4; ++ww) { s += red[ww][tid][0]; sq += red[ww][tid][1]; }
        float mu  = s * (1.f / DM);
        float var = sq * (1.f / DM) - mu * mu;
        stats[tid][0] = mu;
        stats[tid][1] = 1.f / sqrtf(var + LN_EPS);
    }
    __syncthreads();

    #pragma unroll
    for (int mf = 0; mf < 2; ++mf)
        #pragma unroll
        for (int i = 0; i < 4; ++i) {
            int row = mf * 16 + q * 4 + i;
            float mu = stats[row][0], rstd = stats[row][1];
            #pragma unroll
            for (int nf = 0; nf < 8; ++nf) {
                int o = w * 128 + nf * 16 + m;
                out[(size_t)(r0 + row) * DM + o] =
                    ga[nf] * (acc[mf][nf][i] - mu) * rstd + be[nf];
            }
        }
}

// ---------------- launcher ----------------
extern "C" void kernel_launch(void* const* d_in, const int* in_sizes, int n_in,
                              void* d_out, int out_size, void* d_ws, size_t ws_size,
                              hipStream_t stream)
{
    const float* x    = (const float*)d_in[0];
    const float* logA = (const float*)d_in[1];
    const float* Aim  = (const float*)d_in[2];
    const float* Bp   = (const float*)d_in[3];
    const float* Cp   = (const float*)d_in[4];
    const float* Dp   = (const float*)d_in[5];
    const float* W    = (const float*)d_in[6];
    const float* bo   = (const float*)d_in[7];
    const float* ga   = (const float*)d_in[8];
    const float* be   = (const float*)d_in[9];

    char* ws = (char*)d_ws;
    float4* c0          = (float4*)ws;                          // 512 KiB
    __hip_bfloat16* Wbf = (__hip_bfloat16*)(ws + (512 << 10));  // 512 KiB
    __hip_bfloat16* ybf = (__hip_bfloat16*)(ws + (1 << 20));    // 8 MiB
    float2* carr        = (float2*)(ws + (9 << 20));            // 3 MiB: [3][B][D][S]

    k_pre<<<(DM * DM + 255) / 256, 256, 0, stream>>>(logA, Aim, Bp, Cp, W, c0, Wbf);
    k_scanA<<<BATCH * DM / 8, 512, 0, stream>>>(x, c0, carr);
    k_scanB<<<4 * 64, 512, 0, stream>>>(x, c0, Dp, carr, ybf);
    k_gemm_ln<<<(BATCH * SEQ) / 32, 256, 0, stream>>>(ybf, Wbf, x, bo, ga, be, (float*)d_out);
}

// Round 8
// 104.783 us; speedup vs baseline: 1.0382x; 1.0382x over previous
//
#include <hip/hip_runtime.h>
#include <hip/hip_bf16.h>
#include <stdint.h>
#include <stddef.h>

#define BATCH 4
#define SEQ   2048
#define DM    512
#define NST   64
#define LN_EPS 1e-5f
#define NSEG  8
#define SEGL  256   // SEQ / NSEG

typedef __attribute__((ext_vector_type(8))) short short8;
typedef __attribute__((ext_vector_type(4))) float f32x4;

// DPP row_ror:N = 0x120+N (rotate within 16-lane row) — VALU pipe, no LDS
#define ROR_ADD(v, C) \
    v += __int_as_float(__builtin_amdgcn_mov_dpp(__float_as_int(v), (C), 0xF, 0xF, true))

// ---------------- Kernel 0: precompute scan constants + W -> bf16 ----------------
// c0[d,s]   = (er, ei, CBr, CBi)                    for scanB's per-step recurrence
// cgrp[k][i] = eA^k * CB (k=0..7), cgrp[8][i] = eA^8 for scanA's 8-step groups
__global__ __launch_bounds__(256) void k_pre(
    const float* __restrict__ logA, const float* __restrict__ Aim,
    const float* __restrict__ Bp, const float* __restrict__ Cp,
    const float* __restrict__ W,
    float4* __restrict__ c0, float2* __restrict__ cgrp,
    __hip_bfloat16* __restrict__ Wbf)
{
    int i = blockIdx.x * 256 + threadIdx.x;
    if (i < DM * DM) Wbf[i] = __float2bfloat16(W[i]);
    if (i < DM * NST) {
        float a = expf(logA[i]);          // decay rate, > 0
        float wim = Aim[i];
        float mag = expf(-a);             // |e^A| < 1
        float er = mag * cosf(wim);
        float ei = mag * sinf(wim);
        float Br = Bp[2*i], Bi = Bp[2*i+1];
        float Cr = Cp[2*i], Ci = Cp[2*i+1];
        float CBr = Cr*Br + Ci*Bi;        // conj(C)*B
        float CBi = Cr*Bi - Ci*Br;
        c0[i] = make_float4(er, ei, CBr, CBi);

        float pr = CBr, pi = CBi;         // eA^k * CB
        #pragma unroll
        for (int k = 0; k < 8; ++k) {
            cgrp[k * (DM * NST) + i] = make_float2(pr, pi);
            float npr = er * pr - ei * pi;
            float npi = er * pi + ei * pr;
            pr = npr; pi = npi;
        }
        float a2r = er*er - ei*ei,   a2i = 2.f*er*ei;
        float a4r = a2r*a2r - a2i*a2i, a4i = 2.f*a2r*a2i;
        float a8r = a4r*a4r - a4i*a4i, a8i = 2.f*a4r*a4i;
        cgrp[8 * (DM * NST) + i] = make_float2(a8r, a8i);   // eA^8
    }
}

// ---------------- Kernel 1a: carry pre-scan (8-step groups) ----------------
// Scans l = 2047..256 (lane = state, wave = one (b,d) column) recording the exact
// state g at l = 256*k (k=7..1) -> carry-in for phase B segments 6..0.
// Group identity: g[l] = sum_{k<8} (eA^k CB) x[l+k] + eA^8 g[l+8]  (2 dots + 1 cfma).
__global__ __launch_bounds__(512) void k_scanA(
    const float* __restrict__ x, const float2* __restrict__ cgrp,
    float2* __restrict__ carr)
{
    const int tid  = threadIdx.x;
    const int w    = tid >> 6;
    const int lane = tid & 63;
    const int widx = blockIdx.x * 8 + w;     // 0..2047
    const int b    = widx >> 9, d = widx & 511;

    float cr[8], ci[8];
    #pragma unroll
    for (int k = 0; k < 8; ++k) {
        float2 ck = cgrp[k * (DM * NST) + d * NST + lane];
        cr[k] = ck.x; ci[k] = ck.y;
    }
    float2 a8 = cgrp[8 * (DM * NST) + d * NST + lane];
    const float er8 = a8.x, ei8 = a8.y;

    const float* xcol = x + (size_t)b * SEQ * DM + d;
    float gr = 0.f, gi = 0.f;
    float xpre = xcol[(size_t)(SEQ - 64 + lane) * DM];   // 8 waves/block share lines

    for (int ch = 31; ch >= 4; --ch) {
        float xreg = xpre;
        if (ch > 4) xpre = xcol[(size_t)(ch * 64 - 64 + lane) * DM];

        #pragma unroll
        for (int gidx = 0; gidx < 8; ++gidx) {
            const int i0 = 56 - gidx * 8;
            float sr = 0.f, si = 0.f;
            #pragma unroll
            for (int k = 0; k < 8; ++k) {
                float xv = __uint_as_float(
                    __builtin_amdgcn_readlane(__float_as_uint(xreg), i0 + k));
                sr = fmaf(cr[k], xv, sr);
                si = fmaf(ci[k], xv, si);
            }
            float nr = fmaf(er8, gr, fmaf(-ei8, gi, sr));
            float ni = fmaf(er8, gi, fmaf( ei8, gr, si));
            gr = nr; gi = ni;
        }
        if ((ch & 3) == 0) {                 // g at l = 64*ch = 256*(seg+1)
            int seg = (ch >> 2) - 1;         // 6..0
            carr[(((size_t)seg * BATCH + b) * DM + d) * NST + lane] = make_float2(gr, gi);
        }
    }
}

// ---------------- Kernel 1b: segmented scan, 4 states/lane ----------------
// 16 lanes per column (lane m holds states m, m+16, m+32, m+48), 4 columns per wave.
// Reduce over 64 states = 3 in-register adds + 4-stage DPP row_ror rotate-add.
// grid: 8 segments x 64 col-groups = 512 blocks (2 blocks/CU -> 4 waves/SIMD).
__global__ __launch_bounds__(512) void k_scanB(
    const float* __restrict__ x, const float4* __restrict__ c0,
    const float* __restrict__ Dp, const float2* __restrict__ carr,
    __hip_bfloat16* __restrict__ ybf)
{
    __shared__ float xs[2][8][4][65];        // double-buffered per-wave x stage (pad 65)
    __shared__ __hip_bfloat16 yt[64][36];    // block y transpose tile (pad 36)

    const int tid  = threadIdx.x;
    const int w    = tid >> 6;
    const int lane = tid & 63;
    const int g    = lane >> 4;              // column within wave
    const int m    = lane & 15;              // lane within column group
    const int seg  = blockIdx.x >> 6;        // 0..7, l in [256seg, 256seg+255]
    const int cg   = blockIdx.x & 63;
    const int b    = cg >> 4;
    const int d0   = (cg & 15) * 32;
    const int dcol = w * 4 + g;              // 0..31
    const int d    = d0 + dcol;
    const int lbase = seg * SEGL;

    // per-lane 4 states s = m + 16k: constants + carry-in
    float er[4], ei[4], CBr[4], CBi[4], gr[4], gi[4];
    #pragma unroll
    for (int k = 0; k < 4; ++k) {
        float4 cc = c0[d * NST + m + 16 * k];
        er[k] = cc.x; ei[k] = cc.y; CBr[k] = cc.z; CBi[k] = cc.w;
        if (seg < NSEG - 1) {
            float2 cin = carr[(((size_t)seg * BATCH + b) * DM + d) * NST + m + 16 * k];
            gr[k] = cin.x; gi[k] = cin.y;
        } else { gr[k] = 0.f; gi[k] = 0.f; }
    }
    const float Dd = Dp[d];
    const float* xcol = x + (size_t)b * SEQ * DM + d;

    // stage top chunk (ch=3, pb=1) into buffer 1
    float xin[4];
    {
        const int l0 = lbase + 192;
        #pragma unroll
        for (int it = 0; it < 4; ++it)
            xin[it] = xcol[(size_t)(l0 + m + 16 * it) * DM];
        #pragma unroll
        for (int it = 0; it < 4; ++it)
            xs[1][w][g][m + 16 * it] = xin[it];
    }

    for (int ch = 3; ch >= 0; --ch) {
        const int pb  = ch & 1;
        const int l0c = lbase + ch * 64;

        // prefetch next chunk to regs (global latency hides under the 64-step scan)
        if (ch > 0) {
            #pragma unroll
            for (int it = 0; it < 4; ++it)
                xin[it] = xcol[(size_t)(l0c - 64 + m + 16 * it) * DM];
        }

        float yk[4] = {0.f, 0.f, 0.f, 0.f};
        float xk[4] = {0.f, 0.f, 0.f, 0.f};
        const float* xsp = &xs[pb][w][g][0];

        #pragma unroll
        for (int i = 63; i >= 0; --i) {
            float xv = xsp[i];               // LDS broadcast: uniform addr per 16-lane group,
                                             // 4 groups -> 4 distinct banks (pad 65) = free
            #pragma unroll
            for (int k = 0; k < 4; ++k) {
                float u0 = CBr[k] * xv;
                float u1 = CBi[k] * xv;
                float t  = fmaf(ei[k], gr[k], u1);
                gr[k] = fmaf(er[k], gr[k], fmaf(-ei[k], gi[k], u0));
                gi[k] = fmaf(er[k], gi[k], t);
            }
            float ysum = (gr[0] + gr[1]) + (gr[2] + gr[3]);
            ROR_ADD(ysum, 0x121);            // row_ror:1
            ROR_ADD(ysum, 0x122);            // row_ror:2
            ROR_ADD(ysum, 0x124);            // row_ror:4
            ROR_ADD(ysum, 0x128);            // row_ror:8  -> all 16 lanes hold column sum
            const bool pick = (m == (i & 15));
            yk[i >> 4] = pick ? ysum : yk[i >> 4];
            xk[i >> 4] = pick ? xv   : xk[i >> 4];
        }

        // stage next chunk (other buffer; wave-private -> no barrier)
        if (ch > 0) {
            #pragma unroll
            for (int it = 0; it < 4; ++it)
                xs[pb ^ 1][w][g][m + 16 * it] = xin[it];
        }

        // y + D*x -> transpose tile (wave w owns cols 4w..4w+3)
        #pragma unroll
        for (int it = 0; it < 4; ++it)
            yt[m + 16 * it][dcol] = __float2bfloat16(yk[it] + Dd * xk[it]);
        __syncthreads();

        // coalesced store: 512 threads cover 64 rows x 32 cols bf16 (8B per thread)
        {
            const int row = tid >> 3, c4 = (tid & 7) * 4;
            const uint2 vv = *(const uint2*)&yt[row][c4];
            *(uint2*)&ybf[(size_t)(b * SEQ + l0c + row) * DM + d0 + c4] = vv;
        }
        __syncthreads();
    }
}

// ---------------- Kernel 2: fused out_proj GEMM (bf16 MFMA) + residual + LayerNorm ----------------
// out[r][o] = LN_o( b_out[o] + sum_d y[r][d]*W[o][d] + x[r][o] ),  r = b*SEQ+l in [0,8192)
__global__ __launch_bounds__(256) void k_gemm_ln(
    const __hip_bfloat16* __restrict__ ybf, const __hip_bfloat16* __restrict__ Wbf,
    const float* __restrict__ x, const float* __restrict__ bout,
    const float* __restrict__ gamma, const float* __restrict__ beta,
    float* __restrict__ out)
{
    __shared__ short As[32][32];      // y tile [row][k], 16B-chunk XOR swizzle
    __shared__ short Bs[512][32];     // W tile [o][k],   16B-chunk XOR swizzle
    __shared__ float red[4][32][2];   // per-wave row partials (sum, sumsq)
    __shared__ float stats[32][2];    // per-row (mu, rstd)

    const int tid  = threadIdx.x;
    const int w    = tid >> 6;
    const int lane = tid & 63;
    const int q    = lane >> 4;       // k-block / row-quad selector
    const int m    = lane & 15;       // row (A) / col (B,C)
    const int r0   = blockIdx.x * 32;

    f32x4 acc[2][8];
    #pragma unroll
    for (int a = 0; a < 2; ++a)
        #pragma unroll
        for (int n = 0; n < 8; ++n)
            #pragma unroll
            for (int k = 0; k < 4; ++k) acc[a][n][k] = 0.f;

    for (int k0 = 0; k0 < DM; k0 += 32) {
        __syncthreads();
        if (tid < 128) {
            int row = tid >> 2, j = tid & 3;
            short8 v = *(const short8*)(ybf + (size_t)(r0 + row) * DM + k0 + j * 8);
            *(short8*)&As[row][(j ^ (row & 3)) * 8] = v;
        }
        #pragma unroll
        for (int it = 0; it < 8; ++it) {
            int o = it * 64 + (tid >> 2), j = tid & 3;
            short8 v = *(const short8*)(Wbf + (size_t)o * DM + k0 + j * 8);
            *(short8*)&Bs[o][(j ^ (o & 3)) * 8] = v;
        }
        __syncthreads();

        short8 a0 = *(const short8*)&As[m][(q ^ (m & 3)) * 8];
        short8 a1 = *(const short8*)&As[16 + m][(q ^ (m & 3)) * 8];
        #pragma unroll
        for (int nf = 0; nf < 8; ++nf) {
            int o = w * 128 + nf * 16 + m;
            short8 bb = *(const short8*)&Bs[o][(q ^ (m & 3)) * 8];
            acc[0][nf] = __builtin_amdgcn_mfma_f32_16x16x32_bf16(a0, bb, acc[0][nf], 0, 0, 0);
            acc[1][nf] = __builtin_amdgcn_mfma_f32_16x16x32_bf16(a1, bb, acc[1][nf], 0, 0, 0);
        }
    }

    float bo[8], ga[8], be[8];
    #pragma unroll
    for (int nf = 0; nf < 8; ++nf) {
        int o = w * 128 + nf * 16 + m;
        bo[nf] = bout[o]; ga[nf] = gamma[o]; be[nf] = beta[o];
    }

    float rs[2][4], rq[2][4];
    #pragma unroll
    for (int mf = 0; mf < 2; ++mf)
        #pragma unroll
        for (int i = 0; i < 4; ++i) { rs[mf][i] = 0.f; rq[mf][i] = 0.f; }

    #pragma unroll
    for (int mf = 0; mf < 2; ++mf)
        #pragma unroll
        for (int nf = 0; nf < 8; ++nf) {
            int o = w * 128 + nf * 16 + m;
            #pragma unroll
            for (int i = 0; i < 4; ++i) {
                int row = mf * 16 + q * 4 + i;     // C/D: row=(lane>>4)*4+reg, col=lane&15
                float zv = acc[mf][nf][i] + bo[nf] + x[(size_t)(r0 + row) * DM + o];
                acc[mf][nf][i] = zv;
                rs[mf][i] += zv;
                rq[mf][i] += zv * zv;
            }
        }

    #pragma unroll
    for (int mask = 1; mask < 16; mask <<= 1) {
        #pragma unroll
        for (int mf = 0; mf < 2; ++mf)
            #pragma unroll
            for (int i = 0; i < 4; ++i) {
                rs[mf][i] += __shfl_xor(rs[mf][i], mask);
                rq[mf][i] += __shfl_xor(rq[mf][i], mask);
            }
    }
    if (m == 0) {
        #pragma unroll
        for (int mf = 0; mf < 2; ++mf)
            #pragma unroll
            for (int i = 0; i < 4; ++i) {
                int row = mf * 16 + q * 4 + i;
                red[w][row][0] = rs[mf][i];
                red[w][row][1] = rq[mf][i];
            }
    }
    __syncthreads();
    if (tid < 32) {
        float s = 0.f, sq = 0.f;
        #pragma unroll
        for (int ww = 0; ww < 4; ++ww) { s += red[ww][tid][0]; sq += red[ww][tid][1]; }
        float mu  = s * (1.f / DM);
        float var = sq * (1.f / DM) - mu * mu;
        stats[tid][0] = mu;
        stats[tid][1] = 1.f / sqrtf(var + LN_EPS);
    }
    __syncthreads();

    #pragma unroll
    for (int mf = 0; mf < 2; ++mf)
        #pragma unroll
        for (int i = 0; i < 4; ++i) {
            int row = mf * 16 + q * 4 + i;
            float mu = stats[row][0], rstd = stats[row][1];
            #pragma unroll
            for (int nf = 0; nf < 8; ++nf) {
                int o = w * 128 + nf * 16 + m;
                out[(size_t)(r0 + row) * DM + o] =
                    ga[nf] * (acc[mf][nf][i] - mu) * rstd + be[nf];
            }
        }
}

// ---------------- launcher ----------------
extern "C" void kernel_launch(void* const* d_in, const int* in_sizes, int n_in,
                              void* d_out, int out_size, void* d_ws, size_t ws_size,
                              hipStream_t stream)
{
    const float* x    = (const float*)d_in[0];
    const float* logA = (const float*)d_in[1];
    const float* Aim  = (const float*)d_in[2];
    const float* Bp   = (const float*)d_in[3];
    const float* Cp   = (const float*)d_in[4];
    const float* Dp   = (const float*)d_in[5];
    const float* W    = (const float*)d_in[6];
    const float* bo   = (const float*)d_in[7];
    const float* ga   = (const float*)d_in[8];
    const float* be   = (const float*)d_in[9];

    char* ws = (char*)d_ws;
    float4* c0          = (float4*)ws;                          // 512 KiB
    __hip_bfloat16* Wbf = (__hip_bfloat16*)(ws + (512 << 10));  // 512 KiB
    __hip_bfloat16* ybf = (__hip_bfloat16*)(ws + (1 << 20));    // 8 MiB
    float2* carr        = (float2*)(ws + (9 << 20));            // 7.34 MiB: [7][B][D][S]
    float2* cgrp        = (float2*)(ws + (17 << 20));           // 2.36 MiB: [9][D*S]

    k_pre<<<(DM * DM + 255) / 256, 256, 0, stream>>>(logA, Aim, Bp, Cp, W, c0, cgrp, Wbf);
    k_scanA<<<BATCH * DM / 8, 512, 0, stream>>>(x, cgrp, carr);
    k_scanB<<<NSEG * 64, 512, 0, stream>>>(x, c0, Dp, carr, ybf);
    k_gemm_ln<<<(BATCH * SEQ) / 32, 256, 0, stream>>>(ybf, Wbf, x, bo, ga, be, (float*)d_out);
}

// Round 9
// 103.998 us; speedup vs baseline: 1.0460x; 1.0076x over previous
//
#include <hip/hip_runtime.h>
#include <hip/hip_bf16.h>
#include <stdint.h>
#include <stddef.h>

#define BATCH 4
#define SEQ   2048
#define DM    512
#define NST   64
#define LN_EPS 1e-5f
#define NSEG  8
#define SEGL  256   // SEQ / NSEG

typedef __attribute__((ext_vector_type(8))) short short8;
typedef __attribute__((ext_vector_type(4))) float f32x4;

// DPP row_ror:N = 0x120+N (rotate within 16-lane row) — VALU pipe, no LDS
#define ROR_ADD(v, C) \
    v += __int_as_float(__builtin_amdgcn_mov_dpp(__float_as_int(v), (C), 0xF, 0xF, true))

// ---------------- Kernel 0: precompute scan constants + W -> bf16 ----------------
// c0[d,s]   = (er, ei, CBr, CBi)                    for scanB's per-step recurrence
// cgrp[k][i] = eA^k * CB (k=0..7), cgrp[8][i] = eA^8 for scanA's 8-step groups
__global__ __launch_bounds__(256) void k_pre(
    const float* __restrict__ logA, const float* __restrict__ Aim,
    const float* __restrict__ Bp, const float* __restrict__ Cp,
    const float* __restrict__ W,
    float4* __restrict__ c0, float2* __restrict__ cgrp,
    __hip_bfloat16* __restrict__ Wbf)
{
    int i = blockIdx.x * 256 + threadIdx.x;
    if (i < DM * DM) Wbf[i] = __float2bfloat16(W[i]);
    if (i < DM * NST) {
        float a = expf(logA[i]);          // decay rate, > 0
        float wim = Aim[i];
        float mag = expf(-a);             // |e^A| < 1
        float er = mag * cosf(wim);
        float ei = mag * sinf(wim);
        float Br = Bp[2*i], Bi = Bp[2*i+1];
        float Cr = Cp[2*i], Ci = Cp[2*i+1];
        float CBr = Cr*Br + Ci*Bi;        // conj(C)*B
        float CBi = Cr*Bi - Ci*Br;
        c0[i] = make_float4(er, ei, CBr, CBi);

        float pr = CBr, pi = CBi;         // eA^k * CB
        #pragma unroll
        for (int k = 0; k < 8; ++k) {
            cgrp[k * (DM * NST) + i] = make_float2(pr, pi);
            float npr = er * pr - ei * pi;
            float npi = er * pi + ei * pr;
            pr = npr; pi = npi;
        }
        float a2r = er*er - ei*ei,   a2i = 2.f*er*ei;
        float a4r = a2r*a2r - a2i*a2i, a4i = 2.f*a2r*a2i;
        float a8r = a4r*a4r - a4i*a4i, a8i = 2.f*a4r*a4i;
        cgrp[8 * (DM * NST) + i] = make_float2(a8r, a8i);   // eA^8
    }
}

// ---------------- Kernel 1a: carry pre-scan (8-step groups) ----------------
// Scans l = 2047..256 (lane = state, wave = one (b,d) column) recording the exact
// state g at l = 256*k (k=7..1) -> carry-in for phase B segments 6..0.
// Group identity: g[l] = sum_{k<8} (eA^k CB) x[l+k] + eA^8 g[l+8]  (2 dots + 1 cfma).
__global__ __launch_bounds__(512) void k_scanA(
    const float* __restrict__ x, const float2* __restrict__ cgrp,
    float2* __restrict__ carr)
{
    const int tid  = threadIdx.x;
    const int w    = tid >> 6;
    const int lane = tid & 63;
    const int widx = blockIdx.x * 8 + w;     // 0..2047
    const int b    = widx >> 9, d = widx & 511;

    float cr[8], ci[8];
    #pragma unroll
    for (int k = 0; k < 8; ++k) {
        float2 ck = cgrp[k * (DM * NST) + d * NST + lane];
        cr[k] = ck.x; ci[k] = ck.y;
    }
    float2 a8 = cgrp[8 * (DM * NST) + d * NST + lane];
    const float er8 = a8.x, ei8 = a8.y;

    const float* xcol = x + (size_t)b * SEQ * DM + d;
    float gr = 0.f, gi = 0.f;
    float xpre = xcol[(size_t)(SEQ - 64 + lane) * DM];   // 8 waves/block share lines

    for (int ch = 31; ch >= 4; --ch) {
        float xreg = xpre;
        if (ch > 4) xpre = xcol[(size_t)(ch * 64 - 64 + lane) * DM];

        #pragma unroll
        for (int gidx = 0; gidx < 8; ++gidx) {
            const int i0 = 56 - gidx * 8;
            float sr = 0.f, si = 0.f;
            #pragma unroll
            for (int k = 0; k < 8; ++k) {
                float xv = __uint_as_float(
                    __builtin_amdgcn_readlane(__float_as_uint(xreg), i0 + k));
                sr = fmaf(cr[k], xv, sr);
                si = fmaf(ci[k], xv, si);
            }
            float nr = fmaf(er8, gr, fmaf(-ei8, gi, sr));
            float ni = fmaf(er8, gi, fmaf( ei8, gr, si));
            gr = nr; gi = ni;
        }
        if ((ch & 3) == 0) {                 // g at l = 64*ch = 256*(seg+1)
            int seg = (ch >> 2) - 1;         // 6..0
            carr[(((size_t)seg * BATCH + b) * DM + d) * NST + lane] = make_float2(gr, gi);
        }
    }
}

// ---------------- Kernel 1b: segmented scan, 4 states/lane ----------------
// 16 lanes per column (lane m holds states m, m+16, m+32, m+48), 4 columns per wave.
// Reduce over 64 states = 3 in-register adds + 4-stage DPP row_ror rotate-add.
// x broadcast: uniform-address ds_read_b128 (HW broadcast) — 16 LDS reads per chunk
// instead of 64, batched by full unroll so latency amortizes (round-8 postmortem:
// per-step dependent ds_read_b32 was the ~50% stall).
// grid: 8 segments x 64 col-groups = 512 blocks.
__global__ __launch_bounds__(512) void k_scanB(
    const float* __restrict__ x, const float4* __restrict__ c0,
    const float* __restrict__ Dp, const float2* __restrict__ carr,
    __hip_bfloat16* __restrict__ ybf)
{
    __shared__ __align__(16) float xs[2][8][4][68];   // dbuf x stage; row stride 272B = 17*16 (b128-aligned)
    __shared__ __hip_bfloat16 yt[64][36];             // block y transpose tile (pad 36)

    const int tid  = threadIdx.x;
    const int w    = tid >> 6;
    const int lane = tid & 63;
    const int g    = lane >> 4;              // column within wave
    const int m    = lane & 15;              // lane within column group
    const int seg  = blockIdx.x >> 6;        // 0..7, l in [256seg, 256seg+255]
    const int cg   = blockIdx.x & 63;
    const int b    = cg >> 4;
    const int d0   = (cg & 15) * 32;
    const int dcol = w * 4 + g;              // 0..31
    const int d    = d0 + dcol;
    const int lbase = seg * SEGL;

    // per-lane 4 states s = m + 16k: constants + carry-in
    float er[4], ei[4], CBr[4], CBi[4], gr[4], gi[4];
    #pragma unroll
    for (int k = 0; k < 4; ++k) {
        float4 cc = c0[d * NST + m + 16 * k];
        er[k] = cc.x; ei[k] = cc.y; CBr[k] = cc.z; CBi[k] = cc.w;
        if (seg < NSEG - 1) {
            float2 cin = carr[(((size_t)seg * BATCH + b) * DM + d) * NST + m + 16 * k];
            gr[k] = cin.x; gi[k] = cin.y;
        } else { gr[k] = 0.f; gi[k] = 0.f; }
    }
    const float Dd = Dp[d];
    const float* xcol = x + (size_t)b * SEQ * DM + d;

    // load + stage top chunk (ch=3, pb=1); keep chunk values in xcur for the D*x term
    float xcur[4], xnxt[4];
    {
        const int l0 = lbase + 192;
        #pragma unroll
        for (int it = 0; it < 4; ++it)
            xcur[it] = xcol[(size_t)(l0 + m + 16 * it) * DM];
        #pragma unroll
        for (int it = 0; it < 4; ++it)
            xs[1][w][g][m + 16 * it] = xcur[it];
    }

    for (int ch = 3; ch >= 0; --ch) {
        const int pb  = ch & 1;
        const int l0c = lbase + ch * 64;

        // prefetch next chunk to regs (global latency hides under the 64-step scan)
        if (ch > 0) {
            #pragma unroll
            for (int it = 0; it < 4; ++it)
                xnxt[it] = xcol[(size_t)(l0c - 64 + m + 16 * it) * DM];
        }

        float yk[4] = {0.f, 0.f, 0.f, 0.f};
        const float* xsp = &xs[pb][w][g][0];

        // backward scan: 16 uniform-address b128 broadcasts, 4 steps each
        #pragma unroll
        for (int i4 = 15; i4 >= 0; --i4) {
            const f32x4 xv4 = *(const f32x4*)(xsp + i4 * 4);
            #pragma unroll
            for (int jj = 3; jj >= 0; --jj) {
                const int i = i4 * 4 + jj;
                const float xv = xv4[jj];
                #pragma unroll
                for (int k = 0; k < 4; ++k) {
                    float u0 = CBr[k] * xv;
                    float u1 = CBi[k] * xv;
                    float t  = fmaf(ei[k], gr[k], u1);
                    gr[k] = fmaf(er[k], gr[k], fmaf(-ei[k], gi[k], u0));
                    gi[k] = fmaf(er[k], gi[k], t);
                }
                float ysum = (gr[0] + gr[1]) + (gr[2] + gr[3]);
                ROR_ADD(ysum, 0x121);        // row_ror:1
                ROR_ADD(ysum, 0x122);        // row_ror:2
                ROR_ADD(ysum, 0x124);        // row_ror:4
                ROR_ADD(ysum, 0x128);        // row_ror:8 -> all 16 lanes hold column sum
                const bool pick = (m == (i & 15));
                yk[i >> 4] = pick ? ysum : yk[i >> 4];
            }
        }

        // stage next chunk (other buffer; wave-private -> no barrier)
        if (ch > 0) {
            #pragma unroll
            for (int it = 0; it < 4; ++it)
                xs[pb ^ 1][w][g][m + 16 * it] = xnxt[it];
        }

        // y + D*x -> transpose tile (wave w owns cols 4w..4w+3)
        // lane's xcur[it] == x[l0c + m + 16it] of column dcol == the picked x for yk[it]
        #pragma unroll
        for (int it = 0; it < 4; ++it)
            yt[m + 16 * it][dcol] = __float2bfloat16(yk[it] + Dd * xcur[it]);
        __syncthreads();

        // coalesced store: 512 threads cover 64 rows x 32 cols bf16 (8B per thread)
        {
            const int row = tid >> 3, c4 = (tid & 7) * 4;
            const uint2 vv = *(const uint2*)&yt[row][c4];
            *(uint2*)&ybf[(size_t)(b * SEQ + l0c + row) * DM + d0 + c4] = vv;
        }
        __syncthreads();

        #pragma unroll
        for (int it = 0; it < 4; ++it) xcur[it] = xnxt[it];
    }
}

// ---------------- Kernel 2: fused out_proj GEMM (bf16 MFMA) + residual + LayerNorm ----------------
// out[r][o] = LN_o( b_out[o] + sum_d y[r][d]*W[o][d] + x[r][o] ),  r = b*SEQ+l in [0,8192)
__global__ __launch_bounds__(256) void k_gemm_ln(
    const __hip_bfloat16* __restrict__ ybf, const __hip_bfloat16* __restrict__ Wbf,
    const float* __restrict__ x, const float* __restrict__ bout,
    const float* __restrict__ gamma, const float* __restrict__ beta,
    float* __restrict__ out)
{
    __shared__ short As[32][32];      // y tile [row][k], 16B-chunk XOR swizzle
    __shared__ short Bs[512][32];     // W tile [o][k],   16B-chunk XOR swizzle
    __shared__ float red[4][32][2];   // per-wave row partials (sum, sumsq)
    __shared__ float stats[32][2];    // per-row (mu, rstd)

    const int tid  = threadIdx.x;
    const int w    = tid >> 6;
    const int lane = tid & 63;
    const int q    = lane >> 4;       // k-block / row-quad selector
    const int m    = lane & 15;       // row (A) / col (B,C)
    const int r0   = blockIdx.x * 32;

    f32x4 acc[2][8];
    #pragma unroll
    for (int a = 0; a < 2; ++a)
        #pragma unroll
        for (int n = 0; n < 8; ++n)
            #pragma unroll
            for (int k = 0; k < 4; ++k) acc[a][n][k] = 0.f;

    for (int k0 = 0; k0 < DM; k0 += 32) {
        __syncthreads();
        if (tid < 128) {
            int row = tid >> 2, j = tid & 3;
            short8 v = *(const short8*)(ybf + (size_t)(r0 + row) * DM + k0 + j * 8);
            *(short8*)&As[row][(j ^ (row & 3)) * 8] = v;
        }
        #pragma unroll
        for (int it = 0; it < 8; ++it) {
            int o = it * 64 + (tid >> 2), j = tid & 3;
            short8 v = *(const short8*)(Wbf + (size_t)o * DM + k0 + j * 8);
            *(short8*)&Bs[o][(j ^ (o & 3)) * 8] = v;
        }
        __syncthreads();

        short8 a0 = *(const short8*)&As[m][(q ^ (m & 3)) * 8];
        short8 a1 = *(const short8*)&As[16 + m][(q ^ (m & 3)) * 8];
        #pragma unroll
        for (int nf = 0; nf < 8; ++nf) {
            int o = w * 128 + nf * 16 + m;
            short8 bb = *(const short8*)&Bs[o][(q ^ (m & 3)) * 8];
            acc[0][nf] = __builtin_amdgcn_mfma_f32_16x16x32_bf16(a0, bb, acc[0][nf], 0, 0, 0);
            acc[1][nf] = __builtin_amdgcn_mfma_f32_16x16x32_bf16(a1, bb, acc[1][nf], 0, 0, 0);
        }
    }

    float bo[8], ga[8], be[8];
    #pragma unroll
    for (int nf = 0; nf < 8; ++nf) {
        int o = w * 128 + nf * 16 + m;
        bo[nf] = bout[o]; ga[nf] = gamma[o]; be[nf] = beta[o];
    }

    float rs[2][4], rq[2][4];
    #pragma unroll
    for (int mf = 0; mf < 2; ++mf)
        #pragma unroll
        for (int i = 0; i < 4; ++i) { rs[mf][i] = 0.f; rq[mf][i] = 0.f; }

    #pragma unroll
    for (int mf = 0; mf < 2; ++mf)
        #pragma unroll
        for (int nf = 0; nf < 8; ++nf) {
            int o = w * 128 + nf * 16 + m;
            #pragma unroll
            for (int i = 0; i < 4; ++i) {
                int row = mf * 16 + q * 4 + i;     // C/D: row=(lane>>4)*4+reg, col=lane&15
                float zv = acc[mf][nf][i] + bo[nf] + x[(size_t)(r0 + row) * DM + o];
                acc[mf][nf][i] = zv;
                rs[mf][i] += zv;
                rq[mf][i] += zv * zv;
            }
        }

    #pragma unroll
    for (int mask = 1; mask < 16; mask <<= 1) {
        #pragma unroll
        for (int mf = 0; mf < 2; ++mf)
            #pragma unroll
            for (int i = 0; i < 4; ++i) {
                rs[mf][i] += __shfl_xor(rs[mf][i], mask);
                rq[mf][i] += __shfl_xor(rq[mf][i], mask);
            }
    }
    if (m == 0) {
        #pragma unroll
        for (int mf = 0; mf < 2; ++mf)
            #pragma unroll
            for (int i = 0; i < 4; ++i) {
                int row = mf * 16 + q * 4 + i;
                red[w][row][0] = rs[mf][i];
                red[w][row][1] = rq[mf][i];
            }
    }
    __syncthreads();
    if (tid < 32) {
        float s = 0.f, sq = 0.f;
        #pragma unroll
        for (int ww = 0; ww < 4; ++ww) { s += red[ww][tid][0]; sq += red[ww][tid][1]; }
        float mu  = s * (1.f / DM);
        float var = sq * (1.f / DM) - mu * mu;
        stats[tid][0] = mu;
        stats[tid][1] = 1.f / sqrtf(var + LN_EPS);
    }
    __syncthreads();

    #pragma unroll
    for (int mf = 0; mf < 2; ++mf)
        #pragma unroll
        for (int i = 0; i < 4; ++i) {
            int row = mf * 16 + q * 4 + i;
            float mu = stats[row][0], rstd = stats[row][1];
            #pragma unroll
            for (int nf = 0; nf < 8; ++nf) {
                int o = w * 128 + nf * 16 + m;
                out[(size_t)(r0 + row) * DM + o] =
                    ga[nf] * (acc[mf][nf][i] - mu) * rstd + be[nf];
            }
        }
}

// ---------------- launcher ----------------
extern "C" void kernel_launch(void* const* d_in, const int* in_sizes, int n_in,
                              void* d_out, int out_size, void* d_ws, size_t ws_size,
                              hipStream_t stream)
{
    const float* x    = (const float*)d_in[0];
    const float* logA = (const float*)d_in[1];
    const float* Aim  = (const float*)d_in[2];
    const float* Bp   = (const float*)d_in[3];
    const float* Cp   = (const float*)d_in[4];
    const float* Dp   = (const float*)d_in[5];
    const float* W    = (const float*)d_in[6];
    const float* bo   = (const float*)d_in[7];
    const float* ga   = (const float*)d_in[8];
    const float* be   = (const float*)d_in[9];

    char* ws = (char*)d_ws;
    float4* c0          = (float4*)ws;                          // 512 KiB
    __hip_bfloat16* Wbf = (__hip_bfloat16*)(ws + (512 << 10));  // 512 KiB
    __hip_bfloat16* ybf = (__hip_bfloat16*)(ws + (1 << 20));    // 8 MiB
    float2* carr        = (float2*)(ws + (9 << 20));            // 7.34 MiB: [7][B][D][S]
    float2* cgrp        = (float2*)(ws + (17 << 20));           // 2.36 MiB: [9][D*S]

    k_pre<<<(DM * DM + 255) / 256, 256, 0, stream>>>(logA, Aim, Bp, Cp, W, c0, cgrp, Wbf);
    k_scanA<<<BATCH * DM / 8, 512, 0, stream>>>(x, cgrp, carr);
    k_scanB<<<NSEG * 64, 512, 0, stream>>>(x, c0, Dp, carr, ybf);
    k_gemm_ln<<<(BATCH * SEQ) / 32, 256, 0, stream>>>(ybf, Wbf, x, bo, ga, be, (float*)d_out);
}

// Round 10
// 101.042 us; speedup vs baseline: 1.0766x; 1.0293x over previous
//
#include <hip/hip_runtime.h>
#include <hip/hip_bf16.h>
#include <stdint.h>
#include <stddef.h>

#define BATCH 4
#define SEQ   2048
#define DM    512
#define NST   64
#define LN_EPS 1e-5f
#define NCH   32    // 32 chunks of 64
#define KDIM  192   // 64 x-taps + 128 carry (re,im interleaved)

typedef __attribute__((ext_vector_type(8))) short short8;
typedef __attribute__((ext_vector_type(4))) float f32x4;

__device__ __forceinline__ ushort f2bf(float f) {
    __hip_bfloat16 h = __float2bfloat16(f);
    return *(ushort*)&h;
}
__device__ __forceinline__ float bf2f(ushort u) {
    __hip_bfloat16 h = *(__hip_bfloat16*)&u;
    return __bfloat162float(h);
}

// ---------------- k_xt: transpose x[b][l][d] f32 -> xT[d][b][l] bf16 ----------------
__global__ __launch_bounds__(256) void k_xt(
    const float* __restrict__ x, __hip_bfloat16* __restrict__ xT)
{
    __shared__ float t[64][33];
    const int tid = threadIdx.x;
    const int bid = blockIdx.x;                 // b*512 + lt*16 + dt
    const int dt = bid & 15, lt = (bid >> 4) & 31, b = bid >> 9;
    const int l0 = lt * 64, d0 = dt * 32;
    const int dd = tid & 31, lr = tid >> 5;
    #pragma unroll
    for (int it = 0; it < 8; ++it) {
        int ll = it * 8 + lr;
        t[ll][dd] = x[((size_t)b * SEQ + l0 + ll) * DM + d0 + dd];
    }
    __syncthreads();
    const int dw = tid >> 3, lg = (tid & 7) * 8;
    ushort pk[8];
    #pragma unroll
    for (int i = 0; i < 8; ++i) pk[i] = f2bf(t[lg + i][dw]);
    *(short8*)&xT[((size_t)(d0 + dw) * BATCH + b) * SEQ + l0 + lg] = *(short8*)pk;
}

// ---------------- k_pre: W->bf16 + scanA group constants ----------------
// cgrp[k][i] = eA^k * conj(C)B (k=0..7), cgrp[8][i] = eA^8
__global__ __launch_bounds__(256) void k_pre(
    const float* __restrict__ logA, const float* __restrict__ Aim,
    const float* __restrict__ Bp, const float* __restrict__ Cp,
    const float* __restrict__ W,
    float2* __restrict__ cgrp, __hip_bfloat16* __restrict__ Wbf)
{
    int i = blockIdx.x * 256 + threadIdx.x;
    if (i < DM * DM) Wbf[i] = __float2bfloat16(W[i]);
    if (i < DM * NST) {
        float a = expf(logA[i]);
        float wim = Aim[i];
        float mag = expf(-a);
        float er = mag * cosf(wim);
        float ei = mag * sinf(wim);
        float Br = Bp[2*i], Bi = Bp[2*i+1];
        float Cr = Cp[2*i], Ci = Cp[2*i+1];
        float pr = Cr*Br + Ci*Bi;             // conj(C)*B
        float pi = Cr*Bi - Ci*Br;
        #pragma unroll
        for (int k = 0; k < 8; ++k) {
            cgrp[k * (DM * NST) + i] = make_float2(pr, pi);
            float npr = er * pr - ei * pi;
            float npi = er * pi + ei * pr;
            pr = npr; pi = npi;
        }
        float a2r = er*er - ei*ei,     a2i = 2.f*er*ei;
        float a4r = a2r*a2r - a2i*a2i, a4i = 2.f*a2r*a2i;
        float a8r = a4r*a4r - a4i*a4i, a8i = 2.f*a4r*a4i;
        cgrp[8 * (DM * NST) + i] = make_float2(a8r, a8i);
    }
}

// ---------------- k_mbuild: per-d FIR/carry matrix M[64][192] bf16 ----------------
// M[i][j]      = K[j-i] (j>=i else 0),  K[t] = Re sum_s CB_s eA_s^t
// M[i][64+2s]  = Re(eA_s^(64-i)),  M[i][65+2s] = -Im(eA_s^(64-i))
__global__ __launch_bounds__(512) void k_mbuild(
    const float* __restrict__ logA, const float* __restrict__ Aim,
    const float* __restrict__ Bp, const float* __restrict__ Cp,
    __hip_bfloat16* __restrict__ Mt)
{
    __shared__ float Klds[8][64];
    const int tid = threadIdx.x, w = tid >> 6, lane = tid & 63;
    const int d = blockIdx.x * 8 + w;
    const int i = d * NST + lane;
    float aa  = expf(logA[i]);
    float wim = Aim[i];
    float mag = expf(-aa);
    float er = mag * cosf(wim), ei = mag * sinf(wim);
    float Br = Bp[2*i], Bi = Bp[2*i+1];
    float Cr = Cp[2*i], Ci = Cp[2*i+1];
    float pr = Cr*Br + Ci*Bi;                 // CB * eA^t (t=0)
    float pi = Cr*Bi - Ci*Br;
    float ar = 1.f, ai = 0.f;                 // eA^t
    __hip_bfloat16* Md = Mt + (size_t)d * 64 * KDIM;
    for (int t = 0; t < 64; ++t) {
        float kv = pr;
        #pragma unroll
        for (int mask = 1; mask < 64; mask <<= 1) kv += __shfl_xor(kv, mask);
        if (lane == 0) Klds[w][t] = kv;
        float npr = er*pr - ei*pi, npi = er*pi + ei*pr;  pr = npr; pi = npi;
        float nar = er*ar - ei*ai, nai = er*ai + ei*ar;  ar = nar; ai = nai;   // eA^{t+1}
        uint u = (uint)f2bf(ar) | ((uint)f2bf(-ai) << 16);
        *(uint*)&Md[(63 - t) * KDIM + 64 + 2 * lane] = u;   // row 64-(t+1)
    }
    __syncthreads();
    for (int r = 0; r < 64; ++r) {
        float v = (lane >= r) ? Klds[w][lane - r] : 0.f;
        Md[r * KDIM + lane] = __float2bfloat16(v);
    }
}

// ---------------- k_scanA: carry pre-scan, record every 64 steps ----------------
// wave = (b,d), lane = state; 8-step group identity (exact); carr[d][b][ch][s]
// packed bf16 (cr | ci<<16): carr[ch] = g[64*(ch+1)], ch = 0..30.
__global__ __launch_bounds__(512) void k_scanA(
    const __hip_bfloat16* __restrict__ xT, const float2* __restrict__ cgrp,
    uint* __restrict__ carr)
{
    const int tid = threadIdx.x, w = tid >> 6, lane = tid & 63;
    const int widx = blockIdx.x * 8 + w;     // 0..2047
    const int b = widx >> 9, d = widx & 511;

    float cr[8], ci[8];
    #pragma unroll
    for (int k = 0; k < 8; ++k) {
        float2 ck = cgrp[k * (DM * NST) + d * NST + lane];
        cr[k] = ck.x; ci[k] = ck.y;
    }
    float2 a8 = cgrp[8 * (DM * NST) + d * NST + lane];
    const float er8 = a8.x, ei8 = a8.y;

    const __hip_bfloat16* xc = xT + ((size_t)d * BATCH + b) * SEQ;
    float gr = 0.f, gi = 0.f;
    float xpre = __bfloat162float(xc[(NCH - 1) * 64 + lane]);   // coalesced 128B

    for (int ch = NCH - 1; ch >= 1; --ch) {
        float xreg = xpre;
        if (ch > 1) xpre = __bfloat162float(xc[(ch - 1) * 64 + lane]);

        #pragma unroll
        for (int gidx = 0; gidx < 8; ++gidx) {
            const int i0 = 56 - gidx * 8;
            float sr = 0.f, si = 0.f;
            #pragma unroll
            for (int k = 0; k < 8; ++k) {
                float xv = __uint_as_float(
                    __builtin_amdgcn_readlane(__float_as_uint(xreg), i0 + k));
                sr = fmaf(cr[k], xv, sr);
                si = fmaf(ci[k], xv, si);
            }
            float nr = fmaf(er8, gr, fmaf(-ei8, gi, sr));
            float ni = fmaf(er8, gi, fmaf( ei8, gr, si));
            gr = nr; gi = ni;
        }
        // g[64*ch] = carry for chunk ch-1
        carr[(((size_t)d * BATCH + b) * (NCH - 1) + (ch - 1)) * 64 + lane] =
            (uint)f2bf(gr) | ((uint)f2bf(gi) << 16);
    }
}

// ---------------- k_gemmY: per-d GEMM  y(64 x 128cols) = M(64x192) * Z(192x128) ----------------
// col = b*32 + ch; Z rows 0..63 = x_chunk (bf16), rows 64+2s/65+2s = cr/ci (bf16).
// Epilogue adds D*x (x read back from staged Z) and stores yT[d][b][l] bf16.
__global__ __launch_bounds__(256) void k_gemmY(
    const __hip_bfloat16* __restrict__ Mt, const __hip_bfloat16* __restrict__ xT,
    const uint* __restrict__ carr, const float* __restrict__ Dp,
    __hip_bfloat16* __restrict__ yT)
{
    __shared__ short Ms[64 * 24 * 8];    // 24 KiB, 16B-chunk XOR-swizzled by row&7
    __shared__ short Zs[128 * 24 * 8];   // 48 KiB, swizzled by col&7
    const int tid = threadIdx.x;
    const int d = blockIdx.x;
    const int w = tid >> 6, lane = tid & 63;
    const int q = lane >> 4, n = lane & 15;

    // stage M_d (coalesced 16B per thread x6)
    {
        const short* Mg = (const short*)(Mt + (size_t)d * 64 * KDIM);
        #pragma unroll
        for (int it = 0; it < 6; ++it) {
            int G = it * 256 + tid;                  // 0..1535
            int row = G / 24, c = G % 24;
            int cs = (c & ~7) | ((c & 7) ^ (row & 7));
            *(short8*)&Ms[(row * 24 + cs) * 8] = *(const short8*)&Mg[G * 8];
        }
    }
    // stage Z x-part: 128 cols x 8 chunks
    {
        #pragma unroll
        for (int it = 0; it < 4; ++it) {
            int id = it * 256 + tid;                 // 0..1023
            int col = id >> 3, ck = id & 7;
            int bb = col >> 5, ch = col & 31;
            short8 v = *(const short8*)&xT[((size_t)d * BATCH + bb) * SEQ + ch * 64 + ck * 8];
            int cs = ck ^ (col & 7);
            *(short8*)&Zs[(col * 24 + cs) * 8] = v;
        }
    }
    // stage Z carry-part: 128 cols x 16 chunks (4 packed states per 16B)
    {
        #pragma unroll
        for (int it = 0; it < 8; ++it) {
            int id = it * 256 + tid;                 // 0..2047
            int col = id >> 4, st = id & 15;
            int bb = col >> 5, ch = col & 31;
            short8 v = {0,0,0,0,0,0,0,0};
            if (ch != 31)
                v = *(const short8*)(carr + (((size_t)d * BATCH + bb) * (NCH-1) + ch) * 64 + st * 4);
            int c = 8 + st;
            int cs = (c & ~7) | ((c & 7) ^ (col & 7));
            *(short8*)&Zs[(col * 24 + cs) * 8] = v;
        }
    }
    __syncthreads();

    f32x4 acc[8];
    #pragma unroll
    for (int nf = 0; nf < 8; ++nf)
        #pragma unroll
        for (int k = 0; k < 4; ++k) acc[nf][k] = 0.f;

    const int arow = w * 16 + n;                     // wave w owns rows 16w..16w+15
    #pragma unroll
    for (int kt = 0; kt < 6; ++kt) {
        int c = kt * 4 + q;
        int csa = (c & ~7) | ((c & 7) ^ (arow & 7));
        short8 af = *(const short8*)&Ms[(arow * 24 + csa) * 8];
        #pragma unroll
        for (int nf = 0; nf < 8; ++nf) {
            int col = nf * 16 + n;
            int csb = (c & ~7) | ((c & 7) ^ (col & 7));
            short8 bfr = *(const short8*)&Zs[(col * 24 + csb) * 8];
            acc[nf] = __builtin_amdgcn_mfma_f32_16x16x32_bf16(af, bfr, acc[nf], 0, 0, 0);
        }
    }

    // epilogue: + D*x (from staged Z), store yT; C/D: row = 4q+reg (in-wave), col = n
    const float Dd = Dp[d];
    const int i0 = w * 16 + q * 4;
    #pragma unroll
    for (int nf = 0; nf < 8; ++nf) {
        int col = nf * 16 + n;
        int bb = col >> 5, ch = col & 31;
        int cx = (i0 >> 3) ^ (col & 7);
        const ushort* zp = (const ushort*)&Zs[(col * 24 + cx) * 8 + (i0 & 7)];
        ushort o[4];
        #pragma unroll
        for (int r = 0; r < 4; ++r)
            o[r] = f2bf(acc[nf][r] + Dd * bf2f(zp[r]));
        *(uint2*)&yT[((size_t)d * BATCH + bb) * SEQ + ch * 64 + i0] = *(uint2*)o;
    }
}

// ---------------- k_gemm_ln: out_proj GEMM + residual + LayerNorm ----------------
// A tile now sourced from yT[d][b][l]; everything else unchanged (validated).
__global__ __launch_bounds__(256) void k_gemm_ln(
    const __hip_bfloat16* __restrict__ yT, const __hip_bfloat16* __restrict__ Wbf,
    const float* __restrict__ x, const float* __restrict__ bout,
    const float* __restrict__ gamma, const float* __restrict__ beta,
    float* __restrict__ out)
{
    __shared__ short As[32][32];
    __shared__ short Bs[512][32];
    __shared__ float red[4][32][2];
    __shared__ float stats[32][2];

    const int tid  = threadIdx.x;
    const int w    = tid >> 6;
    const int lane = tid & 63;
    const int q    = lane >> 4;
    const int m    = lane & 15;
    const int r0   = blockIdx.x * 32;
    const int bq   = r0 >> 11;           // batch index (r0 32-aligned, no straddle)
    const int l0   = r0 & 2047;

    f32x4 acc[2][8];
    #pragma unroll
    for (int a = 0; a < 2; ++a)
        #pragma unroll
        for (int nn = 0; nn < 8; ++nn)
            #pragma unroll
            for (int k = 0; k < 4; ++k) acc[a][nn][k] = 0.f;

    for (int k0 = 0; k0 < DM; k0 += 32) {
        __syncthreads();
        // stage A from yT: thread = (kd, lgroup of 4 l)
        {
            int kd = tid >> 3, lg = (tid & 7) * 4;
            uint2 vv = *(const uint2*)&yT[((size_t)(k0 + kd) * BATCH + bq) * SEQ + l0 + lg];
            ushort e0 = vv.x & 0xffff, e1 = vv.x >> 16;
            ushort e2 = vv.y & 0xffff, e3 = vv.y >> 16;
            int c = kd >> 3, e = kd & 7;
            As[lg + 0][((c ^ 0) << 3) + e] = (short)e0;
            As[lg + 1][((c ^ 1) << 3) + e] = (short)e1;
            As[lg + 2][((c ^ 2) << 3) + e] = (short)e2;
            As[lg + 3][((c ^ 3) << 3) + e] = (short)e3;
        }
        #pragma unroll
        for (int it = 0; it < 8; ++it) {
            int o = it * 64 + (tid >> 2), j = tid & 3;
            short8 v = *(const short8*)(Wbf + (size_t)o * DM + k0 + j * 8);
            *(short8*)&Bs[o][(j ^ (o & 3)) * 8] = v;
        }
        __syncthreads();

        short8 a0 = *(const short8*)&As[m][(q ^ (m & 3)) * 8];
        short8 a1 = *(const short8*)&As[16 + m][(q ^ (m & 3)) * 8];
        #pragma unroll
        for (int nf = 0; nf < 8; ++nf) {
            int o = w * 128 + nf * 16 + m;
            short8 bb = *(const short8*)&Bs[o][(q ^ (m & 3)) * 8];
            acc[0][nf] = __builtin_amdgcn_mfma_f32_16x16x32_bf16(a0, bb, acc[0][nf], 0, 0, 0);
            acc[1][nf] = __builtin_amdgcn_mfma_f32_16x16x32_bf16(a1, bb, acc[1][nf], 0, 0, 0);
        }
    }

    float bo[8], ga[8], be[8];
    #pragma unroll
    for (int nf = 0; nf < 8; ++nf) {
        int o = w * 128 + nf * 16 + m;
        bo[nf] = bout[o]; ga[nf] = gamma[o]; be[nf] = beta[o];
    }

    float rs[2][4], rq[2][4];
    #pragma unroll
    for (int mf = 0; mf < 2; ++mf)
        #pragma unroll
        for (int i = 0; i < 4; ++i) { rs[mf][i] = 0.f; rq[mf][i] = 0.f; }

    #pragma unroll
    for (int mf = 0; mf < 2; ++mf)
        #pragma unroll
        for (int nf = 0; nf < 8; ++nf) {
            int o = w * 128 + nf * 16 + m;
            #pragma unroll
            for (int i = 0; i < 4; ++i) {
                int row = mf * 16 + q * 4 + i;
                float zv = acc[mf][nf][i] + bo[nf] + x[(size_t)(r0 + row) * DM + o];
                acc[mf][nf][i] = zv;
                rs[mf][i] += zv;
                rq[mf][i] += zv * zv;
            }
        }

    #pragma unroll
    for (int mask = 1; mask < 16; mask <<= 1) {
        #pragma unroll
        for (int mf = 0; mf < 2; ++mf)
            #pragma unroll
            for (int i = 0; i < 4; ++i) {
                rs[mf][i] += __shfl_xor(rs[mf][i], mask);
                rq[mf][i] += __shfl_xor(rq[mf][i], mask);
            }
    }
    if (m == 0) {
        #pragma unroll
        for (int mf = 0; mf < 2; ++mf)
            #pragma unroll
            for (int i = 0; i < 4; ++i) {
                int row = mf * 16 + q * 4 + i;
                red[w][row][0] = rs[mf][i];
                red[w][row][1] = rq[mf][i];
            }
    }
    __syncthreads();
    if (tid < 32) {
        float s = 0.f, sq = 0.f;
        #pragma unroll
        for (int ww = 0; ww < 4; ++ww) { s += red[ww][tid][0]; sq += red[ww][tid][1]; }
        float mu  = s * (1.f / DM);
        float var = sq * (1.f / DM) - mu * mu;
        stats[tid][0] = mu;
        stats[tid][1] = 1.f / sqrtf(var + LN_EPS);
    }
    __syncthreads();

    #pragma unroll
    for (int mf = 0; mf < 2; ++mf)
        #pragma unroll
        for (int i = 0; i < 4; ++i) {
            int row = mf * 16 + q * 4 + i;
            float mu = stats[row][0], rstd = stats[row][1];
            #pragma unroll
            for (int nf = 0; nf < 8; ++nf) {
                int o = w * 128 + nf * 16 + m;
                out[(size_t)(r0 + row) * DM + o] =
                    ga[nf] * (acc[mf][nf][i] - mu) * rstd + be[nf];
            }
        }
}

// ---------------- launcher ----------------
extern "C" void kernel_launch(void* const* d_in, const int* in_sizes, int n_in,
                              void* d_out, int out_size, void* d_ws, size_t ws_size,
                              hipStream_t stream)
{
    const float* x    = (const float*)d_in[0];
    const float* logA = (const float*)d_in[1];
    const float* Aim  = (const float*)d_in[2];
    const float* Bp   = (const float*)d_in[3];
    const float* Cp   = (const float*)d_in[4];
    const float* Dp   = (const float*)d_in[5];
    const float* W    = (const float*)d_in[6];
    const float* bo   = (const float*)d_in[7];
    const float* ga   = (const float*)d_in[8];
    const float* be   = (const float*)d_in[9];

    char* ws = (char*)d_ws;
    __hip_bfloat16* Wbf = (__hip_bfloat16*)ws;                   // 512 KiB @ 0
    float2* cgrp        = (float2*)(ws + (512 << 10));           // 2.36 MiB @ 0.5M
    __hip_bfloat16* xT  = (__hip_bfloat16*)(ws + (3u << 20));    // 8 MiB    @ 3M
    __hip_bfloat16* Mt  = (__hip_bfloat16*)(ws + (11u << 20));   // 12.6 MiB @ 11M
    uint* carr          = (uint*)(ws + (24u << 20));             // 16.25MiB @ 24M
    __hip_bfloat16* yT  = (__hip_bfloat16*)(ws + (41u << 20));   // 8 MiB    @ 41M

    k_xt     <<<BATCH * 32 * 16, 256, 0, stream>>>(x, xT);
    k_pre    <<<(DM * DM + 255) / 256, 256, 0, stream>>>(logA, Aim, Bp, Cp, W, cgrp, Wbf);
    k_mbuild <<<DM / 8, 512, 0, stream>>>(logA, Aim, Bp, Cp, Mt);
    k_scanA  <<<(BATCH * DM) / 8, 512, 0, stream>>>(xT, cgrp, carr);
    k_gemmY  <<<DM, 256, 0, stream>>>(Mt, xT, carr, Dp, yT);
    k_gemm_ln<<<(BATCH * SEQ) / 32, 256, 0, stream>>>(yT, Wbf, x, bo, ga, be, (float*)d_out);
}

// Round 11
// 100.371 us; speedup vs baseline: 1.0838x; 1.0067x over previous
//
#include <hip/hip_runtime.h>
#include <hip/hip_bf16.h>
#include <stdint.h>
#include <stddef.h>

#define BATCH 4
#define SEQ   2048
#define DM    512
#define NST   64
#define LN_EPS 1e-5f
#define NCH   32    // 32 chunks of 64
#define KDIM  192   // 64 x-taps + 128 carry (re,im interleaved)

typedef __attribute__((ext_vector_type(8))) short short8;
typedef __attribute__((ext_vector_type(4))) float f32x4;

__device__ __forceinline__ ushort f2bf(float f) {
    __hip_bfloat16 h = __float2bfloat16(f);
    return *(ushort*)&h;
}
__device__ __forceinline__ float bf2f(ushort u) {
    __hip_bfloat16 h = *(__hip_bfloat16*)&u;
    return __bfloat162float(h);
}

// ---------------- k_xt: transpose x[b][l][d] f32 -> xT[d][b][l] bf16 ----------------
__global__ __launch_bounds__(256) void k_xt(
    const float* __restrict__ x, __hip_bfloat16* __restrict__ xT)
{
    __shared__ float t[64][33];
    const int tid = threadIdx.x;
    const int bid = blockIdx.x;                 // b*512 + lt*16 + dt
    const int dt = bid & 15, lt = (bid >> 4) & 31, b = bid >> 9;
    const int l0 = lt * 64, d0 = dt * 32;
    const int dd = tid & 31, lr = tid >> 5;
    #pragma unroll
    for (int it = 0; it < 8; ++it) {
        int ll = it * 8 + lr;
        t[ll][dd] = x[((size_t)b * SEQ + l0 + ll) * DM + d0 + dd];
    }
    __syncthreads();
    const int dw = tid >> 3, lg = (tid & 7) * 8;
    ushort pk[8];
    #pragma unroll
    for (int i = 0; i < 8; ++i) pk[i] = f2bf(t[lg + i][dw]);
    *(short8*)&xT[((size_t)(d0 + dw) * BATCH + b) * SEQ + l0 + lg] = *(short8*)pk;
}

// ---------------- k_pre: W->bf16 + scanA group constants ----------------
// cgrp[k][i] = eA^k * conj(C)B (k=0..7), cgrp[8][i] = eA^8
__global__ __launch_bounds__(256) void k_pre(
    const float* __restrict__ logA, const float* __restrict__ Aim,
    const float* __restrict__ Bp, const float* __restrict__ Cp,
    const float* __restrict__ W,
    float2* __restrict__ cgrp, __hip_bfloat16* __restrict__ Wbf)
{
    int i = blockIdx.x * 256 + threadIdx.x;
    if (i < DM * DM) Wbf[i] = __float2bfloat16(W[i]);
    if (i < DM * NST) {
        float a = expf(logA[i]);
        float wim = Aim[i];
        float mag = expf(-a);
        float er = mag * cosf(wim);
        float ei = mag * sinf(wim);
        float Br = Bp[2*i], Bi = Bp[2*i+1];
        float Cr = Cp[2*i], Ci = Cp[2*i+1];
        float pr = Cr*Br + Ci*Bi;             // conj(C)*B
        float pi = Cr*Bi - Ci*Br;
        #pragma unroll
        for (int k = 0; k < 8; ++k) {
            cgrp[k * (DM * NST) + i] = make_float2(pr, pi);
            float npr = er * pr - ei * pi;
            float npi = er * pi + ei * pr;
            pr = npr; pi = npi;
        }
        float a2r = er*er - ei*ei,     a2i = 2.f*er*ei;
        float a4r = a2r*a2r - a2i*a2i, a4i = 2.f*a2r*a2i;
        float a8r = a4r*a4r - a4i*a4i, a8i = 2.f*a4r*a4i;
        cgrp[8 * (DM * NST) + i] = make_float2(a8r, a8i);
    }
}

// ---------------- k_mbuild: per-d FIR/carry matrix M[64][192] bf16 ----------------
// M[i][j]      = K[j-i] (j>=i else 0),  K[t] = Re sum_s CB_s eA_s^t
// M[i][64+2s]  = Re(eA_s^(64-i)),  M[i][65+2s] = -Im(eA_s^(64-i))
__global__ __launch_bounds__(512) void k_mbuild(
    const float* __restrict__ logA, const float* __restrict__ Aim,
    const float* __restrict__ Bp, const float* __restrict__ Cp,
    __hip_bfloat16* __restrict__ Mt)
{
    __shared__ float Klds[8][64];
    const int tid = threadIdx.x, w = tid >> 6, lane = tid & 63;
    const int d = blockIdx.x * 8 + w;
    const int i = d * NST + lane;
    float aa  = expf(logA[i]);
    float wim = Aim[i];
    float mag = expf(-aa);
    float er = mag * cosf(wim), ei = mag * sinf(wim);
    float Br = Bp[2*i], Bi = Bp[2*i+1];
    float Cr = Cp[2*i], Ci = Cp[2*i+1];
    float pr = Cr*Br + Ci*Bi;                 // CB * eA^t (t=0)
    float pi = Cr*Bi - Ci*Br;
    float ar = 1.f, ai = 0.f;                 // eA^t
    __hip_bfloat16* Md = Mt + (size_t)d * 64 * KDIM;
    for (int t = 0; t < 64; ++t) {
        float kv = pr;
        #pragma unroll
        for (int mask = 1; mask < 64; mask <<= 1) kv += __shfl_xor(kv, mask);
        if (lane == 0) Klds[w][t] = kv;
        float npr = er*pr - ei*pi, npi = er*pi + ei*pr;  pr = npr; pi = npi;
        float nar = er*ar - ei*ai, nai = er*ai + ei*ar;  ar = nar; ai = nai;   // eA^{t+1}
        uint u = (uint)f2bf(ar) | ((uint)f2bf(-ai) << 16);
        *(uint*)&Md[(63 - t) * KDIM + 64 + 2 * lane] = u;   // row 64-(t+1)
    }
    __syncthreads();
    for (int r = 0; r < 64; ++r) {
        float v = (lane >= r) ? Klds[w][lane - r] : 0.f;
        Md[r * KDIM + lane] = __float2bfloat16(v);
    }
}

// ---------------- k_scanA: carry pre-scan, record every 64 steps ----------------
// wave = (b,d), lane = state; 8-step group identity (exact); carr[d][b][ch][s]
// packed bf16 (cr | ci<<16): carr[ch] = g[64*(ch+1)], ch = 0..30.
__global__ __launch_bounds__(512) void k_scanA(
    const __hip_bfloat16* __restrict__ xT, const float2* __restrict__ cgrp,
    uint* __restrict__ carr)
{
    const int tid = threadIdx.x, w = tid >> 6, lane = tid & 63;
    const int widx = blockIdx.x * 8 + w;     // 0..2047
    const int b = widx >> 9, d = widx & 511;

    float cr[8], ci[8];
    #pragma unroll
    for (int k = 0; k < 8; ++k) {
        float2 ck = cgrp[k * (DM * NST) + d * NST + lane];
        cr[k] = ck.x; ci[k] = ck.y;
    }
    float2 a8 = cgrp[8 * (DM * NST) + d * NST + lane];
    const float er8 = a8.x, ei8 = a8.y;

    const __hip_bfloat16* xc = xT + ((size_t)d * BATCH + b) * SEQ;
    float gr = 0.f, gi = 0.f;
    float xpre = __bfloat162float(xc[(NCH - 1) * 64 + lane]);   // coalesced 128B

    for (int ch = NCH - 1; ch >= 1; --ch) {
        float xreg = xpre;
        if (ch > 1) xpre = __bfloat162float(xc[(ch - 1) * 64 + lane]);

        #pragma unroll
        for (int gidx = 0; gidx < 8; ++gidx) {
            const int i0 = 56 - gidx * 8;
            float sr = 0.f, si = 0.f;
            #pragma unroll
            for (int k = 0; k < 8; ++k) {
                float xv = __uint_as_float(
                    __builtin_amdgcn_readlane(__float_as_uint(xreg), i0 + k));
                sr = fmaf(cr[k], xv, sr);
                si = fmaf(ci[k], xv, si);
            }
            float nr = fmaf(er8, gr, fmaf(-ei8, gi, sr));
            float ni = fmaf(er8, gi, fmaf( ei8, gr, si));
            gr = nr; gi = ni;
        }
        // g[64*ch] = carry for chunk ch-1
        carr[(((size_t)d * BATCH + b) * (NCH - 1) + (ch - 1)) * 64 + lane] =
            (uint)f2bf(gr) | ((uint)f2bf(gi) << 16);
    }
}

// ---------------- k_gemmY: per-d GEMM  y(64 x 128cols) = M(64x192) * Z(192x128) ----------------
// col = b*32 + ch; Z rows 0..63 = x_chunk (bf16), rows 64+2s/65+2s = cr/ci (bf16).
// Epilogue adds D*x (x read back from staged Z) and stores yT[d][b][l] bf16.
__global__ __launch_bounds__(256) void k_gemmY(
    const __hip_bfloat16* __restrict__ Mt, const __hip_bfloat16* __restrict__ xT,
    const uint* __restrict__ carr, const float* __restrict__ Dp,
    __hip_bfloat16* __restrict__ yT)
{
    __shared__ short Ms[64 * 24 * 8];    // 24 KiB, 16B-chunk XOR-swizzled by row&7
    __shared__ short Zs[128 * 24 * 8];   // 48 KiB, swizzled by col&7
    const int tid = threadIdx.x;
    const int d = blockIdx.x;
    const int w = tid >> 6, lane = tid & 63;
    const int q = lane >> 4, n = lane & 15;

    // stage M_d (coalesced 16B per thread x6)
    {
        const short* Mg = (const short*)(Mt + (size_t)d * 64 * KDIM);
        #pragma unroll
        for (int it = 0; it < 6; ++it) {
            int G = it * 256 + tid;                  // 0..1535
            int row = G / 24, c = G % 24;
            int cs = (c & ~7) | ((c & 7) ^ (row & 7));
            *(short8*)&Ms[(row * 24 + cs) * 8] = *(const short8*)&Mg[G * 8];
        }
    }
    // stage Z x-part: 128 cols x 8 chunks
    {
        #pragma unroll
        for (int it = 0; it < 4; ++it) {
            int id = it * 256 + tid;                 // 0..1023
            int col = id >> 3, ck = id & 7;
            int bb = col >> 5, ch = col & 31;
            short8 v = *(const short8*)&xT[((size_t)d * BATCH + bb) * SEQ + ch * 64 + ck * 8];
            int cs = ck ^ (col & 7);
            *(short8*)&Zs[(col * 24 + cs) * 8] = v;
        }
    }
    // stage Z carry-part: 128 cols x 16 chunks (4 packed states per 16B)
    {
        #pragma unroll
        for (int it = 0; it < 8; ++it) {
            int id = it * 256 + tid;                 // 0..2047
            int col = id >> 4, st = id & 15;
            int bb = col >> 5, ch = col & 31;
            short8 v = {0,0,0,0,0,0,0,0};
            if (ch != 31)
                v = *(const short8*)(carr + (((size_t)d * BATCH + bb) * (NCH-1) + ch) * 64 + st * 4);
            int c = 8 + st;
            int cs = (c & ~7) | ((c & 7) ^ (col & 7));
            *(short8*)&Zs[(col * 24 + cs) * 8] = v;
        }
    }
    __syncthreads();

    f32x4 acc[8];
    #pragma unroll
    for (int nf = 0; nf < 8; ++nf)
        #pragma unroll
        for (int k = 0; k < 4; ++k) acc[nf][k] = 0.f;

    const int arow = w * 16 + n;                     // wave w owns rows 16w..16w+15
    #pragma unroll
    for (int kt = 0; kt < 6; ++kt) {
        int c = kt * 4 + q;
        int csa = (c & ~7) | ((c & 7) ^ (arow & 7));
        short8 af = *(const short8*)&Ms[(arow * 24 + csa) * 8];
        #pragma unroll
        for (int nf = 0; nf < 8; ++nf) {
            int col = nf * 16 + n;
            int csb = (c & ~7) | ((c & 7) ^ (col & 7));
            short8 bfr = *(const short8*)&Zs[(col * 24 + csb) * 8];
            acc[nf] = __builtin_amdgcn_mfma_f32_16x16x32_bf16(af, bfr, acc[nf], 0, 0, 0);
        }
    }

    // epilogue: + D*x (from staged Z), store yT; C/D: row = 4q+reg (in-wave), col = n
    const float Dd = Dp[d];
    const int i0 = w * 16 + q * 4;
    #pragma unroll
    for (int nf = 0; nf < 8; ++nf) {
        int col = nf * 16 + n;
        int bb = col >> 5, ch = col & 31;
        int cx = (i0 >> 3) ^ (col & 7);
        const ushort* zp = (const ushort*)&Zs[(col * 24 + cx) * 8 + (i0 & 7)];
        ushort o[4];
        #pragma unroll
        for (int r = 0; r < 4; ++r)
            o[r] = f2bf(acc[nf][r] + Dd * bf2f(zp[r]));
        *(uint2*)&yT[((size_t)d * BATCH + bb) * SEQ + ch * 64 + i0] = *(uint2*)o;
    }
}

// ---------------- k_gemm_ln: out_proj GEMM + residual + LayerNorm ----------------
// v11: one-time A-panel prefetch (32 KB LDS, stride-520 self-swizzled) removes the
// per-K-step yT gather (round-10 regression: 41.7 us latency-bound, MfmaUtil 3.6%).
// 512 threads = 8 waves, each wave owns 64 output cols.
__global__ __launch_bounds__(512) void k_gemm_ln(
    const __hip_bfloat16* __restrict__ yT, const __hip_bfloat16* __restrict__ Wbf,
    const float* __restrict__ x, const float* __restrict__ bout,
    const float* __restrict__ gamma, const float* __restrict__ beta,
    float* __restrict__ out)
{
    __shared__ short Af[32][520];     // full A panel [l][kd]; 520 = 16B-aligned, bank-spread
    __shared__ short Bs[512][32];     // W tile [o][k], 16B-chunk XOR swizzle (validated)
    __shared__ float red[8][32][2];
    __shared__ float stats[32][2];

    const int tid  = threadIdx.x;
    const int w    = tid >> 6;
    const int lane = tid & 63;
    const int q    = lane >> 4;
    const int m    = lane & 15;
    const int r0   = blockIdx.x * 32;
    const int bq   = r0 >> 11;           // batch index (r0 32-aligned, no straddle)
    const int l0   = r0 & 2047;

    // ---- one-time A panel: yT[kd][bq][l0+lg..+3] -> Af[l][kd]; 8 overlapped loads ----
    {
        const int kdb = tid >> 3, lg = (tid & 7) * 4;
        uint2 u[8];
        #pragma unroll
        for (int j = 0; j < 8; ++j)
            u[j] = *(const uint2*)&yT[((size_t)(j * 64 + kdb) * BATCH + bq) * SEQ + l0 + lg];
        #pragma unroll
        for (int j = 0; j < 8; ++j) {
            int kd = j * 64 + kdb;
            Af[lg + 0][kd] = (short)(u[j].x & 0xffff);
            Af[lg + 1][kd] = (short)(u[j].x >> 16);
            Af[lg + 2][kd] = (short)(u[j].y & 0xffff);
            Af[lg + 3][kd] = (short)(u[j].y >> 16);
        }
    }

    f32x4 acc[2][4];
    #pragma unroll
    for (int a = 0; a < 2; ++a)
        #pragma unroll
        for (int nn = 0; nn < 4; ++nn)
            #pragma unroll
            for (int k = 0; k < 4; ++k) acc[a][nn][k] = 0.f;

    for (int k0 = 0; k0 < DM; k0 += 32) {
        __syncthreads();                  // Bs reuse guard; also makes Af visible (k0=0)
        #pragma unroll
        for (int it = 0; it < 4; ++it) {
            int o = it * 128 + (tid >> 2), j = tid & 3;
            short8 v = *(const short8*)(Wbf + (size_t)o * DM + k0 + j * 8);
            *(short8*)&Bs[o][(j ^ (o & 3)) * 8] = v;
        }
        __syncthreads();

        short8 a0 = *(const short8*)&Af[m][k0 + q * 8];
        short8 a1 = *(const short8*)&Af[16 + m][k0 + q * 8];
        #pragma unroll
        for (int nf = 0; nf < 4; ++nf) {
            int o = w * 64 + nf * 16 + m;
            short8 bb = *(const short8*)&Bs[o][(q ^ (m & 3)) * 8];
            acc[0][nf] = __builtin_amdgcn_mfma_f32_16x16x32_bf16(a0, bb, acc[0][nf], 0, 0, 0);
            acc[1][nf] = __builtin_amdgcn_mfma_f32_16x16x32_bf16(a1, bb, acc[1][nf], 0, 0, 0);
        }
    }

    float bo[4], ga[4], be[4];
    #pragma unroll
    for (int nf = 0; nf < 4; ++nf) {
        int o = w * 64 + nf * 16 + m;
        bo[nf] = bout[o]; ga[nf] = gamma[o]; be[nf] = beta[o];
    }

    float rs[2][4], rq[2][4];
    #pragma unroll
    for (int mf = 0; mf < 2; ++mf)
        #pragma unroll
        for (int i = 0; i < 4; ++i) { rs[mf][i] = 0.f; rq[mf][i] = 0.f; }

    #pragma unroll
    for (int mf = 0; mf < 2; ++mf)
        #pragma unroll
        for (int nf = 0; nf < 4; ++nf) {
            int o = w * 64 + nf * 16 + m;
            #pragma unroll
            for (int i = 0; i < 4; ++i) {
                int row = mf * 16 + q * 4 + i;     // C/D: row=(lane>>4)*4+reg, col=lane&15
                float zv = acc[mf][nf][i] + bo[nf] + x[(size_t)(r0 + row) * DM + o];
                acc[mf][nf][i] = zv;
                rs[mf][i] += zv;
                rq[mf][i] += zv * zv;
            }
        }

    #pragma unroll
    for (int mask = 1; mask < 16; mask <<= 1) {
        #pragma unroll
        for (int mf = 0; mf < 2; ++mf)
            #pragma unroll
            for (int i = 0; i < 4; ++i) {
                rs[mf][i] += __shfl_xor(rs[mf][i], mask);
                rq[mf][i] += __shfl_xor(rq[mf][i], mask);
            }
    }
    if (m == 0) {
        #pragma unroll
        for (int mf = 0; mf < 2; ++mf)
            #pragma unroll
            for (int i = 0; i < 4; ++i) {
                int row = mf * 16 + q * 4 + i;
                red[w][row][0] = rs[mf][i];
                red[w][row][1] = rq[mf][i];
            }
    }
    __syncthreads();
    if (tid < 32) {
        float s = 0.f, sq = 0.f;
        #pragma unroll
        for (int ww = 0; ww < 8; ++ww) { s += red[ww][tid][0]; sq += red[ww][tid][1]; }
        float mu  = s * (1.f / DM);
        float var = sq * (1.f / DM) - mu * mu;
        stats[tid][0] = mu;
        stats[tid][1] = 1.f / sqrtf(var + LN_EPS);
    }
    __syncthreads();

    #pragma unroll
    for (int mf = 0; mf < 2; ++mf)
        #pragma unroll
        for (int i = 0; i < 4; ++i) {
            int row = mf * 16 + q * 4 + i;
            float mu = stats[row][0], rstd = stats[row][1];
            #pragma unroll
            for (int nf = 0; nf < 4; ++nf) {
                int o = w * 64 + nf * 16 + m;
                out[(size_t)(r0 + row) * DM + o] =
                    ga[nf] * (acc[mf][nf][i] - mu) * rstd + be[nf];
            }
        }
}

// ---------------- launcher ----------------
extern "C" void kernel_launch(void* const* d_in, const int* in_sizes, int n_in,
                              void* d_out, int out_size, void* d_ws, size_t ws_size,
                              hipStream_t stream)
{
    const float* x    = (const float*)d_in[0];
    const float* logA = (const float*)d_in[1];
    const float* Aim  = (const float*)d_in[2];
    const float* Bp   = (const float*)d_in[3];
    const float* Cp   = (const float*)d_in[4];
    const float* Dp   = (const float*)d_in[5];
    const float* W    = (const float*)d_in[6];
    const float* bo   = (const float*)d_in[7];
    const float* ga   = (const float*)d_in[8];
    const float* be   = (const float*)d_in[9];

    char* ws = (char*)d_ws;
    __hip_bfloat16* Wbf = (__hip_bfloat16*)ws;                   // 512 KiB @ 0
    float2* cgrp        = (float2*)(ws + (512 << 10));           // 2.36 MiB @ 0.5M
    __hip_bfloat16* xT  = (__hip_bfloat16*)(ws + (3u << 20));    // 8 MiB    @ 3M
    __hip_bfloat16* Mt  = (__hip_bfloat16*)(ws + (11u << 20));   // 12.6 MiB @ 11M
    uint* carr          = (uint*)(ws + (24u << 20));             // 16.25MiB @ 24M
    __hip_bfloat16* yT  = (__hip_bfloat16*)(ws + (41u << 20));   // 8 MiB    @ 41M

    k_xt     <<<BATCH * 32 * 16, 256, 0, stream>>>(x, xT);
    k_pre    <<<(DM * DM + 255) / 256, 256, 0, stream>>>(logA, Aim, Bp, Cp, W, cgrp, Wbf);
    k_mbuild <<<DM / 8, 512, 0, stream>>>(logA, Aim, Bp, Cp, Mt);
    k_scanA  <<<(BATCH * DM) / 8, 512, 0, stream>>>(xT, cgrp, carr);
    k_gemmY  <<<DM, 256, 0, stream>>>(Mt, xT, carr, Dp, yT);
    k_gemm_ln<<<(BATCH * SEQ) / 32, 512, 0, stream>>>(yT, Wbf, x, bo, ga, be, (float*)d_out);
}

// Round 13
// 98.609 us; speedup vs baseline: 1.1032x; 1.0179x over previous
//
#include <hip/hip_runtime.h>
#include <hip/hip_bf16.h>
#include <stdint.h>
#include <stddef.h>

#define BATCH 4
#define SEQ   2048
#define DM    512
#define NST   64
#define LN_EPS 1e-5f
#define NCH   32    // 32 chunks of 64
#define KDIM  192   // 64 x-taps + 128 carry (re,im interleaved)

typedef __attribute__((ext_vector_type(8))) short short8;
typedef __attribute__((ext_vector_type(4))) float f32x4;

__device__ __forceinline__ ushort f2bf(float f) {
    __hip_bfloat16 h = __float2bfloat16(f);
    return *(ushort*)&h;
}
__device__ __forceinline__ float bf2f(ushort u) {
    __hip_bfloat16 h = *(__hip_bfloat16*)&u;
    return __bfloat162float(h);
}

// ---------------- k_prep: fused  x-transpose | constants | M-build ----------------
// blocks [0,2048):    x[b][l][d] f32 -> xT[d][b][l] bf16
// blocks [2048,3072): W->bf16 + cgrp (scanA 8-step group constants)
// blocks [3072,3200): per-d FIR/carry matrix M[64][192] bf16
__global__ __launch_bounds__(256) void k_prep(
    const float* __restrict__ x,
    const float* __restrict__ logA, const float* __restrict__ Aim,
    const float* __restrict__ Bp, const float* __restrict__ Cp,
    const float* __restrict__ W,
    __hip_bfloat16* __restrict__ xT, float2* __restrict__ cgrp,
    __hip_bfloat16* __restrict__ Wbf, __hip_bfloat16* __restrict__ Mt)
{
    __shared__ float smem[64][33];
    const int tid = threadIdx.x;
    const int bid = blockIdx.x;

    if (bid < 2048) {
        const int dt = bid & 15, lt = (bid >> 4) & 31, b = bid >> 9;
        const int l0 = lt * 64, d0 = dt * 32;
        const int dd = tid & 31, lr = tid >> 5;
        #pragma unroll
        for (int it = 0; it < 8; ++it) {
            int ll = it * 8 + lr;
            smem[ll][dd] = x[((size_t)b * SEQ + l0 + ll) * DM + d0 + dd];
        }
        __syncthreads();
        const int dw = tid >> 3, lg = (tid & 7) * 8;
        ushort pk[8];
        #pragma unroll
        for (int i = 0; i < 8; ++i) pk[i] = f2bf(smem[lg + i][dw]);
        *(short8*)&xT[((size_t)(d0 + dw) * BATCH + b) * SEQ + l0 + lg] = *(short8*)pk;
    } else if (bid < 3072) {
        int i = (bid - 2048) * 256 + tid;
        if (i < DM * DM) Wbf[i] = __float2bfloat16(W[i]);
        if (i < DM * NST) {
            float a = expf(logA[i]);
            float wim = Aim[i];
            float mag = expf(-a);
            float er = mag * cosf(wim);
            float ei = mag * sinf(wim);
            float Br = Bp[2*i], Bi = Bp[2*i+1];
            float Cr = Cp[2*i], Ci = Cp[2*i+1];
            float pr = Cr*Br + Ci*Bi;             // conj(C)*B
            float pi = Cr*Bi - Ci*Br;
            #pragma unroll
            for (int k = 0; k < 8; ++k) {
                cgrp[k * (DM * NST) + i] = make_float2(pr, pi);
                float npr = er * pr - ei * pi;
                float npi = er * pi + ei * pr;
                pr = npr; pi = npi;
            }
            float a2r = er*er - ei*ei,     a2i = 2.f*er*ei;
            float a4r = a2r*a2r - a2i*a2i, a4i = 2.f*a2r*a2i;
            float a8r = a4r*a4r - a4i*a4i, a8i = 2.f*a4r*a4i;
            cgrp[8 * (DM * NST) + i] = make_float2(a8r, a8i);
        }
    } else {
        // M[i][j] = K[j-i] (j>=i else 0); M[i][64+2s] = Re(eA_s^(64-i)); M[i][65+2s] = -Im
        float (*Klds)[64] = (float(*)[64])smem;
        const int w = tid >> 6, lane = tid & 63;
        const int d = (bid - 3072) * 4 + w;
        const int i = d * NST + lane;
        float aa  = expf(logA[i]);
        float wim = Aim[i];
        float mag = expf(-aa);
        float er = mag * cosf(wim), ei = mag * sinf(wim);
        float Br = Bp[2*i], Bi = Bp[2*i+1];
        float Cr = Cp[2*i], Ci = Cp[2*i+1];
        float pr = Cr*Br + Ci*Bi;                 // CB * eA^t (t=0)
        float pi = Cr*Bi - Ci*Br;
        float ar = 1.f, ai = 0.f;                 // eA^t
        __hip_bfloat16* Md = Mt + (size_t)d * 64 * KDIM;
        for (int t = 0; t < 64; ++t) {
            float kv = pr;
            #pragma unroll
            for (int mask = 1; mask < 64; mask <<= 1) kv += __shfl_xor(kv, mask);
            if (lane == 0) Klds[w][t] = kv;
            float npr = er*pr - ei*pi, npi = er*pi + ei*pr;  pr = npr; pi = npi;
            float nar = er*ar - ei*ai, nai = er*ai + ei*ar;  ar = nar; ai = nai;
            uint u = (uint)f2bf(ar) | ((uint)f2bf(-ai) << 16);
            *(uint*)&Md[(63 - t) * KDIM + 64 + 2 * lane] = u;   // row 64-(t+1)
        }
        __syncthreads();
        for (int r = 0; r < 64; ++r) {
            float v = (lane >= r) ? Klds[w][lane - r] : 0.f;
            Md[r * KDIM + lane] = __float2bfloat16(v);
        }
    }
}

// ---------------- k_scanA: carry pre-scan, record every 64 steps ----------------
__global__ __launch_bounds__(512) void k_scanA(
    const __hip_bfloat16* __restrict__ xT, const float2* __restrict__ cgrp,
    uint* __restrict__ carr)
{
    const int tid = threadIdx.x, w = tid >> 6, lane = tid & 63;
    const int widx = blockIdx.x * 8 + w;     // 0..2047
    const int b = widx >> 9, d = widx & 511;

    float cr[8], ci[8];
    #pragma unroll
    for (int k = 0; k < 8; ++k) {
        float2 ck = cgrp[k * (DM * NST) + d * NST + lane];
        cr[k] = ck.x; ci[k] = ck.y;
    }
    float2 a8 = cgrp[8 * (DM * NST) + d * NST + lane];
    const float er8 = a8.x, ei8 = a8.y;

    const __hip_bfloat16* xc = xT + ((size_t)d * BATCH + b) * SEQ;
    float gr = 0.f, gi = 0.f;
    float xpre = __bfloat162float(xc[(NCH - 1) * 64 + lane]);

    for (int ch = NCH - 1; ch >= 1; --ch) {
        float xreg = xpre;
        if (ch > 1) xpre = __bfloat162float(xc[(ch - 1) * 64 + lane]);

        #pragma unroll
        for (int gidx = 0; gidx < 8; ++gidx) {
            const int i0 = 56 - gidx * 8;
            float sr = 0.f, si = 0.f;
            #pragma unroll
            for (int k = 0; k < 8; ++k) {
                float xv = __uint_as_float(
                    __builtin_amdgcn_readlane(__float_as_uint(xreg), i0 + k));
                sr = fmaf(cr[k], xv, sr);
                si = fmaf(ci[k], xv, si);
            }
            float nr = fmaf(er8, gr, fmaf(-ei8, gi, sr));
            float ni = fmaf(er8, gi, fmaf( ei8, gr, si));
            gr = nr; gi = ni;
        }
        carr[(((size_t)d * BATCH + b) * (NCH - 1) + (ch - 1)) * 64 + lane] =
            (uint)f2bf(gr) | ((uint)f2bf(gi) << 16);
    }
}

// ---------------- k_gemmY: per-d GEMM  y(64 x 128cols) = M(64x192) * Z(192x128) ----------------
__global__ __launch_bounds__(256) void k_gemmY(
    const __hip_bfloat16* __restrict__ Mt, const __hip_bfloat16* __restrict__ xT,
    const uint* __restrict__ carr, const float* __restrict__ Dp,
    __hip_bfloat16* __restrict__ yT)
{
    __shared__ short Ms[64 * 24 * 8];    // 24 KiB, 16B-chunk XOR-swizzled by row&7
    __shared__ short Zs[128 * 24 * 8];   // 48 KiB, swizzled by col&7
    const int tid = threadIdx.x;
    const int d = blockIdx.x;
    const int w = tid >> 6, lane = tid & 63;
    const int q = lane >> 4, n = lane & 15;

    {
        const short* Mg = (const short*)(Mt + (size_t)d * 64 * KDIM);
        #pragma unroll
        for (int it = 0; it < 6; ++it) {
            int G = it * 256 + tid;
            int row = G / 24, c = G % 24;
            int cs = (c & ~7) | ((c & 7) ^ (row & 7));
            *(short8*)&Ms[(row * 24 + cs) * 8] = *(const short8*)&Mg[G * 8];
        }
    }
    {
        #pragma unroll
        for (int it = 0; it < 4; ++it) {
            int id = it * 256 + tid;
            int col = id >> 3, ck = id & 7;
            int bb = col >> 5, ch = col & 31;
            short8 v = *(const short8*)&xT[((size_t)d * BATCH + bb) * SEQ + ch * 64 + ck * 8];
            int cs = ck ^ (col & 7);
            *(short8*)&Zs[(col * 24 + cs) * 8] = v;
        }
    }
    {
        #pragma unroll
        for (int it = 0; it < 8; ++it) {
            int id = it * 256 + tid;
            int col = id >> 4, st = id & 15;
            int bb = col >> 5, ch = col & 31;
            short8 v = {0,0,0,0,0,0,0,0};
            if (ch != 31)
                v = *(const short8*)(carr + (((size_t)d * BATCH + bb) * (NCH-1) + ch) * 64 + st * 4);
            int c = 8 + st;
            int cs = (c & ~7) | ((c & 7) ^ (col & 7));
            *(short8*)&Zs[(col * 24 + cs) * 8] = v;
        }
    }
    __syncthreads();

    f32x4 acc[8];
    #pragma unroll
    for (int nf = 0; nf < 8; ++nf)
        #pragma unroll
        for (int k = 0; k < 4; ++k) acc[nf][k] = 0.f;

    const int arow = w * 16 + n;
    #pragma unroll
    for (int kt = 0; kt < 6; ++kt) {
        int c = kt * 4 + q;
        int csa = (c & ~7) | ((c & 7) ^ (arow & 7));
        short8 af = *(const short8*)&Ms[(arow * 24 + csa) * 8];
        #pragma unroll
        for (int nf = 0; nf < 8; ++nf) {
            int col = nf * 16 + n;
            int csb = (c & ~7) | ((c & 7) ^ (col & 7));
            short8 bfr = *(const short8*)&Zs[(col * 24 + csb) * 8];
            acc[nf] = __builtin_amdgcn_mfma_f32_16x16x32_bf16(af, bfr, acc[nf], 0, 0, 0);
        }
    }

    const float Dd = Dp[d];
    const int i0 = w * 16 + q * 4;
    #pragma unroll
    for (int nf = 0; nf < 8; ++nf) {
        int col = nf * 16 + n;
        int bb = col >> 5, ch = col & 31;
        int cx = (i0 >> 3) ^ (col & 7);
        const ushort* zp = (const ushort*)&Zs[(col * 24 + cx) * 8 + (i0 & 7)];
        ushort o[4];
        #pragma unroll
        for (int r = 0; r < 4; ++r)
            o[r] = f2bf(acc[nf][r] + Dd * bf2f(zp[r]));
        *(uint2*)&yT[((size_t)d * BATCH + bb) * SEQ + ch * 64 + i0] = *(uint2*)o;
    }
}

// ---------------- k_yt: transpose yT[d][b][l] -> ybf[b][l][d] (bf16) ----------------
__global__ __launch_bounds__(256) void k_yt(
    const __hip_bfloat16* __restrict__ yT, __hip_bfloat16* __restrict__ ybf)
{
    __shared__ ushort t[64][34];
    const int tid = threadIdx.x, bid = blockIdx.x;
    const int dt = bid & 15, lt = (bid >> 4) & 31, b = bid >> 9;
    const int l0 = lt * 64, d0 = dt * 32;

    const int dw = tid >> 3, lg = (tid & 7) * 8;
    short8 v = *(const short8*)&yT[((size_t)(d0 + dw) * BATCH + b) * SEQ + l0 + lg];
    #pragma unroll
    for (int i = 0; i < 8; ++i) t[lg + i][dw] = (ushort)v[i];
    __syncthreads();

    const int row = tid >> 2, dg = (tid & 3) * 8;
    ushort pk[8];
    #pragma unroll
    for (int i = 0; i < 8; ++i) pk[i] = t[row][dg + i];
    *(short8*)&ybf[((size_t)b * SEQ + l0 + row) * DM + d0 + dg] = *(short8*)pk;
}

// ---------------- k_gemm_ln: out_proj GEMM + residual + LayerNorm (round-9 proven) ----------------
__global__ __launch_bounds__(256) void k_gemm_ln(
    const __hip_bfloat16* __restrict__ ybf, const __hip_bfloat16* __restrict__ Wbf,
    const float* __restrict__ x, const float* __restrict__ bout,
    const float* __restrict__ gamma, const float* __restrict__ beta,
    float* __restrict__ out)
{
    __shared__ short As[32][32];      // y tile [row][k], 16B-chunk XOR swizzle
    __shared__ short Bs[512][32];     // W tile [o][k],   16B-chunk XOR swizzle
    __shared__ float red[4][32][2];
    __shared__ float stats[32][2];

    const int tid  = threadIdx.x;
    const int w    = tid >> 6;
    const int lane = tid & 63;
    const int q    = lane >> 4;
    const int m    = lane & 15;
    const int r0   = blockIdx.x * 32;

    f32x4 acc[2][8];
    #pragma unroll
    for (int a = 0; a < 2; ++a)
        #pragma unroll
        for (int n = 0; n < 8; ++n)
            #pragma unroll
            for (int k = 0; k < 4; ++k) acc[a][n][k] = 0.f;

    for (int k0 = 0; k0 < DM; k0 += 32) {
        __syncthreads();
        if (tid < 128) {
            int row = tid >> 2, j = tid & 3;
            short8 v = *(const short8*)(ybf + (size_t)(r0 + row) * DM + k0 + j * 8);
            *(short8*)&As[row][(j ^ (row & 3)) * 8] = v;
        }
        #pragma unroll
        for (int it = 0; it < 8; ++it) {
            int o = it * 64 + (tid >> 2), j = tid & 3;
            short8 v = *(const short8*)(Wbf + (size_t)o * DM + k0 + j * 8);
            *(short8*)&Bs[o][(j ^ (o & 3)) * 8] = v;
        }
        __syncthreads();

        short8 a0 = *(const short8*)&As[m][(q ^ (m & 3)) * 8];
        short8 a1 = *(const short8*)&As[16 + m][(q ^ (m & 3)) * 8];
        #pragma unroll
        for (int nf = 0; nf < 8; ++nf) {
            int o = w * 128 + nf * 16 + m;
            short8 bb = *(const short8*)&Bs[o][(q ^ (m & 3)) * 8];
            acc[0][nf] = __builtin_amdgcn_mfma_f32_16x16x32_bf16(a0, bb, acc[0][nf], 0, 0, 0);
            acc[1][nf] = __builtin_amdgcn_mfma_f32_16x16x32_bf16(a1, bb, acc[1][nf], 0, 0, 0);
        }
    }

    float bo[8], ga[8], be[8];
    #pragma unroll
    for (int nf = 0; nf < 8; ++nf) {
        int o = w * 128 + nf * 16 + m;
        bo[nf] = bout[o]; ga[nf] = gamma[o]; be[nf] = beta[o];
    }

    float rs[2][4], rq[2][4];
    #pragma unroll
    for (int mf = 0; mf < 2; ++mf)
        #pragma unroll
        for (int i = 0; i < 4; ++i) { rs[mf][i] = 0.f; rq[mf][i] = 0.f; }

    #pragma unroll
    for (int mf = 0; mf < 2; ++mf)
        #pragma unroll
        for (int nf = 0; nf < 8; ++nf) {
            int o = w * 128 + nf * 16 + m;
            #pragma unroll
            for (int i = 0; i < 4; ++i) {
                int row = mf * 16 + q * 4 + i;     // C/D: row=(lane>>4)*4+reg, col=lane&15
                float zv = acc[mf][nf][i] + bo[nf] + x[(size_t)(r0 + row) * DM + o];
                acc[mf][nf][i] = zv;
                rs[mf][i] += zv;
                rq[mf][i] += zv * zv;
            }
        }

    #pragma unroll
    for (int mask = 1; mask < 16; mask <<= 1) {
        #pragma unroll
        for (int mf = 0; mf < 2; ++mf)
            #pragma unroll
            for (int i = 0; i < 4; ++i) {
                rs[mf][i] += __shfl_xor(rs[mf][i], mask);
                rq[mf][i] += __shfl_xor(rq[mf][i], mask);
            }
    }
    if (m == 0) {
        #pragma unroll
        for (int mf = 0; mf < 2; ++mf)
            #pragma unroll
            for (int i = 0; i < 4; ++i) {
                int row = mf * 16 + q * 4 + i;
                red[w][row][0] = rs[mf][i];
                red[w][row][1] = rq[mf][i];
            }
    }
    __syncthreads();
    if (tid < 32) {
        float s = 0.f, sq = 0.f;
        #pragma unroll
        for (int ww = 0; ww < 4; ++ww) { s += red[ww][tid][0]; sq += red[ww][tid][1]; }
        float mu  = s * (1.f / DM);
        float var = sq * (1.f / DM) - mu * mu;
        stats[tid][0] = mu;
        stats[tid][1] = 1.f / sqrtf(var + LN_EPS);
    }
    __syncthreads();

    #pragma unroll
    for (int mf = 0; mf < 2; ++mf)
        #pragma unroll
        for (int i = 0; i < 4; ++i) {
            int row = mf * 16 + q * 4 + i;
            float mu = stats[row][0], rstd = stats[row][1];
            #pragma unroll
            for (int nf = 0; nf < 8; ++nf) {
                int o = w * 128 + nf * 16 + m;
                out[(size_t)(r0 + row) * DM + o] =
                    ga[nf] * (acc[mf][nf][i] - mu) * rstd + be[nf];
            }
        }
}

// ---------------- launcher ----------------
extern "C" void kernel_launch(void* const* d_in, const int* in_sizes, int n_in,
                              void* d_out, int out_size, void* d_ws, size_t ws_size,
                              hipStream_t stream)
{
    const float* x    = (const float*)d_in[0];
    const float* logA = (const float*)d_in[1];
    const float* Aim  = (const float*)d_in[2];
    const float* Bp   = (const float*)d_in[3];
    const float* Cp   = (const float*)d_in[4];
    const float* Dp   = (const float*)d_in[5];
    const float* W    = (const float*)d_in[6];
    const float* bo   = (const float*)d_in[7];
    const float* ga   = (const float*)d_in[8];
    const float* be   = (const float*)d_in[9];

    char* ws = (char*)d_ws;
    __hip_bfloat16* Wbf = (__hip_bfloat16*)ws;                   // 512 KiB @ 0
    float2* cgrp        = (float2*)(ws + (512 << 10));           // 2.36 MiB @ 0.5M
    __hip_bfloat16* xT  = (__hip_bfloat16*)(ws + (3u << 20));    // 8 MiB    @ 3M
    __hip_bfloat16* Mt  = (__hip_bfloat16*)(ws + (11u << 20));   // 12.6 MiB @ 11M
    uint* carr          = (uint*)(ws + (24u << 20));             // 16.25MiB @ 24M
    __hip_bfloat16* yT  = (__hip_bfloat16*)(ws + (41u << 20));   // 8 MiB    @ 41M
    __hip_bfloat16* ybf = (__hip_bfloat16*)(ws + (49u << 20));   // 8 MiB    @ 49M

    k_prep   <<<3200, 256, 0, stream>>>(x, logA, Aim, Bp, Cp, W, xT, cgrp, Wbf, Mt);
    k_scanA  <<<(BATCH * DM) / 8, 512, 0, stream>>>(xT, cgrp, carr);
    k_gemmY  <<<DM, 256, 0, stream>>>(Mt, xT, carr, Dp, yT);
    k_yt     <<<BATCH * 32 * 16, 256, 0, stream>>>(yT, ybf);
    k_gemm_ln<<<(BATCH * SEQ) / 32, 256, 0, stream>>>(ybf, Wbf, x, bo, ga, be, (float*)d_out);
}

// Round 17
// 91.649 us; speedup vs baseline: 1.1870x; 1.0759x over previous
//
#include <hip/hip_runtime.h>
#include <hip/hip_bf16.h>
#include <stdint.h>
#include <stddef.h>

#define BATCH 4
#define SEQ   2048
#define DM    512
#define NST   64
#define LN_EPS 1e-5f
#define NCH   32    // 32 chunks of 64
#define KDIM  192   // 64 x-taps + 128 carry (re,im interleaved)

typedef __attribute__((ext_vector_type(8))) short short8;
typedef __attribute__((ext_vector_type(4))) float f32x4;

__device__ __forceinline__ ushort f2bf(float f) {
    __hip_bfloat16 h = __float2bfloat16(f);
    return *(ushort*)&h;
}
__device__ __forceinline__ float bf2f(ushort u) {
    __hip_bfloat16 h = *(__hip_bfloat16*)&u;
    return __bfloat162float(h);
}

// ---------------- k_prep: fused  x-transpose | constants | M-build ----------------
// blocks [0,2048):    x[b][l][d] f32 -> xT[d][b][l] bf16
// blocks [2048,3072): W->bf16 + cgrp (scanA 8-step group constants)
// blocks [3072,3200): per-d FIR/carry matrix M[64][192] bf16
__global__ __launch_bounds__(256) void k_prep(
    const float* __restrict__ x,
    const float* __restrict__ logA, const float* __restrict__ Aim,
    const float* __restrict__ Bp, const float* __restrict__ Cp,
    const float* __restrict__ W,
    __hip_bfloat16* __restrict__ xT, float2* __restrict__ cgrp,
    __hip_bfloat16* __restrict__ Wbf, __hip_bfloat16* __restrict__ Mt)
{
    __shared__ float smem[64][33];
    const int tid = threadIdx.x;
    const int bid = blockIdx.x;

    if (bid < 2048) {
        const int dt = bid & 15, lt = (bid >> 4) & 31, b = bid >> 9;
        const int l0 = lt * 64, d0 = dt * 32;
        const int dd = tid & 31, lr = tid >> 5;
        #pragma unroll
        for (int it = 0; it < 8; ++it) {
            int ll = it * 8 + lr;
            smem[ll][dd] = x[((size_t)b * SEQ + l0 + ll) * DM + d0 + dd];
        }
        __syncthreads();
        const int dw = tid >> 3, lg = (tid & 7) * 8;
        ushort pk[8];
        #pragma unroll
        for (int i = 0; i < 8; ++i) pk[i] = f2bf(smem[lg + i][dw]);
        *(short8*)&xT[((size_t)(d0 + dw) * BATCH + b) * SEQ + l0 + lg] = *(short8*)pk;
    } else if (bid < 3072) {
        int i = (bid - 2048) * 256 + tid;
        if (i < DM * DM) Wbf[i] = __float2bfloat16(W[i]);
        if (i < DM * NST) {
            float a = expf(logA[i]);
            float wim = Aim[i];
            float mag = expf(-a);
            float er = mag * cosf(wim);
            float ei = mag * sinf(wim);
            float Br = Bp[2*i], Bi = Bp[2*i+1];
            float Cr = Cp[2*i], Ci = Cp[2*i+1];
            float pr = Cr*Br + Ci*Bi;             // conj(C)*B
            float pi = Cr*Bi - Ci*Br;
            #pragma unroll
            for (int k = 0; k < 8; ++k) {
                cgrp[k * (DM * NST) + i] = make_float2(pr, pi);
                float npr = er * pr - ei * pi;
                float npi = er * pi + ei * pr;
                pr = npr; pi = npi;
            }
            float a2r = er*er - ei*ei,     a2i = 2.f*er*ei;
            float a4r = a2r*a2r - a2i*a2i, a4i = 2.f*a2r*a2i;
            float a8r = a4r*a4r - a4i*a4i, a8i = 2.f*a4r*a4i;
            cgrp[8 * (DM * NST) + i] = make_float2(a8r, a8i);
        }
    } else {
        // M[i][j] = K[j-i] (j>=i else 0); M[i][64+2s] = Re(eA_s^(64-i)); M[i][65+2s] = -Im
        float (*Klds)[64] = (float(*)[64])smem;
        const int w = tid >> 6, lane = tid & 63;
        const int d = (bid - 3072) * 4 + w;
        const int i = d * NST + lane;
        float aa  = expf(logA[i]);
        float wim = Aim[i];
        float mag = expf(-aa);
        float er = mag * cosf(wim), ei = mag * sinf(wim);
        float Br = Bp[2*i], Bi = Bp[2*i+1];
        float Cr = Cp[2*i], Ci = Cp[2*i+1];
        float pr = Cr*Br + Ci*Bi;                 // CB * eA^t (t=0)
        float pi = Cr*Bi - Ci*Br;
        float ar = 1.f, ai = 0.f;                 // eA^t
        __hip_bfloat16* Md = Mt + (size_t)d * 64 * KDIM;
        for (int t = 0; t < 64; ++t) {
            float kv = pr;
            #pragma unroll
            for (int mask = 1; mask < 64; mask <<= 1) kv += __shfl_xor(kv, mask);
            if (lane == 0) Klds[w][t] = kv;
            float npr = er*pr - ei*pi, npi = er*pi + ei*pr;  pr = npr; pi = npi;
            float nar = er*ar - ei*ai, nai = er*ai + ei*ar;  ar = nar; ai = nai;
            uint u = (uint)f2bf(ar) | ((uint)f2bf(-ai) << 16);
            *(uint*)&Md[(63 - t) * KDIM + 64 + 2 * lane] = u;   // row 64-(t+1)
        }
        __syncthreads();
        for (int r = 0; r < 64; ++r) {
            float v = (lane >= r) ? Klds[w][lane - r] : 0.f;
            Md[r * KDIM + lane] = __float2bfloat16(v);
        }
    }
}

// ---------------- k_scanA: carry pre-scan, record every 64 steps ----------------
__global__ __launch_bounds__(512) void k_scanA(
    const __hip_bfloat16* __restrict__ xT, const float2* __restrict__ cgrp,
    uint* __restrict__ carr)
{
    const int tid = threadIdx.x, w = tid >> 6, lane = tid & 63;
    const int widx = blockIdx.x * 8 + w;     // 0..2047
    const int b = widx >> 9, d = widx & 511;

    float cr[8], ci[8];
    #pragma unroll
    for (int k = 0; k < 8; ++k) {
        float2 ck = cgrp[k * (DM * NST) + d * NST + lane];
        cr[k] = ck.x; ci[k] = ck.y;
    }
    float2 a8 = cgrp[8 * (DM * NST) + d * NST + lane];
    const float er8 = a8.x, ei8 = a8.y;

    const __hip_bfloat16* xc = xT + ((size_t)d * BATCH + b) * SEQ;
    float gr = 0.f, gi = 0.f;
    float xpre = __bfloat162float(xc[(NCH - 1) * 64 + lane]);

    for (int ch = NCH - 1; ch >= 1; --ch) {
        float xreg = xpre;
        if (ch > 1) xpre = __bfloat162float(xc[(ch - 1) * 64 + lane]);

        #pragma unroll
        for (int gidx = 0; gidx < 8; ++gidx) {
            const int i0 = 56 - gidx * 8;
            float sr = 0.f, si = 0.f;
            #pragma unroll
            for (int k = 0; k < 8; ++k) {
                float xv = __uint_as_float(
                    __builtin_amdgcn_readlane(__float_as_uint(xreg), i0 + k));
                sr = fmaf(cr[k], xv, sr);
                si = fmaf(ci[k], xv, si);
            }
            float nr = fmaf(er8, gr, fmaf(-ei8, gi, sr));
            float ni = fmaf(er8, gi, fmaf( ei8, gr, si));
            gr = nr; gi = ni;
        }
        carr[(((size_t)d * BATCH + b) * (NCH - 1) + (ch - 1)) * 64 + lane] =
            (uint)f2bf(gr) | ((uint)f2bf(gi) << 16);
    }
}

// ---------------- k_gemmY: per-d GEMM  y(64 x 128cols) = M(64x192) * Z(192x128) ----------------
__global__ __launch_bounds__(256) void k_gemmY(
    const __hip_bfloat16* __restrict__ Mt, const __hip_bfloat16* __restrict__ xT,
    const uint* __restrict__ carr, const float* __restrict__ Dp,
    __hip_bfloat16* __restrict__ yT)
{
    __shared__ short Ms[64 * 24 * 8];    // 24 KiB, 16B-chunk XOR-swizzled by row&7
    __shared__ short Zs[128 * 24 * 8];   // 48 KiB, swizzled by col&7
    const int tid = threadIdx.x;
    const int d = blockIdx.x;
    const int w = tid >> 6, lane = tid & 63;
    const int q = lane >> 4, n = lane & 15;

    {
        const short* Mg = (const short*)(Mt + (size_t)d * 64 * KDIM);
        #pragma unroll
        for (int it = 0; it < 6; ++it) {
            int G = it * 256 + tid;
            int row = G / 24, c = G % 24;
            int cs = (c & ~7) | ((c & 7) ^ (row & 7));
            *(short8*)&Ms[(row * 24 + cs) * 8] = *(const short8*)&Mg[G * 8];
        }
    }
    {
        #pragma unroll
        for (int it = 0; it < 4; ++it) {
            int id = it * 256 + tid;
            int col = id >> 3, ck = id & 7;
            int bb = col >> 5, ch = col & 31;
            short8 v = *(const short8*)&xT[((size_t)d * BATCH + bb) * SEQ + ch * 64 + ck * 8];
            int cs = ck ^ (col & 7);
            *(short8*)&Zs[(col * 24 + cs) * 8] = v;
        }
    }
    {
        #pragma unroll
        for (int it = 0; it < 8; ++it) {
            int id = it * 256 + tid;
            int col = id >> 4, st = id & 15;
            int bb = col >> 5, ch = col & 31;
            short8 v = {0,0,0,0,0,0,0,0};
            if (ch != 31)
                v = *(const short8*)(carr + (((size_t)d * BATCH + bb) * (NCH-1) + ch) * 64 + st * 4);
            int c = 8 + st;
            int cs = (c & ~7) | ((c & 7) ^ (col & 7));
            *(short8*)&Zs[(col * 24 + cs) * 8] = v;
        }
    }
    __syncthreads();

    f32x4 acc[8];
    #pragma unroll
    for (int nf = 0; nf < 8; ++nf)
        #pragma unroll
        for (int k = 0; k < 4; ++k) acc[nf][k] = 0.f;

    const int arow = w * 16 + n;
    #pragma unroll
    for (int kt = 0; kt < 6; ++kt) {
        int c = kt * 4 + q;
        int csa = (c & ~7) | ((c & 7) ^ (arow & 7));
        short8 af = *(const short8*)&Ms[(arow * 24 + csa) * 8];
        #pragma unroll
        for (int nf = 0; nf < 8; ++nf) {
            int col = nf * 16 + n;
            int csb = (c & ~7) | ((c & 7) ^ (col & 7));
            short8 bfr = *(const short8*)&Zs[(col * 24 + csb) * 8];
            acc[nf] = __builtin_amdgcn_mfma_f32_16x16x32_bf16(af, bfr, acc[nf], 0, 0, 0);
        }
    }

    const float Dd = Dp[d];
    const int i0 = w * 16 + q * 4;
    #pragma unroll
    for (int nf = 0; nf < 8; ++nf) {
        int col = nf * 16 + n;
        int bb = col >> 5, ch = col & 31;
        int cx = (i0 >> 3) ^ (col & 7);
        const ushort* zp = (const ushort*)&Zs[(col * 24 + cx) * 8 + (i0 & 7)];
        ushort o[4];
        #pragma unroll
        for (int r = 0; r < 4; ++r)
            o[r] = f2bf(acc[nf][r] + Dd * bf2f(zp[r]));
        *(uint2*)&yT[((size_t)d * BATCH + bb) * SEQ + ch * 64 + i0] = *(uint2*)o;
    }
}

// ---------------- k_yt: transpose yT[d][b][l] -> ybf[b][l][d] (bf16) ----------------
__global__ __launch_bounds__(256) void k_yt(
    const __hip_bfloat16* __restrict__ yT, __hip_bfloat16* __restrict__ ybf)
{
    __shared__ ushort t[64][34];
    const int tid = threadIdx.x, bid = blockIdx.x;
    const int dt = bid & 15, lt = (bid >> 4) & 31, b = bid >> 9;
    const int l0 = lt * 64, d0 = dt * 32;

    const int dw = tid >> 3, lg = (tid & 7) * 8;
    short8 v = *(const short8*)&yT[((size_t)(d0 + dw) * BATCH + b) * SEQ + l0 + lg];
    #pragma unroll
    for (int i = 0; i < 8; ++i) t[lg + i][dw] = (ushort)v[i];
    __syncthreads();

    const int row = tid >> 2, dg = (tid & 3) * 8;
    ushort pk[8];
    #pragma unroll
    for (int i = 0; i < 8; ++i) pk[i] = t[row][dg + i];
    *(short8*)&ybf[((size_t)b * SEQ + l0 + row) * DM + d0 + dg] = *(short8*)pk;
}

// ---------------- k_gemm_ln v13b: one-time A panel (FIXED staging) + dbuf reg-staged B ----------------
// Round-14 bug: A-panel staging covered only k<256 (2 its of row=i>>5,seg=i&31).
// Fixed: 4 its of row=i>>6, seg=i&63 -> full 32x512 panel.
__global__ __launch_bounds__(512) void k_gemm_ln(
    const __hip_bfloat16* __restrict__ ybf, const __hip_bfloat16* __restrict__ Wbf,
    const float* __restrict__ x, const float* __restrict__ bout,
    const float* __restrict__ gamma, const float* __restrict__ beta,
    float* __restrict__ out)
{
    __shared__ short Af[32][520];     // full A panel [l][kd]; stride 520 -> 2-way banks on frag read
    __shared__ short Bs[512][32];     // W tile [o][k], 16B-chunk XOR swizzle (validated)
    __shared__ float red[8][32][2];
    __shared__ float stats[32][2];

    const int tid  = threadIdx.x;
    const int w    = tid >> 6;
    const int lane = tid & 63;
    const int q    = lane >> 4;
    const int m    = lane & 15;
    const int r0   = blockIdx.x * 32;

    // ---- one-time A panel (32 rows x 512 k = 2048 x 16B), 4 x 16B per thread, coalesced ----
    #pragma unroll
    for (int it = 0; it < 4; ++it) {
        int i = it * 512 + tid;
        int row = i >> 6, seg = i & 63;
        short8 v = *(const short8*)(ybf + (size_t)(r0 + row) * DM + seg * 8);
        *(short8*)&Af[row][seg * 8] = v;
    }

    // ---- B tile staging: 512 o x 32 k per step; 4 x 16B per thread ----
    short8 nb0, nb1, nb2, nb3;
    const int ob = tid >> 2, jb = tid & 3;
    const int js = (jb ^ (ob & 3)) * 8;
    #define LOADB(k0) { \
        nb0 = *(const short8*)(Wbf + (size_t)(ob      ) * DM + (k0) + jb * 8); \
        nb1 = *(const short8*)(Wbf + (size_t)(ob + 128) * DM + (k0) + jb * 8); \
        nb2 = *(const short8*)(Wbf + (size_t)(ob + 256) * DM + (k0) + jb * 8); \
        nb3 = *(const short8*)(Wbf + (size_t)(ob + 384) * DM + (k0) + jb * 8); }
    #define WRITEB() { \
        *(short8*)&Bs[ob      ][js] = nb0; \
        *(short8*)&Bs[ob + 128][js] = nb1; \
        *(short8*)&Bs[ob + 256][js] = nb2; \
        *(short8*)&Bs[ob + 384][js] = nb3; }

    LOADB(0);
    WRITEB();
    LOADB(32);
    __syncthreads();

    f32x4 acc[2][4];
    #pragma unroll
    for (int a = 0; a < 2; ++a)
        #pragma unroll
        for (int nn = 0; nn < 4; ++nn)
            #pragma unroll
            for (int k = 0; k < 4; ++k) acc[a][nn][k] = 0.f;

    for (int k = 0; k < 16; ++k) {
        const int k0 = k * 32;
        short8 a0 = *(const short8*)&Af[m][k0 + q * 8];
        short8 a1 = *(const short8*)&Af[16 + m][k0 + q * 8];
        #pragma unroll
        for (int nf = 0; nf < 4; ++nf) {
            int o = w * 64 + nf * 16 + m;        // o&3 == m&3
            short8 bb = *(const short8*)&Bs[o][(q ^ (m & 3)) * 8];
            acc[0][nf] = __builtin_amdgcn_mfma_f32_16x16x32_bf16(a0, bb, acc[0][nf], 0, 0, 0);
            acc[1][nf] = __builtin_amdgcn_mfma_f32_16x16x32_bf16(a1, bb, acc[1][nf], 0, 0, 0);
        }
        __syncthreads();                          // all waves done reading Bs
        if (k < 15) {
            WRITEB();                             // B_{k+1} regs -> LDS
            if (k < 14) LOADB((k + 2) * 32);      // issue B_{k+2}; lands during next compute
            __syncthreads();                      // Bs ready
        }
    }
    #undef LOADB
    #undef WRITEB

    // ---- epilogue: +bias, +x residual, row mean/var, normalize ----
    float bo[4], ga[4], be[4];
    #pragma unroll
    for (int nf = 0; nf < 4; ++nf) {
        int o = w * 64 + nf * 16 + m;
        bo[nf] = bout[o]; ga[nf] = gamma[o]; be[nf] = beta[o];
    }

    float rs[2][4], rq[2][4];
    #pragma unroll
    for (int mf = 0; mf < 2; ++mf)
        #pragma unroll
        for (int i = 0; i < 4; ++i) { rs[mf][i] = 0.f; rq[mf][i] = 0.f; }

    #pragma unroll
    for (int mf = 0; mf < 2; ++mf)
        #pragma unroll
        for (int nf = 0; nf < 4; ++nf) {
            int o = w * 64 + nf * 16 + m;
            #pragma unroll
            for (int i = 0; i < 4; ++i) {
                int row = mf * 16 + q * 4 + i;    // C/D: row=(lane>>4)*4+reg, col=lane&15
                float zv = acc[mf][nf][i] + bo[nf] + x[(size_t)(r0 + row) * DM + o];
                acc[mf][nf][i] = zv;
                rs[mf][i] += zv;
                rq[mf][i] += zv * zv;
            }
        }

    #pragma unroll
    for (int mask = 1; mask < 16; mask <<= 1) {
        #pragma unroll
        for (int mf = 0; mf < 2; ++mf)
            #pragma unroll
            for (int i = 0; i < 4; ++i) {
                rs[mf][i] += __shfl_xor(rs[mf][i], mask);
                rq[mf][i] += __shfl_xor(rq[mf][i], mask);
            }
    }
    if (m == 0) {
        #pragma unroll
        for (int mf = 0; mf < 2; ++mf)
            #pragma unroll
            for (int i = 0; i < 4; ++i) {
                int row = mf * 16 + q * 4 + i;
                red[w][row][0] = rs[mf][i];
                red[w][row][1] = rq[mf][i];
            }
    }
    __syncthreads();
    if (tid < 32) {
        float s = 0.f, sq = 0.f;
        #pragma unroll
        for (int ww = 0; ww < 8; ++ww) { s += red[ww][tid][0]; sq += red[ww][tid][1]; }
        float mu  = s * (1.f / DM);
        float var = sq * (1.f / DM) - mu * mu;
        stats[tid][0] = mu;
        stats[tid][1] = 1.f / sqrtf(var + LN_EPS);
    }
    __syncthreads();

    #pragma unroll
    for (int mf = 0; mf < 2; ++mf)
        #pragma unroll
        for (int i = 0; i < 4; ++i) {
            int row = mf * 16 + q * 4 + i;
            float mu = stats[row][0], rstd = stats[row][1];
            #pragma unroll
            for (int nf = 0; nf < 4; ++nf) {
                int o = w * 64 + nf * 16 + m;
                out[(size_t)(r0 + row) * DM + o] =
                    ga[nf] * (acc[mf][nf][i] - mu) * rstd + be[nf];
            }
        }
}

// ---------------- launcher ----------------
extern "C" void kernel_launch(void* const* d_in, const int* in_sizes, int n_in,
                              void* d_out, int out_size, void* d_ws, size_t ws_size,
                              hipStream_t stream)
{
    const float* x    = (const float*)d_in[0];
    const float* logA = (const float*)d_in[1];
    const float* Aim  = (const float*)d_in[2];
    const float* Bp   = (const float*)d_in[3];
    const float* Cp   = (const float*)d_in[4];
    const float* Dp   = (const float*)d_in[5];
    const float* W    = (const float*)d_in[6];
    const float* bo   = (const float*)d_in[7];
    const float* ga   = (const float*)d_in[8];
    const float* be   = (const float*)d_in[9];

    char* ws = (char*)d_ws;
    __hip_bfloat16* Wbf = (__hip_bfloat16*)ws;                   // 512 KiB @ 0
    float2* cgrp        = (float2*)(ws + (512 << 10));           // 2.36 MiB @ 0.5M
    __hip_bfloat16* xT  = (__hip_bfloat16*)(ws + (3u << 20));    // 8 MiB    @ 3M
    __hip_bfloat16* Mt  = (__hip_bfloat16*)(ws + (11u << 20));   // 12.6 MiB @ 11M
    uint* carr          = (uint*)(ws + (24u << 20));             // 16.25MiB @ 24M
    __hip_bfloat16* yT  = (__hip_bfloat16*)(ws + (41u << 20));   // 8 MiB    @ 41M
    __hip_bfloat16* ybf = (__hip_bfloat16*)(ws + (49u << 20));   // 8 MiB    @ 49M

    k_prep   <<<3200, 256, 0, stream>>>(x, logA, Aim, Bp, Cp, W, xT, cgrp, Wbf, Mt);
    k_scanA  <<<(BATCH * DM) / 8, 512, 0, stream>>>(xT, cgrp, carr);
    k_gemmY  <<<DM, 256, 0, stream>>>(Mt, xT, carr, Dp, yT);
    k_yt     <<<BATCH * 32 * 16, 256, 0, stream>>>(yT, ybf);
    k_gemm_ln<<<(BATCH * SEQ) / 32, 512, 0, stream>>>(ybf, Wbf, x, bo, ga, be, (float*)d_out);
}

// Round 18
// 70.031 us; speedup vs baseline: 1.5534x; 1.3087x over previous
//
#include <hip/hip_runtime.h>
#include <hip/hip_bf16.h>
#include <stdint.h>
#include <stddef.h>

#define BATCH 4
#define SEQ   2048
#define DM    512
#define NST   64
#define LN_EPS 1e-5f
#define NCH   32    // 32 chunks of 64
#define KDIM  192   // 64 x-taps + 128 carry (re,im interleaved)

typedef __attribute__((ext_vector_type(8))) short short8;
typedef __attribute__((ext_vector_type(4))) float f32x4;

__device__ __forceinline__ ushort f2bf(float f) {
    __hip_bfloat16 h = __float2bfloat16(f);
    return *(ushort*)&h;
}
__device__ __forceinline__ float bf2f(ushort u) {
    __hip_bfloat16 h = *(__hip_bfloat16*)&u;
    return __bfloat162float(h);
}

// ---------------- k_prep: fused  x-transpose | W-convert | M+G build ----------------
// blocks [0,2048):    x[b][l][d] f32 -> xT[d][b][l] bf16
// blocks [2048,3072): W->bf16
// blocks [3072,3200): per-d FIR/carry matrix M[64][192] bf16  +  G[128][64] bf16 + eA^64
__global__ __launch_bounds__(256) void k_prep(
    const float* __restrict__ x,
    const float* __restrict__ logA, const float* __restrict__ Aim,
    const float* __restrict__ Bp, const float* __restrict__ Cp,
    const float* __restrict__ W,
    __hip_bfloat16* __restrict__ xT,
    __hip_bfloat16* __restrict__ Wbf, __hip_bfloat16* __restrict__ Mt,
    __hip_bfloat16* __restrict__ Gt, float2* __restrict__ e64)
{
    __shared__ float smem[64][33];
    const int tid = threadIdx.x;
    const int bid = blockIdx.x;

    if (bid < 2048) {
        const int dt = bid & 15, lt = (bid >> 4) & 31, b = bid >> 9;
        const int l0 = lt * 64, d0 = dt * 32;
        const int dd = tid & 31, lr = tid >> 5;
        #pragma unroll
        for (int it = 0; it < 8; ++it) {
            int ll = it * 8 + lr;
            smem[ll][dd] = x[((size_t)b * SEQ + l0 + ll) * DM + d0 + dd];
        }
        __syncthreads();
        const int dw = tid >> 3, lg = (tid & 7) * 8;
        ushort pk[8];
        #pragma unroll
        for (int i = 0; i < 8; ++i) pk[i] = f2bf(smem[lg + i][dw]);
        *(short8*)&xT[((size_t)(d0 + dw) * BATCH + b) * SEQ + l0 + lg] = *(short8*)pk;
    } else if (bid < 3072) {
        int i = (bid - 2048) * 256 + tid;
        if (i < DM * DM) Wbf[i] = __float2bfloat16(W[i]);
    } else {
        // M[i][j] = K[j-i] (j>=i else 0); M[i][64+2s] = Re(eA_s^(64-i)); M[i][65+2s] = -Im
        // G[2s][t] = Re(eA^t CB), G[2s+1][t] = Im(eA^t CB); e64 = eA^64
        float (*Klds)[64] = (float(*)[64])smem;
        const int w = tid >> 6, lane = tid & 63;
        const int d = (bid - 3072) * 4 + w;
        const int i = d * NST + lane;
        float aa  = expf(logA[i]);
        float wim = Aim[i];
        float mag = expf(-aa);
        float er = mag * cosf(wim), ei = mag * sinf(wim);
        float Br = Bp[2*i], Bi = Bp[2*i+1];
        float Cr = Cp[2*i], Ci = Cp[2*i+1];
        float pr = Cr*Br + Ci*Bi;                 // CB * eA^t (t=0)
        float pi = Cr*Bi - Ci*Br;
        float ar = 1.f, ai = 0.f;                 // eA^t
        __hip_bfloat16* Md = Mt + (size_t)d * 64 * KDIM;
        __hip_bfloat16* Gr = Gt + ((size_t)d * 128 + 2 * lane) * 64;       // re row
        __hip_bfloat16* Gi = Gt + ((size_t)d * 128 + 2 * lane + 1) * 64;   // im row
        for (int tb = 0; tb < 8; ++tb) {
            ushort bufR[8], bufI[8];
            #pragma unroll
            for (int tt = 0; tt < 8; ++tt) {
                const int t = tb * 8 + tt;
                float kv = pr;
                #pragma unroll
                for (int mask = 1; mask < 64; mask <<= 1) kv += __shfl_xor(kv, mask);
                if (lane == 0) Klds[w][t] = kv;
                bufR[tt] = f2bf(pr);              // G row values at k=t
                bufI[tt] = f2bf(pi);
                float npr = er*pr - ei*pi, npi = er*pi + ei*pr;  pr = npr; pi = npi;
                float nar = er*ar - ei*ai, nai = er*ai + ei*ar;  ar = nar; ai = nai;
                uint u = (uint)f2bf(ar) | ((uint)f2bf(-ai) << 16);
                *(uint*)&Md[(63 - t) * KDIM + 64 + 2 * lane] = u;   // row 64-(t+1)
            }
            *(short8*)&Gr[tb * 8] = *(short8*)bufR;
            *(short8*)&Gi[tb * 8] = *(short8*)bufI;
        }
        e64[(size_t)d * NST + lane] = make_float2(ar, ai);   // eA^64
        __syncthreads();
        for (int r = 0; r < 64; ++r) {
            float v = (lane >= r) ? Klds[w][lane - r] : 0.f;
            Md[r * KDIM + lane] = __float2bfloat16(v);
        }
    }
}

// ---------------- k_scanU: per-d GEMM U = G_d(128x64) * X(64x128) + in-block carry combine ----------------
// U[2s][col] = Re(sum_k eA^k CB x), U[2s+1][col] = Im; col = b*32+ch.
// carr[ch] = U(ch+1) + eA64*carr[ch+1], carr[30] = U(31)  -> same layout gemmY consumes.
__global__ __launch_bounds__(256) void k_scanU(
    const __hip_bfloat16* __restrict__ Gt, const __hip_bfloat16* __restrict__ xT,
    const float2* __restrict__ e64, uint* __restrict__ carr)
{
    __shared__ short Gs[128 * 8 * 8];   // 16 KiB, chunk swz c^(row&7)
    __shared__ short Xs[128 * 8 * 8];   // 16 KiB, chunk swz c^(col&7)
    __shared__ float Us[128][129];      // 64.5 KiB

    const int tid = threadIdx.x;
    const int d = blockIdx.x;
    const int w = tid >> 6, lane = tid & 63;
    const int q = lane >> 4, n = lane & 15;

    // stage G_d: 128 rows x 8 chunks
    {
        const short* Gg = (const short*)(Gt + (size_t)d * 128 * 64);
        #pragma unroll
        for (int it = 0; it < 4; ++it) {
            int Gc = it * 256 + tid;
            int row = Gc >> 3, c = Gc & 7;
            int cs = c ^ (row & 7);
            *(short8*)&Gs[(row * 8 + cs) * 8] = *(const short8*)&Gg[Gc * 8];
        }
    }
    // stage X: 128 cols x 8 chunks (col = b*32+ch, k = chunk*8..+8)
    {
        #pragma unroll
        for (int it = 0; it < 4; ++it) {
            int id = it * 256 + tid;
            int col = id >> 3, ck = id & 7;
            int bb = col >> 5, ch = col & 31;
            short8 v = *(const short8*)&xT[((size_t)d * BATCH + bb) * SEQ + ch * 64 + ck * 8];
            int cs = ck ^ (col & 7);
            *(short8*)&Xs[(col * 8 + cs) * 8] = v;
        }
    }
    __syncthreads();

    f32x4 acc[2][8];
    #pragma unroll
    for (int rt = 0; rt < 2; ++rt)
        #pragma unroll
        for (int nf = 0; nf < 8; ++nf)
            #pragma unroll
            for (int k = 0; k < 4; ++k) acc[rt][nf][k] = 0.f;

    #pragma unroll
    for (int rt = 0; rt < 2; ++rt) {
        const int arow = w * 32 + rt * 16 + n;
        #pragma unroll
        for (int kt = 0; kt < 2; ++kt) {
            int c = kt * 4 + q;
            int csa = c ^ (arow & 7);
            short8 af = *(const short8*)&Gs[(arow * 8 + csa) * 8];
            #pragma unroll
            for (int nf = 0; nf < 8; ++nf) {
                int col = nf * 16 + n;
                int csb = c ^ (col & 7);
                short8 bf = *(const short8*)&Xs[(col * 8 + csb) * 8];
                acc[rt][nf] = __builtin_amdgcn_mfma_f32_16x16x32_bf16(af, bf, acc[rt][nf], 0, 0, 0);
            }
        }
    }

    // write U tiles: C/D row = q*4+r (within 16-tile), col = n
    #pragma unroll
    for (int rt = 0; rt < 2; ++rt) {
        const int r0w = w * 32 + rt * 16 + q * 4;
        #pragma unroll
        for (int nf = 0; nf < 8; ++nf) {
            int col = nf * 16 + n;
            #pragma unroll
            for (int r = 0; r < 4; ++r) Us[r0w + r][col] = acc[rt][nf][r];
        }
    }
    __syncthreads();

    // combine: thread = (b, s); 31-step serial carry in f32
    {
        const int bb = tid >> 6, s = tid & 63;
        float2 a64 = e64[(size_t)d * NST + s];
        const float er = a64.x, ei = a64.y;
        uint* cp = carr + ((size_t)d * BATCH + bb) * (NCH - 1) * 64 + s;
        float gr = Us[2 * s][bb * 32 + 31], gi = Us[2 * s + 1][bb * 32 + 31];
        cp[30 * 64] = (uint)f2bf(gr) | ((uint)f2bf(gi) << 16);
        for (int ch = 30; ch >= 1; --ch) {
            float ur = Us[2 * s][bb * 32 + ch], ui = Us[2 * s + 1][bb * 32 + ch];
            float nr = ur + er * gr - ei * gi;
            float ni = ui + er * gi + ei * gr;
            gr = nr; gi = ni;
            cp[(ch - 1) * 64] = (uint)f2bf(gr) | ((uint)f2bf(gi) << 16);
        }
    }
}

// ---------------- k_gemmY: per-d GEMM  y(64 x 128cols) = M(64x192) * Z(192x128) ----------------
__global__ __launch_bounds__(256) void k_gemmY(
    const __hip_bfloat16* __restrict__ Mt, const __hip_bfloat16* __restrict__ xT,
    const uint* __restrict__ carr, const float* __restrict__ Dp,
    __hip_bfloat16* __restrict__ yT)
{
    __shared__ short Ms[64 * 24 * 8];    // 24 KiB, 16B-chunk XOR-swizzled by row&7
    __shared__ short Zs[128 * 24 * 8];   // 48 KiB, swizzled by col&7
    const int tid = threadIdx.x;
    const int d = blockIdx.x;
    const int w = tid >> 6, lane = tid & 63;
    const int q = lane >> 4, n = lane & 15;

    {
        const short* Mg = (const short*)(Mt + (size_t)d * 64 * KDIM);
        #pragma unroll
        for (int it = 0; it < 6; ++it) {
            int G = it * 256 + tid;
            int row = G / 24, c = G % 24;
            int cs = (c & ~7) | ((c & 7) ^ (row & 7));
            *(short8*)&Ms[(row * 24 + cs) * 8] = *(const short8*)&Mg[G * 8];
        }
    }
    {
        #pragma unroll
        for (int it = 0; it < 4; ++it) {
            int id = it * 256 + tid;
            int col = id >> 3, ck = id & 7;
            int bb = col >> 5, ch = col & 31;
            short8 v = *(const short8*)&xT[((size_t)d * BATCH + bb) * SEQ + ch * 64 + ck * 8];
            int cs = ck ^ (col & 7);
            *(short8*)&Zs[(col * 24 + cs) * 8] = v;
        }
    }
    {
        #pragma unroll
        for (int it = 0; it < 8; ++it) {
            int id = it * 256 + tid;
            int col = id >> 4, st = id & 15;
            int bb = col >> 5, ch = col & 31;
            short8 v = {0,0,0,0,0,0,0,0};
            if (ch != 31)
                v = *(const short8*)(carr + (((size_t)d * BATCH + bb) * (NCH-1) + ch) * 64 + st * 4);
            int c = 8 + st;
            int cs = (c & ~7) | ((c & 7) ^ (col & 7));
            *(short8*)&Zs[(col * 24 + cs) * 8] = v;
        }
    }
    __syncthreads();

    f32x4 acc[8];
    #pragma unroll
    for (int nf = 0; nf < 8; ++nf)
        #pragma unroll
        for (int k = 0; k < 4; ++k) acc[nf][k] = 0.f;

    const int arow = w * 16 + n;
    #pragma unroll
    for (int kt = 0; kt < 6; ++kt) {
        int c = kt * 4 + q;
        int csa = (c & ~7) | ((c & 7) ^ (arow & 7));
        short8 af = *(const short8*)&Ms[(arow * 24 + csa) * 8];
        #pragma unroll
        for (int nf = 0; nf < 8; ++nf) {
            int col = nf * 16 + n;
            int csb = (c & ~7) | ((c & 7) ^ (col & 7));
            short8 bfr = *(const short8*)&Zs[(col * 24 + csb) * 8];
            acc[nf] = __builtin_amdgcn_mfma_f32_16x16x32_bf16(af, bfr, acc[nf], 0, 0, 0);
        }
    }

    const float Dd = Dp[d];
    const int i0 = w * 16 + q * 4;
    #pragma unroll
    for (int nf = 0; nf < 8; ++nf) {
        int col = nf * 16 + n;
        int bb = col >> 5, ch = col & 31;
        int cx = (i0 >> 3) ^ (col & 7);
        const ushort* zp = (const ushort*)&Zs[(col * 24 + cx) * 8 + (i0 & 7)];
        ushort o[4];
        #pragma unroll
        for (int r = 0; r < 4; ++r)
            o[r] = f2bf(acc[nf][r] + Dd * bf2f(zp[r]));
        *(uint2*)&yT[((size_t)d * BATCH + bb) * SEQ + ch * 64 + i0] = *(uint2*)o;
    }
}

// ---------------- k_yt: transpose yT[d][b][l] -> ybf[b][l][d] (bf16) ----------------
__global__ __launch_bounds__(256) void k_yt(
    const __hip_bfloat16* __restrict__ yT, __hip_bfloat16* __restrict__ ybf)
{
    __shared__ ushort t[64][34];
    const int tid = threadIdx.x, bid = blockIdx.x;
    const int dt = bid & 15, lt = (bid >> 4) & 31, b = bid >> 9;
    const int l0 = lt * 64, d0 = dt * 32;

    const int dw = tid >> 3, lg = (tid & 7) * 8;
    short8 v = *(const short8*)&yT[((size_t)(d0 + dw) * BATCH + b) * SEQ + l0 + lg];
    #pragma unroll
    for (int i = 0; i < 8; ++i) t[lg + i][dw] = (ushort)v[i];
    __syncthreads();

    const int row = tid >> 2, dg = (tid & 3) * 8;
    ushort pk[8];
    #pragma unroll
    for (int i = 0; i < 8; ++i) pk[i] = t[row][dg + i];
    *(short8*)&ybf[((size_t)b * SEQ + l0 + row) * DM + d0 + dg] = *(short8*)pk;
}

// ---------------- k_gemm_ln v13b: one-time A panel + dbuf reg-staged B (round-17 proven) ----------------
__global__ __launch_bounds__(512) void k_gemm_ln(
    const __hip_bfloat16* __restrict__ ybf, const __hip_bfloat16* __restrict__ Wbf,
    const float* __restrict__ x, const float* __restrict__ bout,
    const float* __restrict__ gamma, const float* __restrict__ beta,
    float* __restrict__ out)
{
    __shared__ short Af[32][520];     // full A panel [l][kd]; stride 520 -> 2-way banks on frag read
    __shared__ short Bs[512][32];     // W tile [o][k], 16B-chunk XOR swizzle (validated)
    __shared__ float red[8][32][2];
    __shared__ float stats[32][2];

    const int tid  = threadIdx.x;
    const int w    = tid >> 6;
    const int lane = tid & 63;
    const int q    = lane >> 4;
    const int m    = lane & 15;
    const int r0   = blockIdx.x * 32;

    // ---- one-time A panel (32 rows x 512 k = 2048 x 16B), 4 x 16B per thread, coalesced ----
    #pragma unroll
    for (int it = 0; it < 4; ++it) {
        int i = it * 512 + tid;
        int row = i >> 6, seg = i & 63;
        short8 v = *(const short8*)(ybf + (size_t)(r0 + row) * DM + seg * 8);
        *(short8*)&Af[row][seg * 8] = v;
    }

    // ---- B tile staging: 512 o x 32 k per step; 4 x 16B per thread ----
    short8 nb0, nb1, nb2, nb3;
    const int ob = tid >> 2, jb = tid & 3;
    const int js = (jb ^ (ob & 3)) * 8;
    #define LOADB(k0) { \
        nb0 = *(const short8*)(Wbf + (size_t)(ob      ) * DM + (k0) + jb * 8); \
        nb1 = *(const short8*)(Wbf + (size_t)(ob + 128) * DM + (k0) + jb * 8); \
        nb2 = *(const short8*)(Wbf + (size_t)(ob + 256) * DM + (k0) + jb * 8); \
        nb3 = *(const short8*)(Wbf + (size_t)(ob + 384) * DM + (k0) + jb * 8); }
    #define WRITEB() { \
        *(short8*)&Bs[ob      ][js] = nb0; \
        *(short8*)&Bs[ob + 128][js] = nb1; \
        *(short8*)&Bs[ob + 256][js] = nb2; \
        *(short8*)&Bs[ob + 384][js] = nb3; }

    LOADB(0);
    WRITEB();
    LOADB(32);
    __syncthreads();

    f32x4 acc[2][4];
    #pragma unroll
    for (int a = 0; a < 2; ++a)
        #pragma unroll
        for (int nn = 0; nn < 4; ++nn)
            #pragma unroll
            for (int k = 0; k < 4; ++k) acc[a][nn][k] = 0.f;

    for (int k = 0; k < 16; ++k) {
        const int k0 = k * 32;
        short8 a0 = *(const short8*)&Af[m][k0 + q * 8];
        short8 a1 = *(const short8*)&Af[16 + m][k0 + q * 8];
        #pragma unroll
        for (int nf = 0; nf < 4; ++nf) {
            int o = w * 64 + nf * 16 + m;        // o&3 == m&3
            short8 bb = *(const short8*)&Bs[o][(q ^ (m & 3)) * 8];
            acc[0][nf] = __builtin_amdgcn_mfma_f32_16x16x32_bf16(a0, bb, acc[0][nf], 0, 0, 0);
            acc[1][nf] = __builtin_amdgcn_mfma_f32_16x16x32_bf16(a1, bb, acc[1][nf], 0, 0, 0);
        }
        __syncthreads();                          // all waves done reading Bs
        if (k < 15) {
            WRITEB();                             // B_{k+1} regs -> LDS
            if (k < 14) LOADB((k + 2) * 32);      // issue B_{k+2}; lands during next compute
            __syncthreads();                      // Bs ready
        }
    }
    #undef LOADB
    #undef WRITEB

    // ---- epilogue: +bias, +x residual, row mean/var, normalize ----
    float bo[4], ga[4], be[4];
    #pragma unroll
    for (int nf = 0; nf < 4; ++nf) {
        int o = w * 64 + nf * 16 + m;
        bo[nf] = bout[o]; ga[nf] = gamma[o]; be[nf] = beta[o];
    }

    float rs[2][4], rq[2][4];
    #pragma unroll
    for (int mf = 0; mf < 2; ++mf)
        #pragma unroll
        for (int i = 0; i < 4; ++i) { rs[mf][i] = 0.f; rq[mf][i] = 0.f; }

    #pragma unroll
    for (int mf = 0; mf < 2; ++mf)
        #pragma unroll
        for (int nf = 0; nf < 4; ++nf) {
            int o = w * 64 + nf * 16 + m;
            #pragma unroll
            for (int i = 0; i < 4; ++i) {
                int row = mf * 16 + q * 4 + i;    // C/D: row=(lane>>4)*4+reg, col=lane&15
                float zv = acc[mf][nf][i] + bo[nf] + x[(size_t)(r0 + row) * DM + o];
                acc[mf][nf][i] = zv;
                rs[mf][i] += zv;
                rq[mf][i] += zv * zv;
            }
        }

    #pragma unroll
    for (int mask = 1; mask < 16; mask <<= 1) {
        #pragma unroll
        for (int mf = 0; mf < 2; ++mf)
            #pragma unroll
            for (int i = 0; i < 4; ++i) {
                rs[mf][i] += __shfl_xor(rs[mf][i], mask);
                rq[mf][i] += __shfl_xor(rq[mf][i], mask);
            }
    }
    if (m == 0) {
        #pragma unroll
        for (int mf = 0; mf < 2; ++mf)
            #pragma unroll
            for (int i = 0; i < 4; ++i) {
                int row = mf * 16 + q * 4 + i;
                red[w][row][0] = rs[mf][i];
                red[w][row][1] = rq[mf][i];
            }
    }
    __syncthreads();
    if (tid < 32) {
        float s = 0.f, sq = 0.f;
        #pragma unroll
        for (int ww = 0; ww < 8; ++ww) { s += red[ww][tid][0]; sq += red[ww][tid][1]; }
        float mu  = s * (1.f / DM);
        float var = sq * (1.f / DM) - mu * mu;
        stats[tid][0] = mu;
        stats[tid][1] = 1.f / sqrtf(var + LN_EPS);
    }
    __syncthreads();

    #pragma unroll
    for (int mf = 0; mf < 2; ++mf)
        #pragma unroll
        for (int i = 0; i < 4; ++i) {
            int row = mf * 16 + q * 4 + i;
            float mu = stats[row][0], rstd = stats[row][1];
            #pragma unroll
            for (int nf = 0; nf < 4; ++nf) {
                int o = w * 64 + nf * 16 + m;
                out[(size_t)(r0 + row) * DM + o] =
                    ga[nf] * (acc[mf][nf][i] - mu) * rstd + be[nf];
            }
        }
}

// ---------------- launcher ----------------
extern "C" void kernel_launch(void* const* d_in, const int* in_sizes, int n_in,
                              void* d_out, int out_size, void* d_ws, size_t ws_size,
                              hipStream_t stream)
{
    const float* x    = (const float*)d_in[0];
    const float* logA = (const float*)d_in[1];
    const float* Aim  = (const float*)d_in[2];
    const float* Bp   = (const float*)d_in[3];
    const float* Cp   = (const float*)d_in[4];
    const float* Dp   = (const float*)d_in[5];
    const float* W    = (const float*)d_in[6];
    const float* bo   = (const float*)d_in[7];
    const float* ga   = (const float*)d_in[8];
    const float* be   = (const float*)d_in[9];

    char* ws = (char*)d_ws;
    __hip_bfloat16* Wbf = (__hip_bfloat16*)ws;                   // 512 KiB @ 0
    __hip_bfloat16* xT  = (__hip_bfloat16*)(ws + (3u << 20));    // 8 MiB    @ 3M
    __hip_bfloat16* Mt  = (__hip_bfloat16*)(ws + (11u << 20));   // 12.6 MiB @ 11M
    uint* carr          = (uint*)(ws + (24u << 20));             // 16.25MiB @ 24M
    __hip_bfloat16* yT  = (__hip_bfloat16*)(ws + (41u << 20));   // 8 MiB    @ 41M
    __hip_bfloat16* ybf = (__hip_bfloat16*)(ws + (49u << 20));   // 8 MiB    @ 49M
    __hip_bfloat16* Gt  = (__hip_bfloat16*)(ws + (57u << 20));   // 8 MiB    @ 57M
    float2* e64         = (float2*)(ws + (65u << 20));           // 256 KiB  @ 65M

    k_prep   <<<3200, 256, 0, stream>>>(x, logA, Aim, Bp, Cp, W, xT, Wbf, Mt, Gt, e64);
    k_scanU  <<<DM, 256, 0, stream>>>(Gt, xT, e64, carr);
    k_gemmY  <<<DM, 256, 0, stream>>>(Mt, xT, carr, Dp, yT);
    k_yt     <<<BATCH * 32 * 16, 256, 0, stream>>>(yT, ybf);
    k_gemm_ln<<<(BATCH * SEQ) / 32, 512, 0, stream>>>(ybf, Wbf, x, bo, ga, be, (float*)d_out);
}

// Round 19
// 66.057 us; speedup vs baseline: 1.6469x; 1.0602x over previous
//
#include <hip/hip_runtime.h>
#include <hip/hip_bf16.h>
#include <stdint.h>
#include <stddef.h>

#define BATCH 4
#define SEQ   2048
#define DM    512
#define NST   64
#define LN_EPS 1e-5f
#define NCH   32    // 32 chunks of 64
#define KDIM  192   // 64 x-taps + 128 carry (re,im interleaved)

typedef __attribute__((ext_vector_type(8))) short short8;
typedef __attribute__((ext_vector_type(4))) float f32x4;

__device__ __forceinline__ ushort f2bf(float f) {
    __hip_bfloat16 h = __float2bfloat16(f);
    return *(ushort*)&h;
}
__device__ __forceinline__ float bf2f(ushort u) {
    __hip_bfloat16 h = *(__hip_bfloat16*)&u;
    return __bfloat162float(h);
}

// ---------------- k_prep: fused  x-transpose | W-convert | M+G build ----------------
// blocks [0,2048):    x[b][l][d] f32 -> xT[d][b][l] bf16
// blocks [2048,3072): W->bf16
// blocks [3072,3200): per-d FIR/carry matrix M[64][192] bf16  +  G[128][64] bf16 + eA^64
__global__ __launch_bounds__(256) void k_prep(
    const float* __restrict__ x,
    const float* __restrict__ logA, const float* __restrict__ Aim,
    const float* __restrict__ Bp, const float* __restrict__ Cp,
    const float* __restrict__ W,
    __hip_bfloat16* __restrict__ xT,
    __hip_bfloat16* __restrict__ Wbf, __hip_bfloat16* __restrict__ Mt,
    __hip_bfloat16* __restrict__ Gt, float2* __restrict__ e64)
{
    __shared__ float smem[64][33];
    const int tid = threadIdx.x;
    const int bid = blockIdx.x;

    if (bid < 2048) {
        const int dt = bid & 15, lt = (bid >> 4) & 31, b = bid >> 9;
        const int l0 = lt * 64, d0 = dt * 32;
        const int dd = tid & 31, lr = tid >> 5;
        #pragma unroll
        for (int it = 0; it < 8; ++it) {
            int ll = it * 8 + lr;
            smem[ll][dd] = x[((size_t)b * SEQ + l0 + ll) * DM + d0 + dd];
        }
        __syncthreads();
        const int dw = tid >> 3, lg = (tid & 7) * 8;
        ushort pk[8];
        #pragma unroll
        for (int i = 0; i < 8; ++i) pk[i] = f2bf(smem[lg + i][dw]);
        *(short8*)&xT[((size_t)(d0 + dw) * BATCH + b) * SEQ + l0 + lg] = *(short8*)pk;
    } else if (bid < 3072) {
        int i = (bid - 2048) * 256 + tid;
        if (i < DM * DM) Wbf[i] = __float2bfloat16(W[i]);
    } else {
        // M[i][j] = K[j-i] (j>=i else 0); M[i][64+2s] = Re(eA_s^(64-i)); M[i][65+2s] = -Im
        // G[2s][t] = Re(eA^t CB), G[2s+1][t] = Im(eA^t CB); e64 = eA^64
        float (*Klds)[64] = (float(*)[64])smem;
        const int w = tid >> 6, lane = tid & 63;
        const int d = (bid - 3072) * 4 + w;
        const int i = d * NST + lane;
        float aa  = expf(logA[i]);
        float wim = Aim[i];
        float mag = expf(-aa);
        float er = mag * cosf(wim), ei = mag * sinf(wim);
        float Br = Bp[2*i], Bi = Bp[2*i+1];
        float Cr = Cp[2*i], Ci = Cp[2*i+1];
        float pr = Cr*Br + Ci*Bi;                 // CB * eA^t (t=0)
        float pi = Cr*Bi - Ci*Br;
        float ar = 1.f, ai = 0.f;                 // eA^t
        __hip_bfloat16* Md = Mt + (size_t)d * 64 * KDIM;
        __hip_bfloat16* Gr = Gt + ((size_t)d * 128 + 2 * lane) * 64;       // re row
        __hip_bfloat16* Gi = Gt + ((size_t)d * 128 + 2 * lane + 1) * 64;   // im row
        for (int tb = 0; tb < 8; ++tb) {
            ushort bufR[8], bufI[8];
            #pragma unroll
            for (int tt = 0; tt < 8; ++tt) {
                const int t = tb * 8 + tt;
                float kv = pr;
                #pragma unroll
                for (int mask = 1; mask < 64; mask <<= 1) kv += __shfl_xor(kv, mask);
                if (lane == 0) Klds[w][t] = kv;
                bufR[tt] = f2bf(pr);              // G row values at k=t
                bufI[tt] = f2bf(pi);
                float npr = er*pr - ei*pi, npi = er*pi + ei*pr;  pr = npr; pi = npi;
                float nar = er*ar - ei*ai, nai = er*ai + ei*ar;  ar = nar; ai = nai;
                uint u = (uint)f2bf(ar) | ((uint)f2bf(-ai) << 16);
                *(uint*)&Md[(63 - t) * KDIM + 64 + 2 * lane] = u;   // row 64-(t+1)
            }
            *(short8*)&Gr[tb * 8] = *(short8*)bufR;
            *(short8*)&Gi[tb * 8] = *(short8*)bufI;
        }
        e64[(size_t)d * NST + lane] = make_float2(ar, ai);   // eA^64
        __syncthreads();
        for (int r = 0; r < 64; ++r) {
            float v = (lane >= r) ? Klds[w][lane - r] : 0.f;
            Md[r * KDIM + lane] = __float2bfloat16(v);
        }
    }
}

// ---------------- k_ssm: merged scanU + gemmY (per-d block; carries never leave LDS) ----------------
// Phase 1: U(128x128) = G_d(128x64) * X(64x128) via MFMA -> Us (f32 LDS)
// Phase 2: carry combine carr[ch] = U(ch+1) + eA64*carr[ch+1], written bf16 into Zs carry chunks
// Phase 3: y(64x128) = M_d(64x192) * Z(192x128) via MFMA, +D*x, store yT[d][b][l]
__global__ __launch_bounds__(256) void k_ssm(
    const __hip_bfloat16* __restrict__ Gt, const __hip_bfloat16* __restrict__ Mt,
    const __hip_bfloat16* __restrict__ xT, const float2* __restrict__ e64,
    const float* __restrict__ Dp, __hip_bfloat16* __restrict__ yT)
{
    __shared__ short Zs[128 * 24 * 8];            // 48K persistent: x chunks 0-7, carry chunks 8-23
    __shared__ __align__(16) char Rgn[16384 + 128 * 129 * 4];   // union: {Gs 16K + Us 64.5K} / {Ms 24K}
    short* Gs = (short*)Rgn;
    float (*Us)[129] = (float(*)[129])(Rgn + 16384);
    short* Ms = (short*)Rgn;

    const int tid = threadIdx.x;
    const int d = blockIdx.x;
    const int w = tid >> 6, lane = tid & 63;
    const int q = lane >> 4, n = lane & 15;

    // ---- stage Gs (128 rows x 8 chunks) and Zs x-part (128 cols x 8 chunks) ----
    {
        const short* Gg = (const short*)(Gt + (size_t)d * 128 * 64);
        #pragma unroll
        for (int it = 0; it < 4; ++it) {
            int Gc = it * 256 + tid;
            int row = Gc >> 3, c = Gc & 7;
            int cs = c ^ (row & 7);
            *(short8*)&Gs[(row * 8 + cs) * 8] = *(const short8*)&Gg[Gc * 8];
        }
        #pragma unroll
        for (int it = 0; it < 4; ++it) {
            int id = it * 256 + tid;
            int col = id >> 3, ck = id & 7;
            int bb = col >> 5, ch = col & 31;
            short8 v = *(const short8*)&xT[((size_t)d * BATCH + bb) * SEQ + ch * 64 + ck * 8];
            int cs = ck ^ (col & 7);
            *(short8*)&Zs[(col * 24 + cs) * 8] = v;
        }
    }
    __syncthreads();

    // ---- phase 1: U = G * X ----
    {
        f32x4 acc[2][8];
        #pragma unroll
        for (int rt = 0; rt < 2; ++rt)
            #pragma unroll
            for (int nf = 0; nf < 8; ++nf)
                #pragma unroll
                for (int k = 0; k < 4; ++k) acc[rt][nf][k] = 0.f;

        #pragma unroll
        for (int rt = 0; rt < 2; ++rt) {
            const int arow = w * 32 + rt * 16 + n;
            #pragma unroll
            for (int kt = 0; kt < 2; ++kt) {
                int c = kt * 4 + q;
                int csa = c ^ (arow & 7);
                short8 af = *(const short8*)&Gs[(arow * 8 + csa) * 8];
                #pragma unroll
                for (int nf = 0; nf < 8; ++nf) {
                    int col = nf * 16 + n;
                    int csb = c ^ (col & 7);
                    short8 bf = *(const short8*)&Zs[(col * 24 + csb) * 8];
                    acc[rt][nf] = __builtin_amdgcn_mfma_f32_16x16x32_bf16(af, bf, acc[rt][nf], 0, 0, 0);
                }
            }
        }
        #pragma unroll
        for (int rt = 0; rt < 2; ++rt) {
            const int r0w = w * 32 + rt * 16 + q * 4;
            #pragma unroll
            for (int nf = 0; nf < 8; ++nf) {
                int col = nf * 16 + n;
                #pragma unroll
                for (int r = 0; r < 4; ++r) Us[r0w + r][col] = acc[rt][nf][r];
            }
        }
    }
    __syncthreads();

    // ---- phase 2: carry combine, bf16 results straight into Zs carry chunks ----
    {
        const int bb = tid >> 6, s = tid & 63;
        const int st = s >> 2, so = (s & 3) * 2;        // chunk st, short offset within 16B
        float2 a64 = e64[(size_t)d * NST + s];
        const float er = a64.x, ei = a64.y;
        // col ch=31 carry = 0
        {
            int col = bb * 32 + 31;
            int c = 8 + st, cs = (c & ~7) | ((c & 7) ^ (col & 7));
            *(uint*)&Zs[(col * 24 + cs) * 8 + so] = 0u;
        }
        float gr = Us[2 * s][bb * 32 + 31], gi = Us[2 * s + 1][bb * 32 + 31];
        {
            int col = bb * 32 + 30;                      // carr[30] -> col ch=30
            int c = 8 + st, cs = (c & ~7) | ((c & 7) ^ (col & 7));
            *(uint*)&Zs[(col * 24 + cs) * 8 + so] = (uint)f2bf(gr) | ((uint)f2bf(gi) << 16);
        }
        for (int ch = 30; ch >= 1; --ch) {
            float ur = Us[2 * s][bb * 32 + ch], ui = Us[2 * s + 1][bb * 32 + ch];
            float nr = ur + er * gr - ei * gi;
            float ni = ui + er * gi + ei * gr;
            gr = nr; gi = ni;
            int col = bb * 32 + ch - 1;                  // carr[ch-1] -> col ch-1
            int c = 8 + st, cs = (c & ~7) | ((c & 7) ^ (col & 7));
            *(uint*)&Zs[(col * 24 + cs) * 8 + so] = (uint)f2bf(gr) | ((uint)f2bf(gi) << 16);
        }
    }
    __syncthreads();

    // ---- stage Ms into the union region (Gs/Us dead now) ----
    {
        const short* Mg = (const short*)(Mt + (size_t)d * 64 * KDIM);
        #pragma unroll
        for (int it = 0; it < 6; ++it) {
            int G = it * 256 + tid;
            int row = G / 24, c = G % 24;
            int cs = (c & ~7) | ((c & 7) ^ (row & 7));
            *(short8*)&Ms[(row * 24 + cs) * 8] = *(const short8*)&Mg[G * 8];
        }
    }
    __syncthreads();

    // ---- phase 3: y = M * Z, + D*x, store yT ----
    f32x4 acc[8];
    #pragma unroll
    for (int nf = 0; nf < 8; ++nf)
        #pragma unroll
        for (int k = 0; k < 4; ++k) acc[nf][k] = 0.f;

    const int arow = w * 16 + n;
    #pragma unroll
    for (int kt = 0; kt < 6; ++kt) {
        int c = kt * 4 + q;
        int csa = (c & ~7) | ((c & 7) ^ (arow & 7));
        short8 af = *(const short8*)&Ms[(arow * 24 + csa) * 8];
        #pragma unroll
        for (int nf = 0; nf < 8; ++nf) {
            int col = nf * 16 + n;
            int csb = (c & ~7) | ((c & 7) ^ (col & 7));
            short8 bfr = *(const short8*)&Zs[(col * 24 + csb) * 8];
            acc[nf] = __builtin_amdgcn_mfma_f32_16x16x32_bf16(af, bfr, acc[nf], 0, 0, 0);
        }
    }

    const float Dd = Dp[d];
    const int i0 = w * 16 + q * 4;
    #pragma unroll
    for (int nf = 0; nf < 8; ++nf) {
        int col = nf * 16 + n;
        int bb = col >> 5, ch = col & 31;
        int cx = (i0 >> 3) ^ (col & 7);
        const ushort* zp = (const ushort*)&Zs[(col * 24 + cx) * 8 + (i0 & 7)];
        ushort o[4];
        #pragma unroll
        for (int r = 0; r < 4; ++r)
            o[r] = f2bf(acc[nf][r] + Dd * bf2f(zp[r]));
        *(uint2*)&yT[((size_t)d * BATCH + bb) * SEQ + ch * 64 + i0] = *(uint2*)o;
    }
}

// ---------------- k_yt: transpose yT[d][b][l] -> ybf[b][l][d] (bf16) ----------------
__global__ __launch_bounds__(256) void k_yt(
    const __hip_bfloat16* __restrict__ yT, __hip_bfloat16* __restrict__ ybf)
{
    __shared__ ushort t[64][34];
    const int tid = threadIdx.x, bid = blockIdx.x;
    const int dt = bid & 15, lt = (bid >> 4) & 31, b = bid >> 9;
    const int l0 = lt * 64, d0 = dt * 32;

    const int dw = tid >> 3, lg = (tid & 7) * 8;
    short8 v = *(const short8*)&yT[((size_t)(d0 + dw) * BATCH + b) * SEQ + l0 + lg];
    #pragma unroll
    for (int i = 0; i < 8; ++i) t[lg + i][dw] = (ushort)v[i];
    __syncthreads();

    const int row = tid >> 2, dg = (tid & 3) * 8;
    ushort pk[8];
    #pragma unroll
    for (int i = 0; i < 8; ++i) pk[i] = t[row][dg + i];
    *(short8*)&ybf[((size_t)b * SEQ + l0 + row) * DM + d0 + dg] = *(short8*)pk;
}

// ---------------- k_gemm_ln v13b: one-time A panel + dbuf reg-staged B (round-17 proven) ----------------
__global__ __launch_bounds__(512) void k_gemm_ln(
    const __hip_bfloat16* __restrict__ ybf, const __hip_bfloat16* __restrict__ Wbf,
    const float* __restrict__ x, const float* __restrict__ bout,
    const float* __restrict__ gamma, const float* __restrict__ beta,
    float* __restrict__ out)
{
    __shared__ short Af[32][520];     // full A panel [l][kd]; stride 520 -> 2-way banks on frag read
    __shared__ short Bs[512][32];     // W tile [o][k], 16B-chunk XOR swizzle (validated)
    __shared__ float red[8][32][2];
    __shared__ float stats[32][2];

    const int tid  = threadIdx.x;
    const int w    = tid >> 6;
    const int lane = tid & 63;
    const int q    = lane >> 4;
    const int m    = lane & 15;
    const int r0   = blockIdx.x * 32;

    // ---- one-time A panel (32 rows x 512 k = 2048 x 16B), 4 x 16B per thread, coalesced ----
    #pragma unroll
    for (int it = 0; it < 4; ++it) {
        int i = it * 512 + tid;
        int row = i >> 6, seg = i & 63;
        short8 v = *(const short8*)(ybf + (size_t)(r0 + row) * DM + seg * 8);
        *(short8*)&Af[row][seg * 8] = v;
    }

    // ---- B tile staging: 512 o x 32 k per step; 4 x 16B per thread ----
    short8 nb0, nb1, nb2, nb3;
    const int ob = tid >> 2, jb = tid & 3;
    const int js = (jb ^ (ob & 3)) * 8;
    #define LOADB(k0) { \
        nb0 = *(const short8*)(Wbf + (size_t)(ob      ) * DM + (k0) + jb * 8); \
        nb1 = *(const short8*)(Wbf + (size_t)(ob + 128) * DM + (k0) + jb * 8); \
        nb2 = *(const short8*)(Wbf + (size_t)(ob + 256) * DM + (k0) + jb * 8); \
        nb3 = *(const short8*)(Wbf + (size_t)(ob + 384) * DM + (k0) + jb * 8); }
    #define WRITEB() { \
        *(short8*)&Bs[ob      ][js] = nb0; \
        *(short8*)&Bs[ob + 128][js] = nb1; \
        *(short8*)&Bs[ob + 256][js] = nb2; \
        *(short8*)&Bs[ob + 384][js] = nb3; }

    LOADB(0);
    WRITEB();
    LOADB(32);
    __syncthreads();

    f32x4 acc[2][4];
    #pragma unroll
    for (int a = 0; a < 2; ++a)
        #pragma unroll
        for (int nn = 0; nn < 4; ++nn)
            #pragma unroll
            for (int k = 0; k < 4; ++k) acc[a][nn][k] = 0.f;

    for (int k = 0; k < 16; ++k) {
        const int k0 = k * 32;
        short8 a0 = *(const short8*)&Af[m][k0 + q * 8];
        short8 a1 = *(const short8*)&Af[16 + m][k0 + q * 8];
        #pragma unroll
        for (int nf = 0; nf < 4; ++nf) {
            int o = w * 64 + nf * 16 + m;        // o&3 == m&3
            short8 bb = *(const short8*)&Bs[o][(q ^ (m & 3)) * 8];
            acc[0][nf] = __builtin_amdgcn_mfma_f32_16x16x32_bf16(a0, bb, acc[0][nf], 0, 0, 0);
            acc[1][nf] = __builtin_amdgcn_mfma_f32_16x16x32_bf16(a1, bb, acc[1][nf], 0, 0, 0);
        }
        __syncthreads();                          // all waves done reading Bs
        if (k < 15) {
            WRITEB();                             // B_{k+1} regs -> LDS
            if (k < 14) LOADB((k + 2) * 32);      // issue B_{k+2}; lands during next compute
            __syncthreads();                      // Bs ready
        }
    }
    #undef LOADB
    #undef WRITEB

    // ---- epilogue: +bias, +x residual, row mean/var, normalize ----
    float bo[4], ga[4], be[4];
    #pragma unroll
    for (int nf = 0; nf < 4; ++nf) {
        int o = w * 64 + nf * 16 + m;
        bo[nf] = bout[o]; ga[nf] = gamma[o]; be[nf] = beta[o];
    }

    float rs[2][4], rq[2][4];
    #pragma unroll
    for (int mf = 0; mf < 2; ++mf)
        #pragma unroll
        for (int i = 0; i < 4; ++i) { rs[mf][i] = 0.f; rq[mf][i] = 0.f; }

    #pragma unroll
    for (int mf = 0; mf < 2; ++mf)
        #pragma unroll
        for (int nf = 0; nf < 4; ++nf) {
            int o = w * 64 + nf * 16 + m;
            #pragma unroll
            for (int i = 0; i < 4; ++i) {
                int row = mf * 16 + q * 4 + i;    // C/D: row=(lane>>4)*4+reg, col=lane&15
                float zv = acc[mf][nf][i] + bo[nf] + x[(size_t)(r0 + row) * DM + o];
                acc[mf][nf][i] = zv;
                rs[mf][i] += zv;
                rq[mf][i] += zv * zv;
            }
        }

    #pragma unroll
    for (int mask = 1; mask < 16; mask <<= 1) {
        #pragma unroll
        for (int mf = 0; mf < 2; ++mf)
            #pragma unroll
            for (int i = 0; i < 4; ++i) {
                rs[mf][i] += __shfl_xor(rs[mf][i], mask);
                rq[mf][i] += __shfl_xor(rq[mf][i], mask);
            }
    }
    if (m == 0) {
        #pragma unroll
        for (int mf = 0; mf < 2; ++mf)
            #pragma unroll
            for (int i = 0; i < 4; ++i) {
                int row = mf * 16 + q * 4 + i;
                red[w][row][0] = rs[mf][i];
                red[w][row][1] = rq[mf][i];
            }
    }
    __syncthreads();
    if (tid < 32) {
        float s = 0.f, sq = 0.f;
        #pragma unroll
        for (int ww = 0; ww < 8; ++ww) { s += red[ww][tid][0]; sq += red[ww][tid][1]; }
        float mu  = s * (1.f / DM);
        float var = sq * (1.f / DM) - mu * mu;
        stats[tid][0] = mu;
        stats[tid][1] = 1.f / sqrtf(var + LN_EPS);
    }
    __syncthreads();

    #pragma unroll
    for (int mf = 0; mf < 2; ++mf)
        #pragma unroll
        for (int i = 0; i < 4; ++i) {
            int row = mf * 16 + q * 4 + i;
            float mu = stats[row][0], rstd = stats[row][1];
            #pragma unroll
            for (int nf = 0; nf < 4; ++nf) {
                int o = w * 64 + nf * 16 + m;
                out[(size_t)(r0 + row) * DM + o] =
                    ga[nf] * (acc[mf][nf][i] - mu) * rstd + be[nf];
            }
        }
}

// ---------------- launcher ----------------
extern "C" void kernel_launch(void* const* d_in, const int* in_sizes, int n_in,
                              void* d_out, int out_size, void* d_ws, size_t ws_size,
                              hipStream_t stream)
{
    const float* x    = (const float*)d_in[0];
    const float* logA = (const float*)d_in[1];
    const float* Aim  = (const float*)d_in[2];
    const float* Bp   = (const float*)d_in[3];
    const float* Cp   = (const float*)d_in[4];
    const float* Dp   = (const float*)d_in[5];
    const float* W    = (const float*)d_in[6];
    const float* bo   = (const float*)d_in[7];
    const float* ga   = (const float*)d_in[8];
    const float* be   = (const float*)d_in[9];

    char* ws = (char*)d_ws;
    __hip_bfloat16* Wbf = (__hip_bfloat16*)ws;                   // 512 KiB @ 0
    __hip_bfloat16* xT  = (__hip_bfloat16*)(ws + (3u << 20));    // 8 MiB    @ 3M
    __hip_bfloat16* Mt  = (__hip_bfloat16*)(ws + (11u << 20));   // 12.6 MiB @ 11M
    __hip_bfloat16* yT  = (__hip_bfloat16*)(ws + (41u << 20));   // 8 MiB    @ 41M
    __hip_bfloat16* ybf = (__hip_bfloat16*)(ws + (49u << 20));   // 8 MiB    @ 49M
    __hip_bfloat16* Gt  = (__hip_bfloat16*)(ws + (57u << 20));   // 8 MiB    @ 57M
    float2* e64         = (float2*)(ws + (65u << 20));           // 256 KiB  @ 65M

    k_prep   <<<3200, 256, 0, stream>>>(x, logA, Aim, Bp, Cp, W, xT, Wbf, Mt, Gt, e64);
    k_ssm    <<<DM, 256, 0, stream>>>(Gt, Mt, xT, e64, Dp, yT);
    k_yt     <<<BATCH * 32 * 16, 256, 0, stream>>>(yT, ybf);
    k_gemm_ln<<<(BATCH * SEQ) / 32, 512, 0, stream>>>(ybf, Wbf, x, bo, ga, be, (float*)d_out);
}

// Round 20
// 62.869 us; speedup vs baseline: 1.7304x; 1.0507x over previous
//
#include <hip/hip_runtime.h>
#include <hip/hip_bf16.h>
#include <stdint.h>
#include <stddef.h>

#define BATCH 4
#define SEQ   2048
#define DM    512
#define NST   64
#define LN_EPS 1e-5f
#define NCH   32    // 32 chunks of 64
#define KDIM  192   // 64 x-taps + 128 carry (re,im interleaved)

typedef __attribute__((ext_vector_type(8))) short short8;
typedef __attribute__((ext_vector_type(4))) float f32x4;

__device__ __forceinline__ ushort f2bf(float f) {
    __hip_bfloat16 h = __float2bfloat16(f);
    return *(ushort*)&h;
}
__device__ __forceinline__ float bf2f(ushort u) {
    __hip_bfloat16 h = *(__hip_bfloat16*)&u;
    return __bfloat162float(h);
}

// ---------------- k_prep: fused  x-transpose | W-convert | M+G build ----------------
// blocks [0,2048):    x[b][l][d] f32 -> xT[d][b][l] bf16
// blocks [2048,3072): W->bf16
// blocks [3072,3200): per-d FIR/carry matrix M[64][192] bf16  +  G[128][64] bf16 + eA^64
__global__ __launch_bounds__(256) void k_prep(
    const float* __restrict__ x,
    const float* __restrict__ logA, const float* __restrict__ Aim,
    const float* __restrict__ Bp, const float* __restrict__ Cp,
    const float* __restrict__ W,
    __hip_bfloat16* __restrict__ xT,
    __hip_bfloat16* __restrict__ Wbf, __hip_bfloat16* __restrict__ Mt,
    __hip_bfloat16* __restrict__ Gt, float2* __restrict__ e64)
{
    __shared__ float smem[64][33];
    const int tid = threadIdx.x;
    const int bid = blockIdx.x;

    if (bid < 2048) {
        const int dt = bid & 15, lt = (bid >> 4) & 31, b = bid >> 9;
        const int l0 = lt * 64, d0 = dt * 32;
        const int dd = tid & 31, lr = tid >> 5;
        #pragma unroll
        for (int it = 0; it < 8; ++it) {
            int ll = it * 8 + lr;
            smem[ll][dd] = x[((size_t)b * SEQ + l0 + ll) * DM + d0 + dd];
        }
        __syncthreads();
        const int dw = tid >> 3, lg = (tid & 7) * 8;
        ushort pk[8];
        #pragma unroll
        for (int i = 0; i < 8; ++i) pk[i] = f2bf(smem[lg + i][dw]);
        *(short8*)&xT[((size_t)(d0 + dw) * BATCH + b) * SEQ + l0 + lg] = *(short8*)pk;
    } else if (bid < 3072) {
        int i = (bid - 2048) * 256 + tid;
        if (i < DM * DM) Wbf[i] = __float2bfloat16(W[i]);
    } else {
        // M[i][j] = K[j-i] (j>=i else 0); M[i][64+2s] = Re(eA_s^(64-i)); M[i][65+2s] = -Im
        // G[2s][t] = Re(eA^t CB), G[2s+1][t] = Im(eA^t CB); e64 = eA^64
        float (*Klds)[64] = (float(*)[64])smem;
        const int w = tid >> 6, lane = tid & 63;
        const int d = (bid - 3072) * 4 + w;
        const int i = d * NST + lane;
        float aa  = expf(logA[i]);
        float wim = Aim[i];
        float mag = expf(-aa);
        float er = mag * cosf(wim), ei = mag * sinf(wim);
        float Br = Bp[2*i], Bi = Bp[2*i+1];
        float Cr = Cp[2*i], Ci = Cp[2*i+1];
        float pr = Cr*Br + Ci*Bi;                 // CB * eA^t (t=0)
        float pi = Cr*Bi - Ci*Br;
        float ar = 1.f, ai = 0.f;                 // eA^t
        __hip_bfloat16* Md = Mt + (size_t)d * 64 * KDIM;
        __hip_bfloat16* Gr = Gt + ((size_t)d * 128 + 2 * lane) * 64;       // re row
        __hip_bfloat16* Gi = Gt + ((size_t)d * 128 + 2 * lane + 1) * 64;   // im row
        for (int tb = 0; tb < 8; ++tb) {
            ushort bufR[8], bufI[8];
            #pragma unroll
            for (int tt = 0; tt < 8; ++tt) {
                const int t = tb * 8 + tt;
                float kv = pr;
                #pragma unroll
                for (int mask = 1; mask < 64; mask <<= 1) kv += __shfl_xor(kv, mask);
                if (lane == 0) Klds[w][t] = kv;
                bufR[tt] = f2bf(pr);              // G row values at k=t
                bufI[tt] = f2bf(pi);
                float npr = er*pr - ei*pi, npi = er*pi + ei*pr;  pr = npr; pi = npi;
                float nar = er*ar - ei*ai, nai = er*ai + ei*ar;  ar = nar; ai = nai;
                uint u = (uint)f2bf(ar) | ((uint)f2bf(-ai) << 16);
                *(uint*)&Md[(63 - t) * KDIM + 64 + 2 * lane] = u;   // row 64-(t+1)
            }
            *(short8*)&Gr[tb * 8] = *(short8*)bufR;
            *(short8*)&Gi[tb * 8] = *(short8*)bufI;
        }
        e64[(size_t)d * NST + lane] = make_float2(ar, ai);   // eA^64
        __syncthreads();
        for (int r = 0; r < 64; ++r) {
            float v = (lane >= r) ? Klds[w][lane - r] : 0.f;
            Md[r * KDIM + lane] = __float2bfloat16(v);
        }
    }
}

// ---------------- k_ssm: merged scanU + gemmY (per-d block; carries never leave LDS) ----------------
__global__ __launch_bounds__(256) void k_ssm(
    const __hip_bfloat16* __restrict__ Gt, const __hip_bfloat16* __restrict__ Mt,
    const __hip_bfloat16* __restrict__ xT, const float2* __restrict__ e64,
    const float* __restrict__ Dp, __hip_bfloat16* __restrict__ yT)
{
    __shared__ short Zs[128 * 24 * 8];            // 48K persistent: x chunks 0-7, carry chunks 8-23
    __shared__ __align__(16) char Rgn[16384 + 128 * 129 * 4];   // union: {Gs 16K + Us 64.5K} / {Ms 24K}
    short* Gs = (short*)Rgn;
    float (*Us)[129] = (float(*)[129])(Rgn + 16384);
    short* Ms = (short*)Rgn;

    const int tid = threadIdx.x;
    const int d = blockIdx.x;
    const int w = tid >> 6, lane = tid & 63;
    const int q = lane >> 4, n = lane & 15;

    // ---- stage Gs (128 rows x 8 chunks) and Zs x-part (128 cols x 8 chunks) ----
    {
        const short* Gg = (const short*)(Gt + (size_t)d * 128 * 64);
        #pragma unroll
        for (int it = 0; it < 4; ++it) {
            int Gc = it * 256 + tid;
            int row = Gc >> 3, c = Gc & 7;
            int cs = c ^ (row & 7);
            *(short8*)&Gs[(row * 8 + cs) * 8] = *(const short8*)&Gg[Gc * 8];
        }
        #pragma unroll
        for (int it = 0; it < 4; ++it) {
            int id = it * 256 + tid;
            int col = id >> 3, ck = id & 7;
            int bb = col >> 5, ch = col & 31;
            short8 v = *(const short8*)&xT[((size_t)d * BATCH + bb) * SEQ + ch * 64 + ck * 8];
            int cs = ck ^ (col & 7);
            *(short8*)&Zs[(col * 24 + cs) * 8] = v;
        }
    }
    __syncthreads();

    // ---- phase 1: U = G * X ----
    {
        f32x4 acc[2][8];
        #pragma unroll
        for (int rt = 0; rt < 2; ++rt)
            #pragma unroll
            for (int nf = 0; nf < 8; ++nf)
                #pragma unroll
                for (int k = 0; k < 4; ++k) acc[rt][nf][k] = 0.f;

        #pragma unroll
        for (int rt = 0; rt < 2; ++rt) {
            const int arow = w * 32 + rt * 16 + n;
            #pragma unroll
            for (int kt = 0; kt < 2; ++kt) {
                int c = kt * 4 + q;
                int csa = c ^ (arow & 7);
                short8 af = *(const short8*)&Gs[(arow * 8 + csa) * 8];
                #pragma unroll
                for (int nf = 0; nf < 8; ++nf) {
                    int col = nf * 16 + n;
                    int csb = c ^ (col & 7);
                    short8 bf = *(const short8*)&Zs[(col * 24 + csb) * 8];
                    acc[rt][nf] = __builtin_amdgcn_mfma_f32_16x16x32_bf16(af, bf, acc[rt][nf], 0, 0, 0);
                }
            }
        }
        #pragma unroll
        for (int rt = 0; rt < 2; ++rt) {
            const int r0w = w * 32 + rt * 16 + q * 4;
            #pragma unroll
            for (int nf = 0; nf < 8; ++nf) {
                int col = nf * 16 + n;
                #pragma unroll
                for (int r = 0; r < 4; ++r) Us[r0w + r][col] = acc[rt][nf][r];
            }
        }
    }
    __syncthreads();

    // ---- phase 2: carry combine, bf16 results straight into Zs carry chunks ----
    {
        const int bb = tid >> 6, s = tid & 63;
        const int st = s >> 2, so = (s & 3) * 2;        // chunk st, short offset within 16B
        float2 a64 = e64[(size_t)d * NST + s];
        const float er = a64.x, ei = a64.y;
        {
            int col = bb * 32 + 31;
            int c = 8 + st, cs = (c & ~7) | ((c & 7) ^ (col & 7));
            *(uint*)&Zs[(col * 24 + cs) * 8 + so] = 0u;
        }
        float gr = Us[2 * s][bb * 32 + 31], gi = Us[2 * s + 1][bb * 32 + 31];
        {
            int col = bb * 32 + 30;
            int c = 8 + st, cs = (c & ~7) | ((c & 7) ^ (col & 7));
            *(uint*)&Zs[(col * 24 + cs) * 8 + so] = (uint)f2bf(gr) | ((uint)f2bf(gi) << 16);
        }
        for (int ch = 30; ch >= 1; --ch) {
            float ur = Us[2 * s][bb * 32 + ch], ui = Us[2 * s + 1][bb * 32 + ch];
            float nr = ur + er * gr - ei * gi;
            float ni = ui + er * gi + ei * gr;
            gr = nr; gi = ni;
            int col = bb * 32 + ch - 1;
            int c = 8 + st, cs = (c & ~7) | ((c & 7) ^ (col & 7));
            *(uint*)&Zs[(col * 24 + cs) * 8 + so] = (uint)f2bf(gr) | ((uint)f2bf(gi) << 16);
        }
    }
    __syncthreads();

    // ---- stage Ms into the union region (Gs/Us dead now) ----
    {
        const short* Mg = (const short*)(Mt + (size_t)d * 64 * KDIM);
        #pragma unroll
        for (int it = 0; it < 6; ++it) {
            int G = it * 256 + tid;
            int row = G / 24, c = G % 24;
            int cs = (c & ~7) | ((c & 7) ^ (row & 7));
            *(short8*)&Ms[(row * 24 + cs) * 8] = *(const short8*)&Mg[G * 8];
        }
    }
    __syncthreads();

    // ---- phase 3: y = M * Z, + D*x, store yT ----
    f32x4 acc[8];
    #pragma unroll
    for (int nf = 0; nf < 8; ++nf)
        #pragma unroll
        for (int k = 0; k < 4; ++k) acc[nf][k] = 0.f;

    const int arow = w * 16 + n;
    #pragma unroll
    for (int kt = 0; kt < 6; ++kt) {
        int c = kt * 4 + q;
        int csa = (c & ~7) | ((c & 7) ^ (arow & 7));
        short8 af = *(const short8*)&Ms[(arow * 24 + csa) * 8];
        #pragma unroll
        for (int nf = 0; nf < 8; ++nf) {
            int col = nf * 16 + n;
            int csb = (c & ~7) | ((c & 7) ^ (col & 7));
            short8 bfr = *(const short8*)&Zs[(col * 24 + csb) * 8];
            acc[nf] = __builtin_amdgcn_mfma_f32_16x16x32_bf16(af, bfr, acc[nf], 0, 0, 0);
        }
    }

    const float Dd = Dp[d];
    const int i0 = w * 16 + q * 4;
    #pragma unroll
    for (int nf = 0; nf < 8; ++nf) {
        int col = nf * 16 + n;
        int bb = col >> 5, ch = col & 31;
        int cx = (i0 >> 3) ^ (col & 7);
        const ushort* zp = (const ushort*)&Zs[(col * 24 + cx) * 8 + (i0 & 7)];
        ushort o[4];
        #pragma unroll
        for (int r = 0; r < 4; ++r)
            o[r] = f2bf(acc[nf][r] + Dd * bf2f(zp[r]));
        *(uint2*)&yT[((size_t)d * BATCH + bb) * SEQ + ch * 64 + i0] = *(uint2*)o;
    }
}

// ---------------- k_gemm_ln v14: A panel direct from yT (k_yt eliminated) + dbuf reg-staged B ----------------
__global__ __launch_bounds__(512) void k_gemm_ln(
    const __hip_bfloat16* __restrict__ yT, const __hip_bfloat16* __restrict__ Wbf,
    const float* __restrict__ x, const float* __restrict__ bout,
    const float* __restrict__ gamma, const float* __restrict__ beta,
    float* __restrict__ out)
{
    __shared__ short Af[32][520];     // full A panel [l][kd]; stride 520 -> 2-way banks on frag read
    __shared__ short Bs[512][32];     // W tile [o][k], 16B-chunk XOR swizzle (validated)
    __shared__ float red[8][32][2];
    __shared__ float stats[32][2];

    const int tid  = threadIdx.x;
    const int w    = tid >> 6;
    const int lane = tid & 63;
    const int q    = lane >> 4;
    const int m    = lane & 15;
    const int r0   = blockIdx.x * 32;
    const int bq   = r0 >> 11;           // batch index (r0 32-aligned, no straddle)
    const int l0   = r0 & 2047;

    // ---- one-time A panel from yT[d][b][l]: thread (kdb, lg) reads 8 overlapped uint2 ----
    {
        const int kdb = tid >> 3, lg = (tid & 7) * 4;
        uint2 u[8];
        #pragma unroll
        for (int j = 0; j < 8; ++j)
            u[j] = *(const uint2*)&yT[((size_t)(j * 64 + kdb) * BATCH + bq) * SEQ + l0 + lg];
        #pragma unroll
        for (int j = 0; j < 8; ++j) {
            int kd = j * 64 + kdb;
            Af[lg + 0][kd] = (short)(u[j].x & 0xffff);
            Af[lg + 1][kd] = (short)(u[j].x >> 16);
            Af[lg + 2][kd] = (short)(u[j].y & 0xffff);
            Af[lg + 3][kd] = (short)(u[j].y >> 16);
        }
    }

    // ---- B tile staging: 512 o x 32 k per step; 4 x 16B per thread ----
    short8 nb0, nb1, nb2, nb3;
    const int ob = tid >> 2, jb = tid & 3;
    const int js = (jb ^ (ob & 3)) * 8;
    #define LOADB(k0) { \
        nb0 = *(const short8*)(Wbf + (size_t)(ob      ) * DM + (k0) + jb * 8); \
        nb1 = *(const short8*)(Wbf + (size_t)(ob + 128) * DM + (k0) + jb * 8); \
        nb2 = *(const short8*)(Wbf + (size_t)(ob + 256) * DM + (k0) + jb * 8); \
        nb3 = *(const short8*)(Wbf + (size_t)(ob + 384) * DM + (k0) + jb * 8); }
    #define WRITEB() { \
        *(short8*)&Bs[ob      ][js] = nb0; \
        *(short8*)&Bs[ob + 128][js] = nb1; \
        *(short8*)&Bs[ob + 256][js] = nb2; \
        *(short8*)&Bs[ob + 384][js] = nb3; }

    LOADB(0);
    WRITEB();
    LOADB(32);
    __syncthreads();

    f32x4 acc[2][4];
    #pragma unroll
    for (int a = 0; a < 2; ++a)
        #pragma unroll
        for (int nn = 0; nn < 4; ++nn)
            #pragma unroll
            for (int k = 0; k < 4; ++k) acc[a][nn][k] = 0.f;

    for (int k = 0; k < 16; ++k) {
        const int k0 = k * 32;
        short8 a0 = *(const short8*)&Af[m][k0 + q * 8];
        short8 a1 = *(const short8*)&Af[16 + m][k0 + q * 8];
        #pragma unroll
        for (int nf = 0; nf < 4; ++nf) {
            int o = w * 64 + nf * 16 + m;        // o&3 == m&3
            short8 bb = *(const short8*)&Bs[o][(q ^ (m & 3)) * 8];
            acc[0][nf] = __builtin_amdgcn_mfma_f32_16x16x32_bf16(a0, bb, acc[0][nf], 0, 0, 0);
            acc[1][nf] = __builtin_amdgcn_mfma_f32_16x16x32_bf16(a1, bb, acc[1][nf], 0, 0, 0);
        }
        __syncthreads();                          // all waves done reading Bs
        if (k < 15) {
            WRITEB();                             // B_{k+1} regs -> LDS
            if (k < 14) LOADB((k + 2) * 32);      // issue B_{k+2}; lands during next compute
            __syncthreads();                      // Bs ready
        }
    }
    #undef LOADB
    #undef WRITEB

    // ---- epilogue: +bias, +x residual, row mean/var, normalize ----
    float bo[4], ga[4], be[4];
    #pragma unroll
    for (int nf = 0; nf < 4; ++nf) {
        int o = w * 64 + nf * 16 + m;
        bo[nf] = bout[o]; ga[nf] = gamma[o]; be[nf] = beta[o];
    }

    float rs[2][4], rq[2][4];
    #pragma unroll
    for (int mf = 0; mf < 2; ++mf)
        #pragma unroll
        for (int i = 0; i < 4; ++i) { rs[mf][i] = 0.f; rq[mf][i] = 0.f; }

    #pragma unroll
    for (int mf = 0; mf < 2; ++mf)
        #pragma unroll
        for (int nf = 0; nf < 4; ++nf) {
            int o = w * 64 + nf * 16 + m;
            #pragma unroll
            for (int i = 0; i < 4; ++i) {
                int row = mf * 16 + q * 4 + i;    // C/D: row=(lane>>4)*4+reg, col=lane&15
                float zv = acc[mf][nf][i] + bo[nf] + x[(size_t)(r0 + row) * DM + o];
                acc[mf][nf][i] = zv;
                rs[mf][i] += zv;
                rq[mf][i] += zv * zv;
            }
        }

    #pragma unroll
    for (int mask = 1; mask < 16; mask <<= 1) {
        #pragma unroll
        for (int mf = 0; mf < 2; ++mf)
            #pragma unroll
            for (int i = 0; i < 4; ++i) {
                rs[mf][i] += __shfl_xor(rs[mf][i], mask);
                rq[mf][i] += __shfl_xor(rq[mf][i], mask);
            }
    }
    if (m == 0) {
        #pragma unroll
        for (int mf = 0; mf < 2; ++mf)
            #pragma unroll
            for (int i = 0; i < 4; ++i) {
                int row = mf * 16 + q * 4 + i;
                red[w][row][0] = rs[mf][i];
                red[w][row][1] = rq[mf][i];
            }
    }
    __syncthreads();
    if (tid < 32) {
        float s = 0.f, sq = 0.f;
        #pragma unroll
        for (int ww = 0; ww < 8; ++ww) { s += red[ww][tid][0]; sq += red[ww][tid][1]; }
        float mu  = s * (1.f / DM);
        float var = sq * (1.f / DM) - mu * mu;
        stats[tid][0] = mu;
        stats[tid][1] = 1.f / sqrtf(var + LN_EPS);
    }
    __syncthreads();

    #pragma unroll
    for (int mf = 0; mf < 2; ++mf)
        #pragma unroll
        for (int i = 0; i < 4; ++i) {
            int row = mf * 16 + q * 4 + i;
            float mu = stats[row][0], rstd = stats[row][1];
            #pragma unroll
            for (int nf = 0; nf < 4; ++nf) {
                int o = w * 64 + nf * 16 + m;
                out[(size_t)(r0 + row) * DM + o] =
                    ga[nf] * (acc[mf][nf][i] - mu) * rstd + be[nf];
            }
        }
}

// ---------------- launcher ----------------
extern "C" void kernel_launch(void* const* d_in, const int* in_sizes, int n_in,
                              void* d_out, int out_size, void* d_ws, size_t ws_size,
                              hipStream_t stream)
{
    const float* x    = (const float*)d_in[0];
    const float* logA = (const float*)d_in[1];
    const float* Aim  = (const float*)d_in[2];
    const float* Bp   = (const float*)d_in[3];
    const float* Cp   = (const float*)d_in[4];
    const float* Dp   = (const float*)d_in[5];
    const float* W    = (const float*)d_in[6];
    const float* bo   = (const float*)d_in[7];
    const float* ga   = (const float*)d_in[8];
    const float* be   = (const float*)d_in[9];

    char* ws = (char*)d_ws;
    __hip_bfloat16* Wbf = (__hip_bfloat16*)ws;                   // 512 KiB @ 0
    __hip_bfloat16* xT  = (__hip_bfloat16*)(ws + (3u << 20));    // 8 MiB    @ 3M
    __hip_bfloat16* Mt  = (__hip_bfloat16*)(ws + (11u << 20));   // 12.6 MiB @ 11M
    __hip_bfloat16* yT  = (__hip_bfloat16*)(ws + (41u << 20));   // 8 MiB    @ 41M
    __hip_bfloat16* Gt  = (__hip_bfloat16*)(ws + (57u << 20));   // 8 MiB    @ 57M
    float2* e64         = (float2*)(ws + (65u << 20));           // 256 KiB  @ 65M

    k_prep   <<<3200, 256, 0, stream>>>(x, logA, Aim, Bp, Cp, W, xT, Wbf, Mt, Gt, e64);
    k_ssm    <<<DM, 256, 0, stream>>>(Gt, Mt, xT, e64, Dp, yT);
    k_gemm_ln<<<(BATCH * SEQ) / 32, 512, 0, stream>>>(yT, Wbf, x, bo, ga, be, (float*)d_out);
}